// Round 1
// baseline (482.824 us; speedup 1.0000x reference)
//
#include <hip/hip_runtime.h>
#include <cstddef>

// Problem constants
constexpr int BATCH = 16;
constexpr int CIN   = 512;
constexpr int WID   = 128;   // bottleneck width
constexpr int NQ    = 1024;  // H*W
constexpr int HEADS = 4;
constexpr int HD    = 32;
constexpr float ATT_SCALE = 0.17677669529663687f; // 32^-0.5

// ---------------------------------------------------------------------------
// Tiled fp32 GEMM: C[b][c][n] = sum_k A[c][k] * B[b][k][n]
// BM=64, BN=128, BK=16, 256 threads, 4x8 per thread.
// grid: (NQ/128, M/64, BATCH)
// ---------------------------------------------------------------------------
template<int KTOT>
__global__ __launch_bounds__(256) void k_gemm_conv(const float* __restrict__ A,
                                                   const float* __restrict__ Bmat,
                                                   float* __restrict__ C, int M) {
  const int b   = blockIdx.z;
  const int c0  = blockIdx.y * 64;
  const int n0  = blockIdx.x * 128;
  const int tid = threadIdx.x;
  const int ty  = tid >> 4;       // 0..15
  const int tx  = tid & 15;       // 0..15

  __shared__ float As[16][68];    // [kk][row], padded
  __shared__ float Bs[16][128];   // [kk][n]

  const float* Bp = Bmat + (size_t)b * KTOT * NQ;

  float acc[4][8];
#pragma unroll
  for (int i = 0; i < 4; ++i)
#pragma unroll
    for (int j = 0; j < 8; ++j) acc[i][j] = 0.f;

  const int arow = tid >> 2;         // 0..63
  const int ak4  = (tid & 3) * 4;    // 0,4,8,12
  const int bk   = tid >> 5;         // 0..7
  const int bn4  = (tid & 31) * 4;   // 0..124

  for (int k0 = 0; k0 < KTOT; k0 += 16) {
    float4 av  = *reinterpret_cast<const float4*>(A + (size_t)(c0 + arow) * KTOT + k0 + ak4);
    float4 bv0 = *reinterpret_cast<const float4*>(Bp + (size_t)(k0 + bk    ) * NQ + n0 + bn4);
    float4 bv1 = *reinterpret_cast<const float4*>(Bp + (size_t)(k0 + bk + 8) * NQ + n0 + bn4);
    __syncthreads();
    As[ak4 + 0][arow] = av.x;
    As[ak4 + 1][arow] = av.y;
    As[ak4 + 2][arow] = av.z;
    As[ak4 + 3][arow] = av.w;
    *reinterpret_cast<float4*>(&Bs[bk    ][bn4]) = bv0;
    *reinterpret_cast<float4*>(&Bs[bk + 8][bn4]) = bv1;
    __syncthreads();
#pragma unroll
    for (int kk = 0; kk < 16; ++kk) {
      float4 a  = *reinterpret_cast<const float4*>(&As[kk][ty * 4]);
      float4 b0 = *reinterpret_cast<const float4*>(&Bs[kk][tx * 8]);
      float4 b1 = *reinterpret_cast<const float4*>(&Bs[kk][tx * 8 + 4]);
      float ar[4] = {a.x, a.y, a.z, a.w};
      float br[8] = {b0.x, b0.y, b0.z, b0.w, b1.x, b1.y, b1.z, b1.w};
#pragma unroll
      for (int i = 0; i < 4; ++i)
#pragma unroll
        for (int j = 0; j < 8; ++j) acc[i][j] += ar[i] * br[j];
    }
  }

#pragma unroll
  for (int i = 0; i < 4; ++i) {
    float4 v0 = {acc[i][0], acc[i][1], acc[i][2], acc[i][3]};
    float4 v1 = {acc[i][4], acc[i][5], acc[i][6], acc[i][7]};
    float* cp = C + ((size_t)b * M + c0 + ty * 4 + i) * NQ + n0 + tx * 8;
    *reinterpret_cast<float4*>(cp)     = v0;
    *reinterpret_cast<float4*>(cp + 4) = v1;
  }
}

// ---------------------------------------------------------------------------
// BN train-mode stats -> per-channel scale/shift.  grid = C blocks.
// scale[c] = rstd*g[c];  shift[c] = beta[c] - mean*scale[c]
// ---------------------------------------------------------------------------
__global__ __launch_bounds__(256) void k_bnstats(const float* __restrict__ y, int C,
                                                 const float* __restrict__ g,
                                                 const float* __restrict__ beta,
                                                 float* __restrict__ scl,
                                                 float* __restrict__ sht) {
  const int c = blockIdx.x;
  const int tid = threadIdx.x;
  float s = 0.f, ss = 0.f;
  for (int b = 0; b < BATCH; ++b) {
    const float* p = y + ((size_t)b * C + c) * NQ;
    float4 v = *reinterpret_cast<const float4*>(p + tid * 4);
    s  += v.x + v.y + v.z + v.w;
    ss += v.x * v.x + v.y * v.y + v.z * v.z + v.w * v.w;
  }
  __shared__ float rs[256], rss[256];
  rs[tid] = s; rss[tid] = ss;
  __syncthreads();
  for (int st = 128; st > 0; st >>= 1) {
    if (tid < st) { rs[tid] += rs[tid + st]; rss[tid] += rss[tid + st]; }
    __syncthreads();
  }
  if (tid == 0) {
    const float inv_n = 1.f / (BATCH * NQ);
    float mean = rs[0] * inv_n;
    float var  = rss[0] * inv_n - mean * mean;
    float rstd = rsqrtf(var + 1e-5f);
    float sc = rstd * g[c];
    scl[c] = sc;
    sht[c] = beta[c] - mean * sc;
  }
}

// ---------------------------------------------------------------------------
// qkv GEMM: reads y1 with fused bn1+relu, A = qkv_w [384][128].
// Writes q (scaled, n-major), k' = k + r (n-major), v (n-major).
// grid: (NQ/128, 6, BATCH); mtile 0,1 -> q ; 2,3 -> k ; 4,5 -> v
// ---------------------------------------------------------------------------
__global__ __launch_bounds__(256) void k_gemm_qkv(const float* __restrict__ A,
                                                  const float* __restrict__ y1,
                                                  const float* __restrict__ s1,
                                                  const float* __restrict__ h1,
                                                  const float* __restrict__ rw,
                                                  const float* __restrict__ rh,
                                                  float* __restrict__ qs,
                                                  float* __restrict__ kt,
                                                  float* __restrict__ vt) {
  const int b   = blockIdx.z;
  const int mt  = blockIdx.y;          // 0..5
  const int c0  = mt * 64;
  const int n0  = blockIdx.x * 128;
  const int tid = threadIdx.x;
  const int ty  = tid >> 4;
  const int tx  = tid & 15;

  __shared__ float As[16][68];
  __shared__ float Bs[16][128];

  const float* Bp = y1 + (size_t)b * WID * NQ;

  float acc[4][8];
#pragma unroll
  for (int i = 0; i < 4; ++i)
#pragma unroll
    for (int j = 0; j < 8; ++j) acc[i][j] = 0.f;

  const int arow = tid >> 2;
  const int ak4  = (tid & 3) * 4;
  const int bk   = tid >> 5;
  const int bn4  = (tid & 31) * 4;

  for (int k0 = 0; k0 < WID; k0 += 16) {
    float4 av  = *reinterpret_cast<const float4*>(A + (size_t)(c0 + arow) * WID + k0 + ak4);
    const int kr0 = k0 + bk, kr1 = k0 + bk + 8;
    float4 bv0 = *reinterpret_cast<const float4*>(Bp + (size_t)kr0 * NQ + n0 + bn4);
    float4 bv1 = *reinterpret_cast<const float4*>(Bp + (size_t)kr1 * NQ + n0 + bn4);
    float sc0 = s1[kr0], sh0 = h1[kr0];
    float sc1 = s1[kr1], sh1 = h1[kr1];
    bv0.x = fmaxf(bv0.x * sc0 + sh0, 0.f);
    bv0.y = fmaxf(bv0.y * sc0 + sh0, 0.f);
    bv0.z = fmaxf(bv0.z * sc0 + sh0, 0.f);
    bv0.w = fmaxf(bv0.w * sc0 + sh0, 0.f);
    bv1.x = fmaxf(bv1.x * sc1 + sh1, 0.f);
    bv1.y = fmaxf(bv1.y * sc1 + sh1, 0.f);
    bv1.z = fmaxf(bv1.z * sc1 + sh1, 0.f);
    bv1.w = fmaxf(bv1.w * sc1 + sh1, 0.f);
    __syncthreads();
    As[ak4 + 0][arow] = av.x;
    As[ak4 + 1][arow] = av.y;
    As[ak4 + 2][arow] = av.z;
    As[ak4 + 3][arow] = av.w;
    *reinterpret_cast<float4*>(&Bs[bk    ][bn4]) = bv0;
    *reinterpret_cast<float4*>(&Bs[bk + 8][bn4]) = bv1;
    __syncthreads();
#pragma unroll
    for (int kk = 0; kk < 16; ++kk) {
      float4 a  = *reinterpret_cast<const float4*>(&As[kk][ty * 4]);
      float4 b0 = *reinterpret_cast<const float4*>(&Bs[kk][tx * 8]);
      float4 b1 = *reinterpret_cast<const float4*>(&Bs[kk][tx * 8 + 4]);
      float ar[4] = {a.x, a.y, a.z, a.w};
      float br[8] = {b0.x, b0.y, b0.z, b0.w, b1.x, b1.y, b1.z, b1.w};
#pragma unroll
      for (int i = 0; i < 4; ++i)
#pragma unroll
        for (int j = 0; j < 8; ++j) acc[i][j] += ar[i] * br[j];
    }
  }

  // epilogue: transpose-store into (b,h,n,d)
  const int type = mt >> 1;                  // 0=q,1=k,2=v
  const int c128 = (mt & 1) * 64 + ty * 4;   // base channel within 128
  const int hh = c128 >> 5;
  const int d0 = c128 & 31;
  float* dst = (type == 0) ? qs : (type == 1) ? kt : vt;
  const size_t base = (size_t)(b * HEADS + hh) * NQ * HD;

#pragma unroll
  for (int j = 0; j < 8; ++j) {
    const int n = n0 + tx * 8 + j;
    float4 v = {acc[0][j], acc[1][j], acc[2][j], acc[3][j]};
    if (type == 0) {
      v.x *= ATT_SCALE; v.y *= ATT_SCALE; v.z *= ATT_SCALE; v.w *= ATT_SCALE;
    } else if (type == 1) {
      const int wcol = n & 31, hrow = n >> 5;
      v.x += rw[(hh * 32 + d0 + 0) * 32 + wcol] + rh[(hh * 32 + d0 + 0) * 32 + hrow];
      v.y += rw[(hh * 32 + d0 + 1) * 32 + wcol] + rh[(hh * 32 + d0 + 1) * 32 + hrow];
      v.z += rw[(hh * 32 + d0 + 2) * 32 + wcol] + rh[(hh * 32 + d0 + 2) * 32 + hrow];
      v.w += rw[(hh * 32 + d0 + 3) * 32 + wcol] + rh[(hh * 32 + d0 + 3) * 32 + hrow];
    }
    *reinterpret_cast<float4*>(dst + base + (size_t)n * HD + d0) = v;
  }
}

// ---------------------------------------------------------------------------
// Flash-style attention. 1 query per thread, online softmax.
// grid: (NQ/256, BATCH*HEADS), 256 threads.
// ao[b][h*32+d][n] = sum_m softmax(qk')[n][m] * v[m][d]
// ---------------------------------------------------------------------------
__global__ __launch_bounds__(256) void k_attn(const float* __restrict__ qs,
                                              const float* __restrict__ kt,
                                              const float* __restrict__ vt,
                                              float* __restrict__ ao) {
  const int bh  = blockIdx.y;
  const int tid = threadIdx.x;
  const int n   = blockIdx.x * 256 + tid;

  const float* qp = qs + ((size_t)bh * NQ + n) * HD;
  float q[32];
#pragma unroll
  for (int i = 0; i < 8; ++i) {
    float4 v = *reinterpret_cast<const float4*>(qp + i * 4);
    q[i * 4 + 0] = v.x; q[i * 4 + 1] = v.y; q[i * 4 + 2] = v.z; q[i * 4 + 3] = v.w;
  }
  float o[32];
#pragma unroll
  for (int d = 0; d < 32; ++d) o[d] = 0.f;
  float mrun = -1e30f, l = 0.f;

  __shared__ float Ks[64 * 32];
  __shared__ float Vs[64 * 32];
  const float* kb = kt + (size_t)bh * NQ * HD;
  const float* vb = vt + (size_t)bh * NQ * HD;

  for (int m0 = 0; m0 < NQ; m0 += 64) {
    __syncthreads();
    const float4* ksrc = reinterpret_cast<const float4*>(kb + (size_t)m0 * HD);
    const float4* vsrc = reinterpret_cast<const float4*>(vb + (size_t)m0 * HD);
    reinterpret_cast<float4*>(Ks)[tid]       = ksrc[tid];
    reinterpret_cast<float4*>(Ks)[tid + 256] = ksrc[tid + 256];
    reinterpret_cast<float4*>(Vs)[tid]       = vsrc[tid];
    reinterpret_cast<float4*>(Vs)[tid + 256] = vsrc[tid + 256];
    __syncthreads();

    for (int mm = 0; mm < 64; ++mm) {
      const float* kr = Ks + mm * 32;
      float s = 0.f;
#pragma unroll
      for (int i = 0; i < 8; ++i) {
        float4 kv = *reinterpret_cast<const float4*>(kr + i * 4);
        s += q[i * 4 + 0] * kv.x + q[i * 4 + 1] * kv.y +
             q[i * 4 + 2] * kv.z + q[i * 4 + 3] * kv.w;
      }
      if (s > mrun) {
        float corr = __expf(mrun - s);
        l *= corr;
#pragma unroll
        for (int d = 0; d < 32; ++d) o[d] *= corr;
        mrun = s;
      }
      float p = __expf(s - mrun);
      l += p;
      const float* vr = Vs + mm * 32;
#pragma unroll
      for (int i = 0; i < 8; ++i) {
        float4 vv = *reinterpret_cast<const float4*>(vr + i * 4);
        o[i * 4 + 0] += p * vv.x; o[i * 4 + 1] += p * vv.y;
        o[i * 4 + 2] += p * vv.z; o[i * 4 + 3] += p * vv.w;
      }
    }
  }

  const float inv = 1.f / l;
  float* aop = ao + ((size_t)(bh >> 2) * WID + (bh & 3) * HD) * NQ + n;
#pragma unroll
  for (int d = 0; d < 32; ++d) aop[(size_t)d * NQ] = o[d] * inv;
}

// ---------------------------------------------------------------------------
// Final: out = relu(y2*scale2[c] + shift2[c] + x)
// ---------------------------------------------------------------------------
__global__ __launch_bounds__(256) void k_final(const float* __restrict__ y2,
                                               const float* __restrict__ x,
                                               const float* __restrict__ scl,
                                               const float* __restrict__ sht,
                                               float* __restrict__ out) {
  const size_t i = ((size_t)blockIdx.x * 256 + threadIdx.x) * 4;
  const int c = (int)((i >> 10) & 511);
  const float sc = scl[c], sh = sht[c];
  float4 v  = *reinterpret_cast<const float4*>(y2 + i);
  float4 xv = *reinterpret_cast<const float4*>(x + i);
  v.x = fmaxf(v.x * sc + sh + xv.x, 0.f);
  v.y = fmaxf(v.y * sc + sh + xv.y, 0.f);
  v.z = fmaxf(v.z * sc + sh + xv.z, 0.f);
  v.w = fmaxf(v.w * sc + sh + xv.w, 0.f);
  *reinterpret_cast<float4*>(out + i) = v;
}

// ---------------------------------------------------------------------------
extern "C" void kernel_launch(void* const* d_in, const int* in_sizes, int n_in,
                              void* d_out, int out_size, void* d_ws, size_t ws_size,
                              hipStream_t stream) {
  (void)in_sizes; (void)n_in; (void)out_size; (void)ws_size;
  const float* x    = (const float*)d_in[0];
  const float* w1   = (const float*)d_in[1];
  const float* g1   = (const float*)d_in[2];
  const float* b1   = (const float*)d_in[3];
  const float* wqkv = (const float*)d_in[4];
  const float* rw   = (const float*)d_in[5];
  const float* rh   = (const float*)d_in[6];
  const float* w2   = (const float*)d_in[7];
  const float* g2   = (const float*)d_in[8];
  const float* b2   = (const float*)d_in[9];
  float* out = (float*)d_out;
  float* ws  = (float*)d_ws;

  // Workspace layout (floats). y2 reuses [0, 8388608) after y1/q/k/v are dead.
  constexpr size_t SEG = 2097152;        // 16*128*1024
  float* y1   = ws;                      // [0, SEG)
  float* qs   = ws + SEG;                // [SEG, 2*SEG)
  float* kt   = ws + 2 * SEG;
  float* vt   = ws + 3 * SEG;
  float* ao   = ws + 4 * SEG;            // [4SEG, 5SEG)
  float* y2   = ws;                      // overlaps y1..vt (dead by then), 4*SEG floats
  float* scl1 = ws + 5 * SEG;
  float* sht1 = scl1 + 128;
  float* scl2 = sht1 + 128;
  float* sht2 = scl2 + 512;

  // 1) conv1: y1 = w1 @ x                (M=128, K=512)
  k_gemm_conv<512><<<dim3(8, 2, BATCH), 256, 0, stream>>>(w1, x, y1, 128);
  // 2) bn1 stats
  k_bnstats<<<128, 256, 0, stream>>>(y1, 128, g1, b1, scl1, sht1);
  // 3) qkv = wqkv @ relu(bn1(y1)); write q*scale, k+r, v  (n-major)
  k_gemm_qkv<<<dim3(8, 6, BATCH), 256, 0, stream>>>(wqkv, y1, scl1, sht1, rw, rh, qs, kt, vt);
  // 4) attention
  k_attn<<<dim3(4, BATCH * HEADS), 256, 0, stream>>>(qs, kt, vt, ao);
  // 5) conv2: y2 = w2 @ ao               (M=512, K=128)
  k_gemm_conv<128><<<dim3(8, 8, BATCH), 256, 0, stream>>>(w2, ao, y2, 512);
  // 6) bn2 stats
  k_bnstats<<<512, 256, 0, stream>>>(y2, 512, g2, b2, scl2, sht2);
  // 7) out = relu(bn2(y2) + x)
  k_final<<<8192, 256, 0, stream>>>(y2, x, scl2, sht2, out);
}

// Round 2
// 354.176 us; speedup vs baseline: 1.3632x; 1.3632x over previous
//
#include <hip/hip_runtime.h>
#include <cstddef>

// Problem constants
constexpr int BATCH = 16;
constexpr int CIN   = 512;
constexpr int WID   = 128;   // bottleneck width
constexpr int NQ    = 1024;  // H*W
constexpr int HEADS = 4;
constexpr int HD    = 32;
constexpr int NCHUNK = 4;    // KV chunks for attention split
constexpr float ATT_SCALE = 0.17677669529663687f;  // 32^-0.5
constexpr float QSCALE = 0.17677669529663687f * 1.4426950408889634f; // scale*log2e

// ---------------------------------------------------------------------------
// Tiled fp32 GEMM: C[b][c][n] = sum_k A[c][k] * B[b][k][n]
// BM=64, BN=128, BK=16, 256 threads, 4x8 per thread.
// grid: (NQ/128, M/64, BATCH)
// ---------------------------------------------------------------------------
template<int KTOT>
__global__ __launch_bounds__(256) void k_gemm_conv(const float* __restrict__ A,
                                                   const float* __restrict__ Bmat,
                                                   float* __restrict__ C, int M) {
  const int b   = blockIdx.z;
  const int c0  = blockIdx.y * 64;
  const int n0  = blockIdx.x * 128;
  const int tid = threadIdx.x;
  const int ty  = tid >> 4;       // 0..15
  const int tx  = tid & 15;       // 0..15

  __shared__ float As[16][68];    // [kk][row], padded
  __shared__ float Bs[16][128];   // [kk][n]

  const float* Bp = Bmat + (size_t)b * KTOT * NQ;

  float acc[4][8];
#pragma unroll
  for (int i = 0; i < 4; ++i)
#pragma unroll
    for (int j = 0; j < 8; ++j) acc[i][j] = 0.f;

  const int arow = tid >> 2;         // 0..63
  const int ak4  = (tid & 3) * 4;    // 0,4,8,12
  const int bk   = tid >> 5;         // 0..7
  const int bn4  = (tid & 31) * 4;   // 0..124

  for (int k0 = 0; k0 < KTOT; k0 += 16) {
    float4 av  = *reinterpret_cast<const float4*>(A + (size_t)(c0 + arow) * KTOT + k0 + ak4);
    float4 bv0 = *reinterpret_cast<const float4*>(Bp + (size_t)(k0 + bk    ) * NQ + n0 + bn4);
    float4 bv1 = *reinterpret_cast<const float4*>(Bp + (size_t)(k0 + bk + 8) * NQ + n0 + bn4);
    __syncthreads();
    As[ak4 + 0][arow] = av.x;
    As[ak4 + 1][arow] = av.y;
    As[ak4 + 2][arow] = av.z;
    As[ak4 + 3][arow] = av.w;
    *reinterpret_cast<float4*>(&Bs[bk    ][bn4]) = bv0;
    *reinterpret_cast<float4*>(&Bs[bk + 8][bn4]) = bv1;
    __syncthreads();
#pragma unroll
    for (int kk = 0; kk < 16; ++kk) {
      float4 a  = *reinterpret_cast<const float4*>(&As[kk][ty * 4]);
      float4 b0 = *reinterpret_cast<const float4*>(&Bs[kk][tx * 8]);
      float4 b1 = *reinterpret_cast<const float4*>(&Bs[kk][tx * 8 + 4]);
      float ar[4] = {a.x, a.y, a.z, a.w};
      float br[8] = {b0.x, b0.y, b0.z, b0.w, b1.x, b1.y, b1.z, b1.w};
#pragma unroll
      for (int i = 0; i < 4; ++i)
#pragma unroll
        for (int j = 0; j < 8; ++j) acc[i][j] += ar[i] * br[j];
    }
  }

#pragma unroll
  for (int i = 0; i < 4; ++i) {
    float4 v0 = {acc[i][0], acc[i][1], acc[i][2], acc[i][3]};
    float4 v1 = {acc[i][4], acc[i][5], acc[i][6], acc[i][7]};
    float* cp = C + ((size_t)b * M + c0 + ty * 4 + i) * NQ + n0 + tx * 8;
    *reinterpret_cast<float4*>(cp)     = v0;
    *reinterpret_cast<float4*>(cp + 4) = v1;
  }
}

// ---------------------------------------------------------------------------
// BN train-mode stats -> per-channel scale/shift.  grid = C blocks.
// ---------------------------------------------------------------------------
__global__ __launch_bounds__(256) void k_bnstats(const float* __restrict__ y, int C,
                                                 const float* __restrict__ g,
                                                 const float* __restrict__ beta,
                                                 float* __restrict__ scl,
                                                 float* __restrict__ sht) {
  const int c = blockIdx.x;
  const int tid = threadIdx.x;
  float s = 0.f, ss = 0.f;
  for (int b = 0; b < BATCH; ++b) {
    const float* p = y + ((size_t)b * C + c) * NQ;
    float4 v = *reinterpret_cast<const float4*>(p + tid * 4);
    s  += v.x + v.y + v.z + v.w;
    ss += v.x * v.x + v.y * v.y + v.z * v.z + v.w * v.w;
  }
  __shared__ float rs[256], rss[256];
  rs[tid] = s; rss[tid] = ss;
  __syncthreads();
  for (int st = 128; st > 0; st >>= 1) {
    if (tid < st) { rs[tid] += rs[tid + st]; rss[tid] += rss[tid + st]; }
    __syncthreads();
  }
  if (tid == 0) {
    const float inv_n = 1.f / (BATCH * NQ);
    float mean = rs[0] * inv_n;
    float var  = rss[0] * inv_n - mean * mean;
    float rstd = rsqrtf(var + 1e-5f);
    float sc = rstd * g[c];
    scl[c] = sc;
    sht[c] = beta[c] - mean * sc;
  }
}

// ---------------------------------------------------------------------------
// qkv GEMM: reads y1 with fused bn1+relu, A = qkv_w [384][128].
// Writes q (scaled by scale*log2e, n-major), k' = k + r (n-major), v (n-major).
// grid: (NQ/128, 6, BATCH); mtile 0,1 -> q ; 2,3 -> k ; 4,5 -> v
// ---------------------------------------------------------------------------
__global__ __launch_bounds__(256) void k_gemm_qkv(const float* __restrict__ A,
                                                  const float* __restrict__ y1,
                                                  const float* __restrict__ s1,
                                                  const float* __restrict__ h1,
                                                  const float* __restrict__ rw,
                                                  const float* __restrict__ rh,
                                                  float* __restrict__ qs,
                                                  float* __restrict__ kt,
                                                  float* __restrict__ vt) {
  const int b   = blockIdx.z;
  const int mt  = blockIdx.y;          // 0..5
  const int c0  = mt * 64;
  const int n0  = blockIdx.x * 128;
  const int tid = threadIdx.x;
  const int ty  = tid >> 4;
  const int tx  = tid & 15;

  __shared__ float As[16][68];
  __shared__ float Bs[16][128];

  const float* Bp = y1 + (size_t)b * WID * NQ;

  float acc[4][8];
#pragma unroll
  for (int i = 0; i < 4; ++i)
#pragma unroll
    for (int j = 0; j < 8; ++j) acc[i][j] = 0.f;

  const int arow = tid >> 2;
  const int ak4  = (tid & 3) * 4;
  const int bk   = tid >> 5;
  const int bn4  = (tid & 31) * 4;

  for (int k0 = 0; k0 < WID; k0 += 16) {
    float4 av  = *reinterpret_cast<const float4*>(A + (size_t)(c0 + arow) * WID + k0 + ak4);
    const int kr0 = k0 + bk, kr1 = k0 + bk + 8;
    float4 bv0 = *reinterpret_cast<const float4*>(Bp + (size_t)kr0 * NQ + n0 + bn4);
    float4 bv1 = *reinterpret_cast<const float4*>(Bp + (size_t)kr1 * NQ + n0 + bn4);
    float sc0 = s1[kr0], sh0 = h1[kr0];
    float sc1 = s1[kr1], sh1 = h1[kr1];
    bv0.x = fmaxf(bv0.x * sc0 + sh0, 0.f);
    bv0.y = fmaxf(bv0.y * sc0 + sh0, 0.f);
    bv0.z = fmaxf(bv0.z * sc0 + sh0, 0.f);
    bv0.w = fmaxf(bv0.w * sc0 + sh0, 0.f);
    bv1.x = fmaxf(bv1.x * sc1 + sh1, 0.f);
    bv1.y = fmaxf(bv1.y * sc1 + sh1, 0.f);
    bv1.z = fmaxf(bv1.z * sc1 + sh1, 0.f);
    bv1.w = fmaxf(bv1.w * sc1 + sh1, 0.f);
    __syncthreads();
    As[ak4 + 0][arow] = av.x;
    As[ak4 + 1][arow] = av.y;
    As[ak4 + 2][arow] = av.z;
    As[ak4 + 3][arow] = av.w;
    *reinterpret_cast<float4*>(&Bs[bk    ][bn4]) = bv0;
    *reinterpret_cast<float4*>(&Bs[bk + 8][bn4]) = bv1;
    __syncthreads();
#pragma unroll
    for (int kk = 0; kk < 16; ++kk) {
      float4 a  = *reinterpret_cast<const float4*>(&As[kk][ty * 4]);
      float4 b0 = *reinterpret_cast<const float4*>(&Bs[kk][tx * 8]);
      float4 b1 = *reinterpret_cast<const float4*>(&Bs[kk][tx * 8 + 4]);
      float ar[4] = {a.x, a.y, a.z, a.w};
      float br[8] = {b0.x, b0.y, b0.z, b0.w, b1.x, b1.y, b1.z, b1.w};
#pragma unroll
      for (int i = 0; i < 4; ++i)
#pragma unroll
        for (int j = 0; j < 8; ++j) acc[i][j] += ar[i] * br[j];
    }
  }

  // epilogue: transpose-store into (b,h,n,d)
  const int type = mt >> 1;                  // 0=q,1=k,2=v
  const int c128 = (mt & 1) * 64 + ty * 4;   // base channel within 128
  const int hh = c128 >> 5;
  const int d0 = c128 & 31;
  float* dst = (type == 0) ? qs : (type == 1) ? kt : vt;
  const size_t base = (size_t)(b * HEADS + hh) * NQ * HD;

#pragma unroll
  for (int j = 0; j < 8; ++j) {
    const int n = n0 + tx * 8 + j;
    float4 v = {acc[0][j], acc[1][j], acc[2][j], acc[3][j]};
    if (type == 0) {
      v.x *= QSCALE; v.y *= QSCALE; v.z *= QSCALE; v.w *= QSCALE;
    } else if (type == 1) {
      const int wcol = n & 31, hrow = n >> 5;
      v.x += rw[(hh * 32 + d0 + 0) * 32 + wcol] + rh[(hh * 32 + d0 + 0) * 32 + hrow];
      v.y += rw[(hh * 32 + d0 + 1) * 32 + wcol] + rh[(hh * 32 + d0 + 1) * 32 + hrow];
      v.z += rw[(hh * 32 + d0 + 2) * 32 + wcol] + rh[(hh * 32 + d0 + 2) * 32 + hrow];
      v.w += rw[(hh * 32 + d0 + 3) * 32 + wcol] + rh[(hh * 32 + d0 + 3) * 32 + hrow];
    }
    *reinterpret_cast<float4*>(dst + base + (size_t)n * HD + d0) = v;
  }
}

// ---------------------------------------------------------------------------
// Flash attention, KV-split. 1 query/thread, online softmax over a 256-wide
// KV chunk. grid: (NQ/256, NCHUNK, BATCH*HEADS), 256 threads.
// Emits unnormalized partials: po[(bh,c,d)][n], pm/pl[(bh,c)][n].
// Uses base-2 exponentials (q pre-scaled by log2e).
// ---------------------------------------------------------------------------
__global__ __launch_bounds__(256) void k_attn_part(const float* __restrict__ qs,
                                                   const float* __restrict__ kt,
                                                   const float* __restrict__ vt,
                                                   float* __restrict__ po,
                                                   float* __restrict__ pm,
                                                   float* __restrict__ pl) {
  const int bh  = blockIdx.z;
  const int ck  = blockIdx.y;
  const int tid = threadIdx.x;
  const int n   = blockIdx.x * 256 + tid;

  const float* qp = qs + ((size_t)bh * NQ + n) * HD;
  float q[32];
#pragma unroll
  for (int i = 0; i < 8; ++i) {
    float4 v = *reinterpret_cast<const float4*>(qp + i * 4);
    q[i * 4 + 0] = v.x; q[i * 4 + 1] = v.y; q[i * 4 + 2] = v.z; q[i * 4 + 3] = v.w;
  }
  float o[32];
#pragma unroll
  for (int d = 0; d < 32; ++d) o[d] = 0.f;
  float mrun = -1e30f, l = 0.f;

  __shared__ float Ks[64 * 32];
  __shared__ float Vs[64 * 32];
  const float* kb = kt + (size_t)bh * NQ * HD;
  const float* vb = vt + (size_t)bh * NQ * HD;

  const int mbeg = ck * (NQ / NCHUNK);
  for (int m0 = mbeg; m0 < mbeg + NQ / NCHUNK; m0 += 64) {
    __syncthreads();
    const float4* ksrc = reinterpret_cast<const float4*>(kb + (size_t)m0 * HD);
    const float4* vsrc = reinterpret_cast<const float4*>(vb + (size_t)m0 * HD);
    reinterpret_cast<float4*>(Ks)[tid]       = ksrc[tid];
    reinterpret_cast<float4*>(Ks)[tid + 256] = ksrc[tid + 256];
    reinterpret_cast<float4*>(Vs)[tid]       = vsrc[tid];
    reinterpret_cast<float4*>(Vs)[tid + 256] = vsrc[tid + 256];
    __syncthreads();

    for (int mm = 0; mm < 64; ++mm) {
      const float* kr = Ks + mm * 32;
      float s = 0.f;
#pragma unroll
      for (int i = 0; i < 8; ++i) {
        float4 kv = *reinterpret_cast<const float4*>(kr + i * 4);
        s += q[i * 4 + 0] * kv.x + q[i * 4 + 1] * kv.y +
             q[i * 4 + 2] * kv.z + q[i * 4 + 3] * kv.w;
      }
      if (s > mrun) {
        float corr = exp2f(mrun - s);
        l *= corr;
#pragma unroll
        for (int d = 0; d < 32; ++d) o[d] *= corr;
        mrun = s;
      }
      float p = exp2f(s - mrun);
      l += p;
      const float* vr = Vs + mm * 32;
#pragma unroll
      for (int i = 0; i < 8; ++i) {
        float4 vv = *reinterpret_cast<const float4*>(vr + i * 4);
        o[i * 4 + 0] += p * vv.x; o[i * 4 + 1] += p * vv.y;
        o[i * 4 + 2] += p * vv.z; o[i * 4 + 3] += p * vv.w;
      }
    }
  }

  // store unnormalized partials, d-major (coalesced in n)
  float* pob = po + ((size_t)(bh * NCHUNK + ck) * HD) * NQ + n;
#pragma unroll
  for (int d = 0; d < 32; ++d) pob[(size_t)d * NQ] = o[d];
  pm[(size_t)(bh * NCHUNK + ck) * NQ + n] = mrun;
  pl[(size_t)(bh * NCHUNK + ck) * NQ + n] = l;
}

// ---------------------------------------------------------------------------
// Combine partials -> ao[b][h*32+d][n].  grid: (NQ/256, BATCH*HEADS)
// ---------------------------------------------------------------------------
__global__ __launch_bounds__(256) void k_attn_comb(const float* __restrict__ po,
                                                   const float* __restrict__ pm,
                                                   const float* __restrict__ pl,
                                                   float* __restrict__ ao) {
  const int bh = blockIdx.y;
  const int n  = blockIdx.x * 256 + threadIdx.x;

  float mc[NCHUNK], M = -1e30f;
#pragma unroll
  for (int c = 0; c < NCHUNK; ++c) {
    mc[c] = pm[(size_t)(bh * NCHUNK + c) * NQ + n];
    M = fmaxf(M, mc[c]);
  }
  float w[NCHUNK], l = 0.f;
#pragma unroll
  for (int c = 0; c < NCHUNK; ++c) {
    w[c] = exp2f(mc[c] - M);
    l += w[c] * pl[(size_t)(bh * NCHUNK + c) * NQ + n];
  }
  const float inv = 1.f / l;

  float* aop = ao + ((size_t)(bh >> 2) * WID + (bh & 3) * HD) * NQ + n;
#pragma unroll
  for (int d = 0; d < 32; ++d) {
    float s = 0.f;
#pragma unroll
    for (int c = 0; c < NCHUNK; ++c)
      s += w[c] * po[((size_t)(bh * NCHUNK + c) * HD + d) * NQ + n];
    aop[(size_t)d * NQ] = s * inv;
  }
}

// ---------------------------------------------------------------------------
// Final: out = relu(y2*scale2[c] + shift2[c] + x)
// ---------------------------------------------------------------------------
__global__ __launch_bounds__(256) void k_final(const float* __restrict__ y2,
                                               const float* __restrict__ x,
                                               const float* __restrict__ scl,
                                               const float* __restrict__ sht,
                                               float* __restrict__ out) {
  const size_t i = ((size_t)blockIdx.x * 256 + threadIdx.x) * 4;
  const int c = (int)((i >> 10) & 511);
  const float sc = scl[c], sh = sht[c];
  float4 v  = *reinterpret_cast<const float4*>(y2 + i);
  float4 xv = *reinterpret_cast<const float4*>(x + i);
  v.x = fmaxf(v.x * sc + sh + xv.x, 0.f);
  v.y = fmaxf(v.y * sc + sh + xv.y, 0.f);
  v.z = fmaxf(v.z * sc + sh + xv.z, 0.f);
  v.w = fmaxf(v.w * sc + sh + xv.w, 0.f);
  *reinterpret_cast<float4*>(out + i) = v;
}

// ---------------------------------------------------------------------------
extern "C" void kernel_launch(void* const* d_in, const int* in_sizes, int n_in,
                              void* d_out, int out_size, void* d_ws, size_t ws_size,
                              hipStream_t stream) {
  (void)in_sizes; (void)n_in; (void)out_size; (void)ws_size;
  const float* x    = (const float*)d_in[0];
  const float* w1   = (const float*)d_in[1];
  const float* g1   = (const float*)d_in[2];
  const float* b1   = (const float*)d_in[3];
  const float* wqkv = (const float*)d_in[4];
  const float* rw   = (const float*)d_in[5];
  const float* rh   = (const float*)d_in[6];
  const float* w2   = (const float*)d_in[7];
  const float* g2   = (const float*)d_in[8];
  const float* b2   = (const float*)d_in[9];
  float* out = (float*)d_out;
  float* ws  = (float*)d_ws;

  // Workspace layout (floats).
  constexpr size_t SEG = 2097152;        // 16*128*1024
  float* y1   = ws;                      // [0, SEG)
  float* qs   = ws + SEG;                // [SEG, 2SEG)
  float* kt   = ws + 2 * SEG;            // [2SEG, 3SEG)
  float* vt   = ws + 3 * SEG;            // [3SEG, 4SEG)
  float* ao   = ws + 4 * SEG;            // [4SEG, 5SEG)
  float* po   = ws + 5 * SEG;            // [5SEG, 9SEG)  64*4*32*1024
  float* pm   = ws + 9 * SEG;            // 262144
  float* pl   = pm + 262144;             // 262144
  float* scl1 = pl + 262144;
  float* sht1 = scl1 + 128;
  float* scl2 = sht1 + 128;
  float* sht2 = scl2 + 512;
  float* y2   = ws;                      // reuses [0,4SEG) after attention

  // 1) conv1: y1 = w1 @ x                (M=128, K=512)
  k_gemm_conv<512><<<dim3(8, 2, BATCH), 256, 0, stream>>>(w1, x, y1, 128);
  // 2) bn1 stats
  k_bnstats<<<128, 256, 0, stream>>>(y1, 128, g1, b1, scl1, sht1);
  // 3) qkv = wqkv @ relu(bn1(y1)); write q*(scale*log2e), k+r, v  (n-major)
  k_gemm_qkv<<<dim3(8, 6, BATCH), 256, 0, stream>>>(wqkv, y1, scl1, sht1, rw, rh, qs, kt, vt);
  // 4) attention partials over 4 KV chunks
  k_attn_part<<<dim3(NQ / 256, NCHUNK, BATCH * HEADS), 256, 0, stream>>>(qs, kt, vt, po, pm, pl);
  // 5) combine partials
  k_attn_comb<<<dim3(NQ / 256, BATCH * HEADS), 256, 0, stream>>>(po, pm, pl, ao);
  // 6) conv2: y2 = w2 @ ao               (M=512, K=128)
  k_gemm_conv<128><<<dim3(8, 8, BATCH), 256, 0, stream>>>(w2, ao, y2, 512);
  // 7) bn2 stats
  k_bnstats<<<512, 256, 0, stream>>>(y2, 512, g2, b2, scl2, sht2);
  // 8) out = relu(bn2(y2) + x)
  k_final<<<8192, 256, 0, stream>>>(y2, x, scl2, sht2, out);
}

// Round 4
// 170.304 us; speedup vs baseline: 2.8351x; 2.0797x over previous
//
#include <hip/hip_runtime.h>
#include <cstddef>
#include <cstdint>

// Problem constants
constexpr int BATCH = 16;
constexpr int WID   = 128;   // bottleneck width
constexpr int NQ    = 1024;  // H*W
constexpr int HEADS = 4;
constexpr float QSCALE = 0.17677669529663687f * 1.4426950408889634f; // 32^-0.5 * log2e

typedef __attribute__((ext_vector_type(8))) short bf8;        // 8 bf16 (4 VGPR)
typedef __attribute__((ext_vector_type(4))) float f32x4;
typedef __attribute__((ext_vector_type(4))) unsigned short us4;
typedef __attribute__((ext_vector_type(8))) unsigned short us8;

__device__ inline unsigned short f2bf(float x) {
  union { float f; uint32_t u; } c{x};
  uint32_t r = c.u + 0x7fffu + ((c.u >> 16) & 1u);   // RNE
  return (unsigned short)(r >> 16);
}

__device__ inline float fast_exp2(float x) {
#if __has_builtin(__builtin_amdgcn_exp2f)
  return __builtin_amdgcn_exp2f(x);
#else
  return exp2f(x);
#endif
}

// ---------------------------------------------------------------------------
// Tiled fp32 GEMM: C[b][c][n] = sum_k A[c][k] * B[b][k][n]
// BM=64, BN=128, BK=16, 256 threads, 4x8 per thread. grid: (NQ/128, M/64, B)
// ---------------------------------------------------------------------------
template<int KTOT>
__global__ __launch_bounds__(256) void k_gemm_conv(const float* __restrict__ A,
                                                   const float* __restrict__ Bmat,
                                                   float* __restrict__ C, int M) {
  const int b   = blockIdx.z;
  const int c0  = blockIdx.y * 64;
  const int n0  = blockIdx.x * 128;
  const int tid = threadIdx.x;
  const int ty  = tid >> 4;
  const int tx  = tid & 15;

  __shared__ float As[16][68];
  __shared__ float Bs[16][128];

  const float* Bp = Bmat + (size_t)b * KTOT * NQ;

  float acc[4][8];
#pragma unroll
  for (int i = 0; i < 4; ++i)
#pragma unroll
    for (int j = 0; j < 8; ++j) acc[i][j] = 0.f;

  const int arow = tid >> 2;
  const int ak4  = (tid & 3) * 4;
  const int bk   = tid >> 5;
  const int bn4  = (tid & 31) * 4;

  for (int k0 = 0; k0 < KTOT; k0 += 16) {
    float4 av  = *reinterpret_cast<const float4*>(A + (size_t)(c0 + arow) * KTOT + k0 + ak4);
    float4 bv0 = *reinterpret_cast<const float4*>(Bp + (size_t)(k0 + bk    ) * NQ + n0 + bn4);
    float4 bv1 = *reinterpret_cast<const float4*>(Bp + (size_t)(k0 + bk + 8) * NQ + n0 + bn4);
    __syncthreads();
    As[ak4 + 0][arow] = av.x;
    As[ak4 + 1][arow] = av.y;
    As[ak4 + 2][arow] = av.z;
    As[ak4 + 3][arow] = av.w;
    *reinterpret_cast<float4*>(&Bs[bk    ][bn4]) = bv0;
    *reinterpret_cast<float4*>(&Bs[bk + 8][bn4]) = bv1;
    __syncthreads();
#pragma unroll
    for (int kk = 0; kk < 16; ++kk) {
      float4 a  = *reinterpret_cast<const float4*>(&As[kk][ty * 4]);
      float4 b0 = *reinterpret_cast<const float4*>(&Bs[kk][tx * 8]);
      float4 b1 = *reinterpret_cast<const float4*>(&Bs[kk][tx * 8 + 4]);
      float ar[4] = {a.x, a.y, a.z, a.w};
      float br[8] = {b0.x, b0.y, b0.z, b0.w, b1.x, b1.y, b1.z, b1.w};
#pragma unroll
      for (int i = 0; i < 4; ++i)
#pragma unroll
        for (int j = 0; j < 8; ++j) acc[i][j] += ar[i] * br[j];
    }
  }

#pragma unroll
  for (int i = 0; i < 4; ++i) {
    float4 v0 = {acc[i][0], acc[i][1], acc[i][2], acc[i][3]};
    float4 v1 = {acc[i][4], acc[i][5], acc[i][6], acc[i][7]};
    float* cp = C + ((size_t)b * M + c0 + ty * 4 + i) * NQ + n0 + tx * 8;
    *reinterpret_cast<float4*>(cp)     = v0;
    *reinterpret_cast<float4*>(cp + 4) = v1;
  }
}

// ---------------------------------------------------------------------------
// BN train-mode stats -> per-channel scale/shift.  grid = C blocks.
// ---------------------------------------------------------------------------
__global__ __launch_bounds__(256) void k_bnstats(const float* __restrict__ y, int C,
                                                 const float* __restrict__ g,
                                                 const float* __restrict__ beta,
                                                 float* __restrict__ scl,
                                                 float* __restrict__ sht) {
  const int c = blockIdx.x;
  const int tid = threadIdx.x;
  float s = 0.f, ss = 0.f;
  for (int b = 0; b < BATCH; ++b) {
    const float* p = y + ((size_t)b * C + c) * NQ;
    float4 v = *reinterpret_cast<const float4*>(p + tid * 4);
    s  += v.x + v.y + v.z + v.w;
    ss += v.x * v.x + v.y * v.y + v.z * v.z + v.w * v.w;
  }
  __shared__ float rs[256], rss[256];
  rs[tid] = s; rss[tid] = ss;
  __syncthreads();
  for (int st = 128; st > 0; st >>= 1) {
    if (tid < st) { rs[tid] += rs[tid + st]; rss[tid] += rss[tid + st]; }
    __syncthreads();
  }
  if (tid == 0) {
    const float inv_n = 1.f / (BATCH * NQ);
    float mean = rs[0] * inv_n;
    float var  = rss[0] * inv_n - mean * mean;
    float rstd = rsqrtf(var + 1e-5f);
    float sc = rstd * g[c];
    scl[c] = sc;
    sht[c] = beta[c] - mean * sc;
  }
}

// ---------------------------------------------------------------------------
// qkv GEMM: reads y1 with fused bn1+relu, A = qkv_w [384][128].
// Outputs bf16: q*(scale*log2e) at (bh,n,d); k'=k+r at (bh,n,d); v at (bh,d,n).
// grid: (NQ/128, 6, BATCH); mtile 0,1 -> q ; 2,3 -> k ; 4,5 -> v
// ---------------------------------------------------------------------------
__global__ __launch_bounds__(256) void k_gemm_qkv(const float* __restrict__ A,
                                                  const float* __restrict__ y1,
                                                  const float* __restrict__ s1,
                                                  const float* __restrict__ h1,
                                                  const float* __restrict__ rw,
                                                  const float* __restrict__ rh,
                                                  unsigned short* __restrict__ qs,
                                                  unsigned short* __restrict__ kt,
                                                  unsigned short* __restrict__ vt) {
  const int b   = blockIdx.z;
  const int mt  = blockIdx.y;
  const int c0  = mt * 64;
  const int n0  = blockIdx.x * 128;
  const int tid = threadIdx.x;
  const int ty  = tid >> 4;
  const int tx  = tid & 15;

  __shared__ float As[16][68];
  __shared__ float Bs[16][128];

  const float* Bp = y1 + (size_t)b * WID * NQ;

  float acc[4][8];
#pragma unroll
  for (int i = 0; i < 4; ++i)
#pragma unroll
    for (int j = 0; j < 8; ++j) acc[i][j] = 0.f;

  const int arow = tid >> 2;
  const int ak4  = (tid & 3) * 4;
  const int bk   = tid >> 5;
  const int bn4  = (tid & 31) * 4;

  for (int k0 = 0; k0 < WID; k0 += 16) {
    float4 av  = *reinterpret_cast<const float4*>(A + (size_t)(c0 + arow) * WID + k0 + ak4);
    const int kr0 = k0 + bk, kr1 = k0 + bk + 8;
    float4 bv0 = *reinterpret_cast<const float4*>(Bp + (size_t)kr0 * NQ + n0 + bn4);
    float4 bv1 = *reinterpret_cast<const float4*>(Bp + (size_t)kr1 * NQ + n0 + bn4);
    float sc0 = s1[kr0], sh0 = h1[kr0];
    float sc1 = s1[kr1], sh1 = h1[kr1];
    bv0.x = fmaxf(bv0.x * sc0 + sh0, 0.f);
    bv0.y = fmaxf(bv0.y * sc0 + sh0, 0.f);
    bv0.z = fmaxf(bv0.z * sc0 + sh0, 0.f);
    bv0.w = fmaxf(bv0.w * sc0 + sh0, 0.f);
    bv1.x = fmaxf(bv1.x * sc1 + sh1, 0.f);
    bv1.y = fmaxf(bv1.y * sc1 + sh1, 0.f);
    bv1.z = fmaxf(bv1.z * sc1 + sh1, 0.f);
    bv1.w = fmaxf(bv1.w * sc1 + sh1, 0.f);
    __syncthreads();
    As[ak4 + 0][arow] = av.x;
    As[ak4 + 1][arow] = av.y;
    As[ak4 + 2][arow] = av.z;
    As[ak4 + 3][arow] = av.w;
    *reinterpret_cast<float4*>(&Bs[bk    ][bn4]) = bv0;
    *reinterpret_cast<float4*>(&Bs[bk + 8][bn4]) = bv1;
    __syncthreads();
#pragma unroll
    for (int kk = 0; kk < 16; ++kk) {
      float4 a  = *reinterpret_cast<const float4*>(&As[kk][ty * 4]);
      float4 b0 = *reinterpret_cast<const float4*>(&Bs[kk][tx * 8]);
      float4 b1 = *reinterpret_cast<const float4*>(&Bs[kk][tx * 8 + 4]);
      float ar[4] = {a.x, a.y, a.z, a.w};
      float br[8] = {b0.x, b0.y, b0.z, b0.w, b1.x, b1.y, b1.z, b1.w};
#pragma unroll
      for (int i = 0; i < 4; ++i)
#pragma unroll
        for (int j = 0; j < 8; ++j) acc[i][j] += ar[i] * br[j];
    }
  }

  const int type = mt >> 1;                  // 0=q,1=k,2=v
  const int c128 = (mt & 1) * 64 + ty * 4;
  const int hh = c128 >> 5;
  const int d0 = c128 & 31;

  if (type == 2) {
    // v: transposed bf16 store, vt[bh][d][n]
    unsigned short* dst = vt + ((size_t)(b * HEADS + hh) * 32 + d0) * NQ + n0 + tx * 8;
#pragma unroll
    for (int r = 0; r < 4; ++r) {
      us8 pk;
#pragma unroll
      for (int j = 0; j < 8; ++j) pk[j] = f2bf(acc[r][j]);
      *reinterpret_cast<us8*>(dst + (size_t)r * NQ) = pk;
    }
  } else {
    unsigned short* dst = (type == 0 ? qs : kt) + (size_t)(b * HEADS + hh) * NQ * 32;
#pragma unroll
    for (int j = 0; j < 8; ++j) {
      const int n = n0 + tx * 8 + j;
      float v0 = acc[0][j], v1 = acc[1][j], v2 = acc[2][j], v3 = acc[3][j];
      if (type == 0) {
        v0 *= QSCALE; v1 *= QSCALE; v2 *= QSCALE; v3 *= QSCALE;
      } else {
        const int wcol = n & 31, hrow = n >> 5;
        v0 += rw[(hh * 32 + d0 + 0) * 32 + wcol] + rh[(hh * 32 + d0 + 0) * 32 + hrow];
        v1 += rw[(hh * 32 + d0 + 1) * 32 + wcol] + rh[(hh * 32 + d0 + 1) * 32 + hrow];
        v2 += rw[(hh * 32 + d0 + 2) * 32 + wcol] + rh[(hh * 32 + d0 + 2) * 32 + hrow];
        v3 += rw[(hh * 32 + d0 + 3) * 32 + wcol] + rh[(hh * 32 + d0 + 3) * 32 + hrow];
      }
      us4 pk = {f2bf(v0), f2bf(v1), f2bf(v2), f2bf(v3)};
      *reinterpret_cast<us4*>(dst + (size_t)n * 32 + d0) = pk;
    }
  }
}

// ---------------------------------------------------------------------------
// MFMA flash attention (swapped operands). Block = 4 waves x 16 queries.
// grid: (NQ/64, BATCH*HEADS), 256 threads.
// S^T = mfma(Kfrag, Qfrag): lane holds 16 scores of ONE query (lane&15).
// PV: O^T = mfma(V^T frag, P^T frag); P^T redistributed via cvt_pk + shfl.
// ---------------------------------------------------------------------------
__global__ __launch_bounds__(256) void k_attn_mfma(const unsigned short* __restrict__ qs,
                                                   const unsigned short* __restrict__ kt,
                                                   const unsigned short* __restrict__ vt,
                                                   float* __restrict__ ao) {
  const int bh   = blockIdx.y;
  const int tid  = threadIdx.x;
  const int lane = tid & 63;
  const int wv   = tid >> 6;
  const int i    = lane & 15;      // query index within wave tile
  const int g    = lane >> 4;      // lane group 0..3
  const int n0w  = blockIdx.x * 64 + wv * 16;

  __shared__ unsigned short Ks[64 * 56];   // [key][d], stride 56
  __shared__ unsigned short Vt[32 * 72];   // [d][key], stride 72

  const bf8 qf = *reinterpret_cast<const bf8*>(
      qs + ((size_t)bh * NQ + n0w + i) * 32 + g * 8);

  f32x4 o0 = {0.f, 0.f, 0.f, 0.f}, o1 = {0.f, 0.f, 0.f, 0.f};
  float m = -1e30f, lsum = 0.f;

  const unsigned short* kb = kt + (size_t)bh * NQ * 32;
  const unsigned short* vb = vt + (size_t)bh * 32 * NQ;

  const int skey = tid >> 2, sds = (tid & 3) * 8;  // K staging coords
  const int svd  = tid >> 3, svn = (tid & 7) * 8;  // V staging coords

  for (int k0 = 0; k0 < NQ; k0 += 64) {
    bf8 kvld = *reinterpret_cast<const bf8*>(kb + (size_t)(k0 + skey) * 32 + sds);
    bf8 vvld = *reinterpret_cast<const bf8*>(vb + (size_t)svd * NQ + k0 + svn);
    __syncthreads();
    *reinterpret_cast<bf8*>(&Ks[skey * 56 + sds]) = kvld;
    *reinterpret_cast<bf8*>(&Vt[svd * 72 + svn])  = vvld;
    __syncthreads();

    // QK^T (transposed): 4 key-tiles of 16
    f32x4 st[4];
    const f32x4 zero = {0.f, 0.f, 0.f, 0.f};
#pragma unroll
    for (int t = 0; t < 4; ++t) {
      bf8 kf = *reinterpret_cast<const bf8*>(&Ks[(t * 16 + i) * 56 + g * 8]);
      st[t] = __builtin_amdgcn_mfma_f32_16x16x32_bf16(kf, qf, zero, 0, 0, 0);
    }

    // online softmax (base-2), per-query state is lane-scalar
    float tmax = st[0][0];
#pragma unroll
    for (int t = 0; t < 4; ++t)
#pragma unroll
      for (int r = 0; r < 4; ++r) tmax = fmaxf(tmax, st[t][r]);
    tmax = fmaxf(tmax, __shfl_xor(tmax, 16));
    tmax = fmaxf(tmax, __shfl_xor(tmax, 32));

    const float mn   = fmaxf(m, tmax);
    const float corr = fast_exp2(m - mn);
    m = mn;

    float ps = 0.f;
    unsigned int pk[4][2];
#pragma unroll
    for (int t = 0; t < 4; ++t) {
      float p0 = fast_exp2(st[t][0] - mn);
      float p1 = fast_exp2(st[t][1] - mn);
      float p2 = fast_exp2(st[t][2] - mn);
      float p3 = fast_exp2(st[t][3] - mn);
      ps += (p0 + p1) + (p2 + p3);
      unsigned int pa, pb;
      asm("v_cvt_pk_bf16_f32 %0, %1, %2" : "=v"(pa) : "v"(p0), "v"(p1));
      asm("v_cvt_pk_bf16_f32 %0, %1, %2" : "=v"(pb) : "v"(p2), "v"(p3));
      pk[t][0] = pa; pk[t][1] = pb;
    }
    ps += __shfl_xor(ps, 16);
    ps += __shfl_xor(ps, 32);
    lsum = lsum * corr + ps;
#pragma unroll
    for (int r = 0; r < 4; ++r) { o0[r] *= corr; o1[r] *= corr; }

    // redistribute P^T into B-fragments and do PV
    const int src0 = ((g & 1) << 5) + i;
    const int src1 = src0 + 16;
    const bool hi = (g >= 2);
#pragma unroll
    for (int s = 0; s < 2; ++s) {
      int a0 = __shfl((int)pk[2 * s][0], src0);
      int a1 = __shfl((int)pk[2 * s][1], src0);
      int a2 = __shfl((int)pk[2 * s][0], src1);
      int a3 = __shfl((int)pk[2 * s][1], src1);
      int b0 = __shfl((int)pk[2 * s + 1][0], src0);
      int b1 = __shfl((int)pk[2 * s + 1][1], src0);
      int b2 = __shfl((int)pk[2 * s + 1][0], src1);
      int b3 = __shfl((int)pk[2 * s + 1][1], src1);
      union { int d[4]; bf8 v; } pf;
      pf.d[0] = hi ? b0 : a0;
      pf.d[1] = hi ? b1 : a1;
      pf.d[2] = hi ? b2 : a2;
      pf.d[3] = hi ? b3 : a3;
      bf8 vf0 = *reinterpret_cast<const bf8*>(&Vt[(i)      * 72 + s * 32 + g * 8]);
      bf8 vf1 = *reinterpret_cast<const bf8*>(&Vt[(16 + i) * 72 + s * 32 + g * 8]);
      o0 = __builtin_amdgcn_mfma_f32_16x16x32_bf16(vf0, pf.v, o0, 0, 0, 0);
      o1 = __builtin_amdgcn_mfma_f32_16x16x32_bf16(vf1, pf.v, o1, 0, 0, 0);
    }
  }

  const float inv = 1.f / lsum;
  // O^T lane layout: d = dt*16 + 4g + r, q = i
  float* aob = ao + ((size_t)(bh >> 2) * WID + (bh & 3) * 32) * NQ + n0w + i;
#pragma unroll
  for (int r = 0; r < 4; ++r) {
    aob[(size_t)(4 * g + r) * NQ]      = o0[r] * inv;
    aob[(size_t)(16 + 4 * g + r) * NQ] = o1[r] * inv;
  }
}

// ---------------------------------------------------------------------------
// Final: out = relu(y2*scale2[c] + shift2[c] + x)
// ---------------------------------------------------------------------------
__global__ __launch_bounds__(256) void k_final(const float* __restrict__ y2,
                                               const float* __restrict__ x,
                                               const float* __restrict__ scl,
                                               const float* __restrict__ sht,
                                               float* __restrict__ out) {
  const size_t i = ((size_t)blockIdx.x * 256 + threadIdx.x) * 4;
  const int c = (int)((i >> 10) & 511);
  const float sc = scl[c], sh = sht[c];
  float4 v  = *reinterpret_cast<const float4*>(y2 + i);
  float4 xv = *reinterpret_cast<const float4*>(x + i);
  v.x = fmaxf(v.x * sc + sh + xv.x, 0.f);
  v.y = fmaxf(v.y * sc + sh + xv.y, 0.f);
  v.z = fmaxf(v.z * sc + sh + xv.z, 0.f);
  v.w = fmaxf(v.w * sc + sh + xv.w, 0.f);
  *reinterpret_cast<float4*>(out + i) = v;
}

// ---------------------------------------------------------------------------
extern "C" void kernel_launch(void* const* d_in, const int* in_sizes, int n_in,
                              void* d_out, int out_size, void* d_ws, size_t ws_size,
                              hipStream_t stream) {
  (void)in_sizes; (void)n_in; (void)out_size; (void)ws_size;
  const float* x    = (const float*)d_in[0];
  const float* w1   = (const float*)d_in[1];
  const float* g1   = (const float*)d_in[2];
  const float* b1   = (const float*)d_in[3];
  const float* wqkv = (const float*)d_in[4];
  const float* rw   = (const float*)d_in[5];
  const float* rh   = (const float*)d_in[6];
  const float* w2   = (const float*)d_in[7];
  const float* g2   = (const float*)d_in[8];
  const float* b2   = (const float*)d_in[9];
  float* out = (float*)d_out;
  char* base = (char*)d_ws;

  // Workspace layout (bytes):
  //   y1: [0,8MB)  qs: [8,12) kt: [12,16) vt: [16,20) ao: [20,28)
  //   y2: [28,60)  (16*512*1024 fp32 = 32MB!)  scalars: [60MB, ...)
  float*          y1   = (float*)(base);
  unsigned short* qs   = (unsigned short*)(base + (8u  << 20));
  unsigned short* kt   = (unsigned short*)(base + (12u << 20));
  unsigned short* vt   = (unsigned short*)(base + (16u << 20));
  float*          ao   = (float*)(base + (20u << 20));
  float*          y2   = (float*)(base + (28u << 20));
  float*          scl1 = (float*)(base + (60u << 20));   // PAST y2's end
  float*          sht1 = scl1 + 128;
  float*          scl2 = sht1 + 128;
  float*          sht2 = scl2 + 512;

  // 1) conv1: y1 = w1 @ x                (M=128, K=512)
  k_gemm_conv<512><<<dim3(8, 2, BATCH), 256, 0, stream>>>(w1, x, y1, 128);
  // 2) bn1 stats
  k_bnstats<<<128, 256, 0, stream>>>(y1, 128, g1, b1, scl1, sht1);
  // 3) qkv with fused bn1+relu; bf16 outputs q/k'(n,d), v(d,n)
  k_gemm_qkv<<<dim3(8, 6, BATCH), 256, 0, stream>>>(wqkv, y1, scl1, sht1, rw, rh, qs, kt, vt);
  // 4) MFMA flash attention -> ao (fp32, (b,128,1024))
  k_attn_mfma<<<dim3(NQ / 64, BATCH * HEADS), 256, 0, stream>>>(qs, kt, vt, ao);
  // 5) conv2: y2 = w2 @ ao               (M=512, K=128)
  k_gemm_conv<128><<<dim3(8, 8, BATCH), 256, 0, stream>>>(w2, ao, y2, 512);
  // 6) bn2 stats
  k_bnstats<<<512, 256, 0, stream>>>(y2, 512, g2, b2, scl2, sht2);
  // 7) out = relu(bn2(y2) + x)
  k_final<<<8192, 256, 0, stream>>>(y2, x, scl2, sht2, out);
}

// Round 6
// 127.294 us; speedup vs baseline: 3.7930x; 1.3379x over previous
//
#include <hip/hip_runtime.h>
#include <cstddef>
#include <cstdint>

constexpr int BATCH = 16;
constexpr int NQ    = 1024;
constexpr float QSCALE = 0.17677669529663687f * 1.4426950408889634f; // 32^-0.5 * log2e

typedef __attribute__((ext_vector_type(8))) short bf8;            // MFMA operand (8 bf16)
typedef __attribute__((ext_vector_type(4))) float f32x4;
typedef __attribute__((ext_vector_type(4))) unsigned short us4;
typedef __attribute__((ext_vector_type(8))) unsigned short us8;

__device__ inline unsigned short f2bf(float x) {
  union { float f; uint32_t u; } c{x};
  uint32_t r = c.u + 0x7fffu + ((c.u >> 16) & 1u);   // RNE
  return (unsigned short)(r >> 16);
}
__device__ inline float b2f(unsigned short v) {
  union { uint32_t u; float f; } c{(uint32_t)v << 16};
  return c.f;
}
__device__ inline float fast_exp2(float x) {
#if __has_builtin(__builtin_amdgcn_exp2f)
  return __builtin_amdgcn_exp2f(x);
#else
  return exp2f(x);
#endif
}

// ---------------------------------------------------------------------------
// Convert the three weight tensors to bf16.
// ---------------------------------------------------------------------------
__global__ __launch_bounds__(256) void k_wcvt(const float* __restrict__ w1,
                                              const float* __restrict__ wq,
                                              const float* __restrict__ w2,
                                              unsigned short* __restrict__ o1,
                                              unsigned short* __restrict__ oq,
                                              unsigned short* __restrict__ o2) {
  int idx = (blockIdx.x * 256 + threadIdx.x) * 8;
  const float* s; unsigned short* d; int off;
  if (idx < 65536)        { s = w1; d = o1; off = idx; }
  else if (idx < 114688)  { s = wq; d = oq; off = idx - 65536; }
  else                    { s = w2; d = o2; off = idx - 114688; }
  float4 a = *(const float4*)(s + off);
  float4 b = *(const float4*)(s + off + 4);
  us8 o = {f2bf(a.x), f2bf(a.y), f2bf(a.z), f2bf(a.w),
           f2bf(b.x), f2bf(b.y), f2bf(b.z), f2bf(b.w)};
  *(us8*)(d + off) = o;
}

// ---------------------------------------------------------------------------
// Transpose x [b][512][1024] fp32 -> xT [b][1024][512] bf16.
// ---------------------------------------------------------------------------
__global__ __launch_bounds__(256) void k_xpose(const float* __restrict__ x,
                                               unsigned short* __restrict__ xT) {
  __shared__ unsigned short t2[64 * 68];
  const int bb = blockIdx.z, c0 = blockIdx.y * 64, n0 = blockIdx.x * 64;
  const int t = threadIdx.x;
  const int n4 = t & 15, cg = t >> 4;

  float4 rv[4];
#pragma unroll
  for (int r = 0; r < 4; ++r)
    rv[r] = *(const float4*)(x + (((size_t)(bb * 512 + c0 + cg * 4 + r)) << 10) + n0 + n4 * 4);
#pragma unroll
  for (int j = 0; j < 4; ++j) {
    us4 pk = {f2bf((&rv[0].x)[j]), f2bf((&rv[1].x)[j]),
              f2bf((&rv[2].x)[j]), f2bf((&rv[3].x)[j])};
    *(us4*)&t2[(n4 * 4 + j) * 68 + cg * 4] = pk;
  }
  __syncthreads();
  const int cc = t & 7, nn = t >> 3;
#pragma unroll
  for (int p = 0; p < 2; ++p) {
    const int n = nn + p * 32;
    us4 lo = *(const us4*)&t2[n * 68 + cc * 8];
    us4 hi = *(const us4*)&t2[n * 68 + cc * 8 + 4];
    us8 o = {lo[0], lo[1], lo[2], lo[3], hi[0], hi[1], hi[2], hi[3]};
    *(us8*)(xT + ((size_t)(bb << 10) + n0 + n) * 512 + c0 + cc * 8) = o;
  }
}

// ---------------------------------------------------------------------------
// bf16 MFMA GEMM (conv1 / qkv). Block tile 128n x 64m, 4 waves (2n x 2m).
// MODE 0: conv1 (KTOT=512) -> y1T[b][n][128] bf16
// MODE 1: qkv  (KTOT=128, bn1+relu fused); mt 0,1=q 2,3=k 4,5=v
// ---------------------------------------------------------------------------
template<int KTOT, int MODE>
__global__ __launch_bounds__(256) void k_mm(const unsigned short* __restrict__ W,
                                            const unsigned short* __restrict__ Bact,
                                            const float* __restrict__ scl,
                                            const float* __restrict__ sht,
                                            const float* __restrict__ rw,
                                            const float* __restrict__ rh,
                                            unsigned short* __restrict__ out0,
                                            unsigned short* __restrict__ out1,
                                            unsigned short* __restrict__ out2) {
  constexpr int BS = (KTOT == 128) ? 136 : 72;   // LDS row stride (bf16)
  __shared__ unsigned short Blds[128 * BS];
  __shared__ float scl_s[128], sht_s[128];

  const int bb = blockIdx.z, mt = blockIdx.y;
  const int n0 = blockIdx.x * 128, m0 = mt * 64;
  const int tid = threadIdx.x, lane = tid & 63, wv = tid >> 6;
  const int wn = wv & 1, wm = wv >> 1;
  const int i = lane & 15, g = lane >> 4;

  const unsigned short* Bp = Bact + ((size_t)bb * NQ + n0) * KTOT;

  f32x4 acc[4][2];
#pragma unroll
  for (int a = 0; a < 4; ++a)
#pragma unroll
    for (int b = 0; b < 2; ++b) acc[a][b] = {0.f, 0.f, 0.f, 0.f};

  const int sn = tid >> 1;        // staging row
  const int sk = (tid & 1) * 8;   // staging k base

  if constexpr (KTOT == 128) {
    if constexpr (MODE == 1) {
      if (tid < 128) { scl_s[tid] = scl[tid]; sht_s[tid] = sht[tid]; }
    }
    bf8 wf[2][4];
#pragma unroll
    for (int b = 0; b < 2; ++b)
#pragma unroll
      for (int h = 0; h < 4; ++h)
        wf[b][h] = *(const bf8*)(W + (size_t)(m0 + wm * 32 + b * 16 + i) * 128 + h * 32 + g * 8);
    if constexpr (MODE == 1) __syncthreads();
#pragma unroll
    for (int p = 0; p < 8; ++p) {
      us8 v = *(const us8*)(Bp + (size_t)sn * 128 + sk + p * 16);
      if constexpr (MODE == 1) {
        const int kb = sk + p * 16;
        float scv[8], shv[8];
        *(float4*)scv = *(const float4*)&scl_s[kb];
        *(float4*)(scv + 4) = *(const float4*)&scl_s[kb + 4];
        *(float4*)shv = *(const float4*)&sht_s[kb];
        *(float4*)(shv + 4) = *(const float4*)&sht_s[kb + 4];
#pragma unroll
        for (int j = 0; j < 8; ++j)
          v[j] = f2bf(fmaxf(fmaf(b2f(v[j]), scv[j], shv[j]), 0.f));
      }
      *(us8*)(&Blds[sn * BS + sk + p * 16]) = v;
    }
    __syncthreads();

    const bool actA = (MODE == 1 && mt >= 4);
    if (actA) {
#pragma unroll
      for (int h = 0; h < 4; ++h) {
        bf8 af[4];
#pragma unroll
        for (int a = 0; a < 4; ++a)
          af[a] = *(const bf8*)&Blds[(wn * 64 + a * 16 + i) * BS + h * 32 + g * 8];
#pragma unroll
        for (int a = 0; a < 4; ++a)
#pragma unroll
          for (int b = 0; b < 2; ++b)
            acc[a][b] = __builtin_amdgcn_mfma_f32_16x16x32_bf16(af[a], wf[b][h], acc[a][b], 0, 0, 0);
      }
    } else {
#pragma unroll
      for (int h = 0; h < 4; ++h) {
        bf8 af[4];
#pragma unroll
        for (int a = 0; a < 4; ++a)
          af[a] = *(const bf8*)&Blds[(wn * 64 + a * 16 + i) * BS + h * 32 + g * 8];
#pragma unroll
        for (int a = 0; a < 4; ++a)
#pragma unroll
          for (int b = 0; b < 2; ++b)
            acc[a][b] = __builtin_amdgcn_mfma_f32_16x16x32_bf16(wf[b][h], af[a], acc[a][b], 0, 0, 0);
      }
    }
  } else {
    // KTOT = 512 (conv1)
    us8 breg[4];
#pragma unroll
    for (int p = 0; p < 4; ++p)
      breg[p] = *(const us8*)(Bp + (size_t)sn * 512 + sk + p * 16);
    for (int s = 0; s < 8; ++s) {
      bf8 wf[2][2];
#pragma unroll
      for (int b = 0; b < 2; ++b)
#pragma unroll
        for (int h = 0; h < 2; ++h)
          wf[b][h] = *(const bf8*)(W + (size_t)(m0 + wm * 32 + b * 16 + i) * 512 + s * 64 + h * 32 + g * 8);
      __syncthreads();
#pragma unroll
      for (int p = 0; p < 4; ++p)
        *(us8*)(&Blds[sn * BS + sk + p * 16]) = breg[p];
      __syncthreads();
      if (s < 7) {
#pragma unroll
        for (int p = 0; p < 4; ++p)
          breg[p] = *(const us8*)(Bp + (size_t)sn * 512 + (s + 1) * 64 + sk + p * 16);
      }
#pragma unroll
      for (int h = 0; h < 2; ++h) {
        bf8 af[4];
#pragma unroll
        for (int a = 0; a < 4; ++a)
          af[a] = *(const bf8*)&Blds[(wn * 64 + a * 16 + i) * BS + h * 32 + g * 8];
#pragma unroll
        for (int a = 0; a < 4; ++a)
#pragma unroll
          for (int b = 0; b < 2; ++b)
            acc[a][b] = __builtin_amdgcn_mfma_f32_16x16x32_bf16(wf[b][h], af[a], acc[a][b], 0, 0, 0);
      }
    }
  }

  // ------------------------------ epilogues ------------------------------
  if constexpr (MODE == 0) {
    // y1T[b][n][128], D: c-run (4g+r), n = lane i
#pragma unroll
    for (int a = 0; a < 4; ++a)
#pragma unroll
      for (int b = 0; b < 2; ++b) {
        const int n = n0 + wn * 64 + a * 16 + i;
        const int c = m0 + wm * 32 + b * 16 + 4 * g;
        us4 pk = {f2bf(acc[a][b][0]), f2bf(acc[a][b][1]), f2bf(acc[a][b][2]), f2bf(acc[a][b][3])};
        *(us4*)(out0 + ((size_t)(bb << 10) + n) * 128 + c) = pk;
      }
  } else {
    if (mt < 2) {           // q: [bh][n][32], scaled
#pragma unroll
      for (int a = 0; a < 4; ++a)
#pragma unroll
        for (int b = 0; b < 2; ++b) {
          const int n = n0 + wn * 64 + a * 16 + i;
          const int c = m0 + wm * 32 + b * 16 + 4 * g;
          const int hh = c >> 5, d = c & 31;
          us4 pk = {f2bf(acc[a][b][0] * QSCALE), f2bf(acc[a][b][1] * QSCALE),
                    f2bf(acc[a][b][2] * QSCALE), f2bf(acc[a][b][3] * QSCALE)};
          *(us4*)(out0 + (((size_t)(bb * 4 + hh) << 10) + n) * 32 + d) = pk;
        }
    } else if (mt < 4) {    // k: [bh][n][32], + r bias
#pragma unroll
      for (int a = 0; a < 4; ++a)
#pragma unroll
        for (int b = 0; b < 2; ++b) {
          const int n = n0 + wn * 64 + a * 16 + i;
          const int c = (m0 - 128) + wm * 32 + b * 16 + 4 * g;
          const int hh = c >> 5, d = c & 31;
          const int wcol = n & 31, hrow = n >> 5;
          float vv[4];
#pragma unroll
          for (int r = 0; r < 4; ++r)
            vv[r] = acc[a][b][r] + rw[(c + r) * 32 + wcol] + rh[(c + r) * 32 + hrow];
          us4 pk = {f2bf(vv[0]), f2bf(vv[1]), f2bf(vv[2]), f2bf(vv[3])};
          *(us4*)(out1 + (((size_t)(bb * 4 + hh) << 10) + n) * 32 + d) = pk;
        }
    } else {                // v: [bh][32][1024] (n-run per lane)
#pragma unroll
      for (int a = 0; a < 4; ++a)
#pragma unroll
        for (int b = 0; b < 2; ++b) {
          const int c = (m0 - 256) + wm * 32 + b * 16 + i;
          const int nb = n0 + wn * 64 + a * 16 + 4 * g;
          const int hh = c >> 5, dd = c & 31;
          us4 pk = {f2bf(acc[a][b][0]), f2bf(acc[a][b][1]), f2bf(acc[a][b][2]), f2bf(acc[a][b][3])};
          *(us4*)(out2 + (((size_t)(bb * 4 + hh) * 32 + dd) << 10) + nb) = pk;
        }
    }
  }
}

// ---------------------------------------------------------------------------
// conv2, split-precision: ao (fp32) -> hi/lo bf16 pair, y2 = w2*hi + w2*lo
// accumulated fp32 -> y2 fp32.  Block 64n x 64m, 4 waves (2n x 2m).
// grid (16, 8, 16).
// ---------------------------------------------------------------------------
__global__ __launch_bounds__(256) void k_mm2(const unsigned short* __restrict__ W,
                                             const float* __restrict__ Aof,
                                             float* __restrict__ y2) {
  constexpr int BS = 264;                    // 128 hi | 128 lo | 8 pad
  __shared__ unsigned short Blds[64 * BS];   // 33792 B
  const int bb = blockIdx.z;
  const int n0 = blockIdx.x * 64, m0 = blockIdx.y * 64;
  const int tid = threadIdx.x, lane = tid & 63, wv = tid >> 6;
  const int wn = wv & 1, wm = wv >> 1;
  const int i = lane & 15, g = lane >> 4;

  bf8 wf[2][4];
#pragma unroll
  for (int b = 0; b < 2; ++b)
#pragma unroll
    for (int h = 0; h < 4; ++h)
      wf[b][h] = *(const bf8*)(W + (size_t)(m0 + wm * 32 + b * 16 + i) * 128 + h * 32 + g * 8);

  const int sn = tid >> 2, sk = (tid & 3) * 32;
  const float* src = Aof + (((size_t)(bb << 10)) + n0 + sn) * 128 + sk;
#pragma unroll
  for (int p = 0; p < 4; ++p) {
    float4 f0 = *(const float4*)(src + p * 8);
    float4 f1 = *(const float4*)(src + p * 8 + 4);
    float fv[8] = {f0.x, f0.y, f0.z, f0.w, f1.x, f1.y, f1.z, f1.w};
    us8 hi, lo;
#pragma unroll
    for (int j = 0; j < 8; ++j) {
      unsigned short h16 = f2bf(fv[j]);
      hi[j] = h16;
      lo[j] = f2bf(fv[j] - b2f(h16));
    }
    *(us8*)&Blds[sn * BS + sk + p * 8]       = hi;
    *(us8*)&Blds[sn * BS + 128 + sk + p * 8] = lo;
  }
  __syncthreads();

  f32x4 acc[2][2];
#pragma unroll
  for (int a = 0; a < 2; ++a)
#pragma unroll
    for (int b = 0; b < 2; ++b) acc[a][b] = {0.f, 0.f, 0.f, 0.f};

#pragma unroll
  for (int h = 0; h < 4; ++h) {
    bf8 ah[2], al[2];
#pragma unroll
    for (int a = 0; a < 2; ++a) {
      ah[a] = *(const bf8*)&Blds[(wn * 32 + a * 16 + i) * BS + h * 32 + g * 8];
      al[a] = *(const bf8*)&Blds[(wn * 32 + a * 16 + i) * BS + 128 + h * 32 + g * 8];
    }
#pragma unroll
    for (int a = 0; a < 2; ++a)
#pragma unroll
      for (int b = 0; b < 2; ++b) {
        acc[a][b] = __builtin_amdgcn_mfma_f32_16x16x32_bf16(ah[a], wf[b][h], acc[a][b], 0, 0, 0);
        acc[a][b] = __builtin_amdgcn_mfma_f32_16x16x32_bf16(al[a], wf[b][h], acc[a][b], 0, 0, 0);
      }
  }

  // D: n-run (4g+r), c = lane i  -> y2[b][512][1024] fp32
#pragma unroll
  for (int a = 0; a < 2; ++a)
#pragma unroll
    for (int b = 0; b < 2; ++b) {
      const int c = m0 + wm * 32 + b * 16 + i;
      const int nb = n0 + wn * 32 + a * 16 + 4 * g;
      *(f32x4*)(y2 + (((size_t)(bb * 512 + c)) << 10) + nb) = acc[a][b];
    }
}

// ---------------------------------------------------------------------------
// bn1 stats over y1T [16384 rows][128 c] bf16.
// ---------------------------------------------------------------------------
__global__ __launch_bounds__(256) void k_bnstat1a(const unsigned short* __restrict__ y1T,
                                                  float* __restrict__ pS,
                                                  float* __restrict__ pQ) {
  const int blk = blockIdx.x, t = threadIdx.x;
  const int rr = t >> 4, co = t & 15;
  float s[8], q[8];
#pragma unroll
  for (int j = 0; j < 8; ++j) { s[j] = 0.f; q[j] = 0.f; }
  for (int it = 0; it < 16; ++it) {
    const int r = blk * 256 + rr + it * 16;
    us8 v = *(const us8*)(y1T + (size_t)r * 128 + co * 8);
#pragma unroll
    for (int j = 0; j < 8; ++j) { float f = b2f(v[j]); s[j] += f; q[j] += f * f; }
  }
  __shared__ float rs[16][16][8], rq[16][16][8];
#pragma unroll
  for (int j = 0; j < 8; ++j) { rs[rr][co][j] = s[j]; rq[rr][co][j] = q[j]; }
  __syncthreads();
  if (t < 128) {
    const int c = t;
    float S = 0.f, Q = 0.f;
    for (int r2 = 0; r2 < 16; ++r2) { S += rs[r2][c >> 3][c & 7]; Q += rq[r2][c >> 3][c & 7]; }
    pS[c * 64 + blk] = S;
    pQ[c * 64 + blk] = Q;
  }
}

__global__ __launch_bounds__(128) void k_bnfin1(const float* __restrict__ pS,
                                                const float* __restrict__ pQ,
                                                const float* __restrict__ g,
                                                const float* __restrict__ be,
                                                float* __restrict__ scl,
                                                float* __restrict__ sht) {
  const int c = threadIdx.x;
  float S = 0.f, Q = 0.f;
  for (int k = 0; k < 64; ++k) { S += pS[c * 64 + k]; Q += pQ[c * 64 + k]; }
  const float inv_n = 1.f / 16384.f;
  const float mean = S * inv_n, var = Q * inv_n - mean * mean;
  const float sc = rsqrtf(var + 1e-5f) * g[c];
  scl[c] = sc;
  sht[c] = be[c] - mean * sc;
}

// ---------------------------------------------------------------------------
// bn2 stats: one block per channel over y2[b][512][1024] fp32.
// ---------------------------------------------------------------------------
__global__ __launch_bounds__(256) void k_bnstat2(const float* __restrict__ y2,
                                                 const float* __restrict__ g,
                                                 const float* __restrict__ be,
                                                 float* __restrict__ scl,
                                                 float* __restrict__ sht) {
  const int c = blockIdx.x, t = threadIdx.x;
  float s = 0.f, q = 0.f;
  for (int it = 0; it < 8; ++it) {
    const int bbb = (t >> 7) + it * 2;
    const float* p = y2 + (((size_t)(bbb * 512 + c)) << 10) + (t & 127) * 8;
    float4 v0 = *(const float4*)p;
    float4 v1 = *(const float4*)(p + 4);
    s += (v0.x + v0.y) + (v0.z + v0.w) + (v1.x + v1.y) + (v1.z + v1.w);
    q += v0.x * v0.x + v0.y * v0.y + v0.z * v0.z + v0.w * v0.w
       + v1.x * v1.x + v1.y * v1.y + v1.z * v1.z + v1.w * v1.w;
  }
  __shared__ float ls[256], lq[256];
  ls[t] = s; lq[t] = q;
  __syncthreads();
  for (int st = 128; st > 0; st >>= 1) {
    if (t < st) { ls[t] += ls[t + st]; lq[t] += lq[t + st]; }
    __syncthreads();
  }
  if (t == 0) {
    const float inv_n = 1.f / 16384.f;
    const float mean = ls[0] * inv_n, var = lq[0] * inv_n - mean * mean;
    const float sc = rsqrtf(var + 1e-5f) * g[c];
    scl[c] = sc;
    sht[c] = be[c] - mean * sc;
  }
}

// ---------------------------------------------------------------------------
// MFMA flash attention (r4-proven core); epilogue writes fp32 aoT [b][n][128].
// ---------------------------------------------------------------------------
__global__ __launch_bounds__(256) void k_attn_mfma(const unsigned short* __restrict__ qs,
                                                   const unsigned short* __restrict__ kt,
                                                   const unsigned short* __restrict__ vt,
                                                   float* __restrict__ aoT) {
  const int bh   = blockIdx.y;
  const int tid  = threadIdx.x;
  const int lane = tid & 63;
  const int wv   = tid >> 6;
  const int i    = lane & 15;
  const int g    = lane >> 4;
  const int n0w  = blockIdx.x * 64 + wv * 16;

  __shared__ unsigned short Ks[64 * 56];
  __shared__ unsigned short Vt[32 * 72];

  const bf8 qf = *reinterpret_cast<const bf8*>(
      qs + ((size_t)bh * NQ + n0w + i) * 32 + g * 8);

  f32x4 o0 = {0.f, 0.f, 0.f, 0.f}, o1 = {0.f, 0.f, 0.f, 0.f};
  float m = -1e30f, lsum = 0.f;

  const unsigned short* kb = kt + (size_t)bh * NQ * 32;
  const unsigned short* vb = vt + (size_t)bh * 32 * NQ;

  const int skey = tid >> 2, sds = (tid & 3) * 8;
  const int svd  = tid >> 3, svn = (tid & 7) * 8;

  for (int k0 = 0; k0 < NQ; k0 += 64) {
    bf8 kvld = *reinterpret_cast<const bf8*>(kb + (size_t)(k0 + skey) * 32 + sds);
    bf8 vvld = *reinterpret_cast<const bf8*>(vb + (size_t)svd * NQ + k0 + svn);
    __syncthreads();
    *reinterpret_cast<bf8*>(&Ks[skey * 56 + sds]) = kvld;
    *reinterpret_cast<bf8*>(&Vt[svd * 72 + svn])  = vvld;
    __syncthreads();

    f32x4 st[4];
    const f32x4 zero = {0.f, 0.f, 0.f, 0.f};
#pragma unroll
    for (int t = 0; t < 4; ++t) {
      bf8 kf = *reinterpret_cast<const bf8*>(&Ks[(t * 16 + i) * 56 + g * 8]);
      st[t] = __builtin_amdgcn_mfma_f32_16x16x32_bf16(kf, qf, zero, 0, 0, 0);
    }

    float tmax = st[0][0];
#pragma unroll
    for (int t = 0; t < 4; ++t)
#pragma unroll
      for (int r = 0; r < 4; ++r) tmax = fmaxf(tmax, st[t][r]);
    tmax = fmaxf(tmax, __shfl_xor(tmax, 16));
    tmax = fmaxf(tmax, __shfl_xor(tmax, 32));

    const float mn   = fmaxf(m, tmax);
    const float corr = fast_exp2(m - mn);
    m = mn;

    float ps = 0.f;
    unsigned int pk[4][2];
#pragma unroll
    for (int t = 0; t < 4; ++t) {
      float p0 = fast_exp2(st[t][0] - mn);
      float p1 = fast_exp2(st[t][1] - mn);
      float p2 = fast_exp2(st[t][2] - mn);
      float p3 = fast_exp2(st[t][3] - mn);
      ps += (p0 + p1) + (p2 + p3);
      unsigned int pa, pb;
      asm("v_cvt_pk_bf16_f32 %0, %1, %2" : "=v"(pa) : "v"(p0), "v"(p1));
      asm("v_cvt_pk_bf16_f32 %0, %1, %2" : "=v"(pb) : "v"(p2), "v"(p3));
      pk[t][0] = pa; pk[t][1] = pb;
    }
    ps += __shfl_xor(ps, 16);
    ps += __shfl_xor(ps, 32);
    lsum = lsum * corr + ps;
#pragma unroll
    for (int r = 0; r < 4; ++r) { o0[r] *= corr; o1[r] *= corr; }

    const int src0 = ((g & 1) << 5) + i;
    const int src1 = src0 + 16;
    const bool hi = (g >= 2);
#pragma unroll
    for (int s = 0; s < 2; ++s) {
      int a0 = __shfl((int)pk[2 * s][0], src0);
      int a1 = __shfl((int)pk[2 * s][1], src0);
      int a2 = __shfl((int)pk[2 * s][0], src1);
      int a3 = __shfl((int)pk[2 * s][1], src1);
      int b0 = __shfl((int)pk[2 * s + 1][0], src0);
      int b1 = __shfl((int)pk[2 * s + 1][1], src0);
      int b2 = __shfl((int)pk[2 * s + 1][0], src1);
      int b3 = __shfl((int)pk[2 * s + 1][1], src1);
      union { int d[4]; bf8 v; } pf;
      pf.d[0] = hi ? b0 : a0;
      pf.d[1] = hi ? b1 : a1;
      pf.d[2] = hi ? b2 : a2;
      pf.d[3] = hi ? b3 : a3;
      bf8 vf0 = *reinterpret_cast<const bf8*>(&Vt[(i)      * 72 + s * 32 + g * 8]);
      bf8 vf1 = *reinterpret_cast<const bf8*>(&Vt[(16 + i) * 72 + s * 32 + g * 8]);
      o0 = __builtin_amdgcn_mfma_f32_16x16x32_bf16(vf0, pf.v, o0, 0, 0, 0);
      o1 = __builtin_amdgcn_mfma_f32_16x16x32_bf16(vf1, pf.v, o1, 0, 0, 0);
    }
  }

  const float inv = 1.f / lsum;
  float* dst = aoT + (((size_t)(bh >> 2) << 10) + n0w + i) * 128 + (bh & 3) * 32 + 4 * g;
  f32x4 p0 = {o0[0] * inv, o0[1] * inv, o0[2] * inv, o0[3] * inv};
  f32x4 p1 = {o1[0] * inv, o1[1] * inv, o1[2] * inv, o1[3] * inv};
  *(f32x4*)dst        = p0;
  *(f32x4*)(dst + 16) = p1;
}

// ---------------------------------------------------------------------------
// Final: out = relu(bn2(y2) + x), all fp32.  8 elts/thread.
// ---------------------------------------------------------------------------
__global__ __launch_bounds__(256) void k_final(const float* __restrict__ y2,
                                               const float* __restrict__ x,
                                               const float* __restrict__ scl,
                                               const float* __restrict__ sht,
                                               float* __restrict__ out) {
  const size_t idx = ((size_t)blockIdx.x * 256 + threadIdx.x) * 8;
  const int c = (int)((idx >> 10) & 511);
  const float sc = scl[c], sh = sht[c];
  float4 v0 = *(const float4*)(y2 + idx);
  float4 v1 = *(const float4*)(y2 + idx + 4);
  float4 x0 = *(const float4*)(x + idx);
  float4 x1 = *(const float4*)(x + idx + 4);
  float4 o0, o1;
  o0.x = fmaxf(v0.x * sc + sh + x0.x, 0.f);
  o0.y = fmaxf(v0.y * sc + sh + x0.y, 0.f);
  o0.z = fmaxf(v0.z * sc + sh + x0.z, 0.f);
  o0.w = fmaxf(v0.w * sc + sh + x0.w, 0.f);
  o1.x = fmaxf(v1.x * sc + sh + x1.x, 0.f);
  o1.y = fmaxf(v1.y * sc + sh + x1.y, 0.f);
  o1.z = fmaxf(v1.z * sc + sh + x1.z, 0.f);
  o1.w = fmaxf(v1.w * sc + sh + x1.w, 0.f);
  *(float4*)(out + idx)     = o0;
  *(float4*)(out + idx + 4) = o1;
}

// ---------------------------------------------------------------------------
extern "C" void kernel_launch(void* const* d_in, const int* in_sizes, int n_in,
                              void* d_out, int out_size, void* d_ws, size_t ws_size,
                              hipStream_t stream) {
  (void)in_sizes; (void)n_in; (void)out_size; (void)ws_size;
  const float* x    = (const float*)d_in[0];
  const float* w1   = (const float*)d_in[1];
  const float* g1   = (const float*)d_in[2];
  const float* b1   = (const float*)d_in[3];
  const float* wqkv = (const float*)d_in[4];
  const float* rw   = (const float*)d_in[5];
  const float* rh   = (const float*)d_in[6];
  const float* w2   = (const float*)d_in[7];
  const float* g2   = (const float*)d_in[8];
  const float* b2   = (const float*)d_in[9];
  float* out = (float*)d_out;
  char* base = (char*)d_ws;

  // Workspace (bytes):
  // xT [0,16M) | y1T [16,20) | qs [20,24) | kt [24,28) | vt [28,32)
  // aoT fp32 [32,40) | y2 fp32 [0,32) (overlays dead xT..vt)
  // weights bf16 [40M,+352K) | partials/scalars [41M..)
  unsigned short* xT  = (unsigned short*)(base);
  unsigned short* y1T = (unsigned short*)(base + (16u << 20));
  unsigned short* qs  = (unsigned short*)(base + (20u << 20));
  unsigned short* kt  = (unsigned short*)(base + (24u << 20));
  unsigned short* vt  = (unsigned short*)(base + (28u << 20));
  float*          aoT = (float*)(base + (32u << 20));
  float*          y2  = (float*)(base);
  unsigned short* wb1 = (unsigned short*)(base + (40u << 20));
  unsigned short* wbq = wb1 + 65536;
  unsigned short* wb2 = wbq + 49152;
  float* pS   = (float*)(base + (41u << 20));
  float* pQ   = pS + 8192;
  float* scl1 = pQ + 8192;
  float* sht1 = scl1 + 128;
  float* scl2 = sht1 + 128;
  float* sht2 = scl2 + 512;

  // 1) weights -> bf16
  k_wcvt<<<88, 256, 0, stream>>>(w1, wqkv, w2, wb1, wbq, wb2);
  // 2) x -> xT (k-major bf16)
  k_xpose<<<dim3(16, 8, BATCH), 256, 0, stream>>>(x, xT);
  // 3) conv1 (MFMA) -> y1T [b][n][128] bf16
  k_mm<512, 0><<<dim3(8, 2, BATCH), 256, 0, stream>>>(wb1, xT, nullptr, nullptr,
                                                      nullptr, nullptr, y1T, nullptr, nullptr);
  // 4) bn1 stats
  k_bnstat1a<<<64, 256, 0, stream>>>(y1T, pS, pQ);
  k_bnfin1<<<1, 128, 0, stream>>>(pS, pQ, g1, b1, scl1, sht1);
  // 5) qkv (MFMA, bn1+relu fused) -> q,k'(+r),v bf16
  k_mm<128, 1><<<dim3(8, 6, BATCH), 256, 0, stream>>>(wbq, y1T, scl1, sht1,
                                                      rw, rh, qs, kt, vt);
  // 6) flash attention -> aoT fp32 [b][n][128]
  k_attn_mfma<<<dim3(NQ / 64, BATCH * 4), 256, 0, stream>>>(qs, kt, vt, aoT);
  // 7) conv2 split-precision MFMA -> y2 fp32
  k_mm2<<<dim3(16, 8, BATCH), 256, 0, stream>>>(wb2, aoT, y2);
  // 8) bn2 stats (fp32)
  k_bnstat2<<<512, 256, 0, stream>>>(y2, g2, b2, scl2, sht2);
  // 9) out = relu(bn2(y2) + x)
  k_final<<<4096, 256, 0, stream>>>(y2, x, scl2, sht2, out);
}

// Round 7
// 124.949 us; speedup vs baseline: 3.8642x; 1.0188x over previous
//
#include <hip/hip_runtime.h>
#include <cstddef>
#include <cstdint>

constexpr int BATCH = 16;
constexpr int NQ    = 1024;
constexpr float QSCALE = 0.17677669529663687f * 1.4426950408889634f; // 32^-0.5 * log2e

typedef __attribute__((ext_vector_type(8))) short bf8;            // MFMA operand (8 bf16)
typedef __attribute__((ext_vector_type(4))) float f32x4;
typedef __attribute__((ext_vector_type(4))) unsigned short us4;
typedef __attribute__((ext_vector_type(8))) unsigned short us8;

__device__ inline unsigned short f2bf(float x) {
  union { float f; uint32_t u; } c{x};
  uint32_t r = c.u + 0x7fffu + ((c.u >> 16) & 1u);   // RNE
  return (unsigned short)(r >> 16);
}
__device__ inline float b2f(unsigned short v) {
  union { uint32_t u; float f; } c{(uint32_t)v << 16};
  return c.f;
}
__device__ inline float fast_exp2(float x) {
#if __has_builtin(__builtin_amdgcn_exp2f)
  return __builtin_amdgcn_exp2f(x);
#else
  return exp2f(x);
#endif
}

// ---------------------------------------------------------------------------
// Weights -> bf16 (88 conversion blocks) + zero bn2 atomic partials (block 88).
// ---------------------------------------------------------------------------
__global__ __launch_bounds__(256) void k_wcvt(const float* __restrict__ w1,
                                              const float* __restrict__ wq,
                                              const float* __restrict__ w2,
                                              unsigned short* __restrict__ o1,
                                              unsigned short* __restrict__ oq,
                                              unsigned short* __restrict__ o2,
                                              float* __restrict__ S2,
                                              float* __restrict__ Q2) {
  if (blockIdx.x == 88) {
    // zero S2[512], Q2[512]
    const int t = threadIdx.x;
    S2[t * 2] = 0.f; S2[t * 2 + 1] = 0.f;
    Q2[t * 2] = 0.f; Q2[t * 2 + 1] = 0.f;
    return;
  }
  int idx = (blockIdx.x * 256 + threadIdx.x) * 8;
  const float* s; unsigned short* d; int off;
  if (idx < 65536)        { s = w1; d = o1; off = idx; }
  else if (idx < 114688)  { s = wq; d = oq; off = idx - 65536; }
  else                    { s = w2; d = o2; off = idx - 114688; }
  float4 a = *(const float4*)(s + off);
  float4 b = *(const float4*)(s + off + 4);
  us8 o = {f2bf(a.x), f2bf(a.y), f2bf(a.z), f2bf(a.w),
           f2bf(b.x), f2bf(b.y), f2bf(b.z), f2bf(b.w)};
  *(us8*)(d + off) = o;
}

// ---------------------------------------------------------------------------
// conv1 with fused transpose: y1T[b][n][128] bf16 = w1 @ x, x read directly.
// Block: 64n x 128m, K=512 in 8 steps of 64. 4 waves (2n x 2m), wave 32n x 64m.
// Staging: 4x4 register micro-transpose of x fp32 -> bf16 k-major LDS.
// grid (16, 1, 16).
// ---------------------------------------------------------------------------
__global__ __launch_bounds__(256) void k_conv1(const float* __restrict__ x,
                                               const unsigned short* __restrict__ W,
                                               unsigned short* __restrict__ y1T) {
  constexpr int BS = 68;                    // LDS row stride (bf16)
  __shared__ unsigned short Bl[64 * BS];    // [n][k], 8704 B

  const int bb = blockIdx.z;
  const int n0 = blockIdx.x * 64;
  const int tid = threadIdx.x, lane = tid & 63, wv = tid >> 6;
  const int wn = wv & 1, wm = wv >> 1;
  const int i = lane & 15, g = lane >> 4;

  const int kb = tid >> 4, nb = tid & 15;   // staging coords (4x4 block)

  f32x4 acc[2][4];
#pragma unroll
  for (int a = 0; a < 2; ++a)
#pragma unroll
    for (int b = 0; b < 4; ++b) acc[a][b] = {0.f, 0.f, 0.f, 0.f};

  // preload x-stage for step 0
  float4 rv[4];
#pragma unroll
  for (int r = 0; r < 4; ++r)
    rv[r] = *(const float4*)(x + (((size_t)(bb * 512 + kb * 4 + r)) << 10) + n0 + nb * 4);

  for (int s = 0; s < 8; ++s) {
    // weight frags for this K-step (global, L2-resident)
    bf8 wf[4][2];
#pragma unroll
    for (int b = 0; b < 4; ++b)
#pragma unroll
      for (int h = 0; h < 2; ++h)
        wf[b][h] = *(const bf8*)(W + (size_t)(wm * 64 + b * 16 + i) * 512 + s * 64 + h * 32 + g * 8);

    __syncthreads();
    // transpose-write staged tile: Bl[n][k]
#pragma unroll
    for (int j = 0; j < 4; ++j) {
      us4 pk = {f2bf((&rv[0].x)[j]), f2bf((&rv[1].x)[j]),
                f2bf((&rv[2].x)[j]), f2bf((&rv[3].x)[j])};
      *(us4*)&Bl[(nb * 4 + j) * BS + kb * 4] = pk;
    }
    __syncthreads();

    if (s < 7) {
#pragma unroll
      for (int r = 0; r < 4; ++r)
        rv[r] = *(const float4*)(x + (((size_t)(bb * 512 + (s + 1) * 64 + kb * 4 + r)) << 10) + n0 + nb * 4);
    }

#pragma unroll
    for (int h = 0; h < 2; ++h) {
      bf8 af[2];
#pragma unroll
      for (int a = 0; a < 2; ++a)
        af[a] = *(const bf8*)&Bl[(wn * 32 + a * 16 + i) * BS + h * 32 + g * 8];
#pragma unroll
      for (int a = 0; a < 2; ++a)
#pragma unroll
        for (int b = 0; b < 4; ++b)
          acc[a][b] = __builtin_amdgcn_mfma_f32_16x16x32_bf16(wf[b][h], af[a], acc[a][b], 0, 0, 0);
    }
  }

  // epilogue: D c-run (4g+r), n = lane i -> y1T[b][n][128]
#pragma unroll
  for (int a = 0; a < 2; ++a)
#pragma unroll
    for (int b = 0; b < 4; ++b) {
      const int n = n0 + wn * 32 + a * 16 + i;
      const int c = wm * 64 + b * 16 + 4 * g;
      us4 pk = {f2bf(acc[a][b][0]), f2bf(acc[a][b][1]), f2bf(acc[a][b][2]), f2bf(acc[a][b][3])};
      *(us4*)(y1T + ((size_t)(bb << 10) + n) * 128 + c) = pk;
    }
}

// ---------------------------------------------------------------------------
// qkv GEMM (unchanged r6 core): reads y1T with fused bn1+relu.
// grid: (NQ/128, 6, BATCH); mt 0,1=q 2,3=k 4,5=v
// ---------------------------------------------------------------------------
template<int KTOT, int MODE>
__global__ __launch_bounds__(256) void k_mm(const unsigned short* __restrict__ W,
                                            const unsigned short* __restrict__ Bact,
                                            const float* __restrict__ scl,
                                            const float* __restrict__ sht,
                                            const float* __restrict__ rw,
                                            const float* __restrict__ rh,
                                            unsigned short* __restrict__ out0,
                                            unsigned short* __restrict__ out1,
                                            unsigned short* __restrict__ out2) {
  constexpr int BS = 136;
  __shared__ unsigned short Blds[128 * BS];
  __shared__ float scl_s[128], sht_s[128];

  const int bb = blockIdx.z, mt = blockIdx.y;
  const int n0 = blockIdx.x * 128, m0 = mt * 64;
  const int tid = threadIdx.x, lane = tid & 63, wv = tid >> 6;
  const int wn = wv & 1, wm = wv >> 1;
  const int i = lane & 15, g = lane >> 4;

  const unsigned short* Bp = Bact + ((size_t)bb * NQ + n0) * KTOT;

  f32x4 acc[4][2];
#pragma unroll
  for (int a = 0; a < 4; ++a)
#pragma unroll
    for (int b = 0; b < 2; ++b) acc[a][b] = {0.f, 0.f, 0.f, 0.f};

  const int sn = tid >> 1;
  const int sk = (tid & 1) * 8;

  if (tid < 128) { scl_s[tid] = scl[tid]; sht_s[tid] = sht[tid]; }
  bf8 wf[2][4];
#pragma unroll
  for (int b = 0; b < 2; ++b)
#pragma unroll
    for (int h = 0; h < 4; ++h)
      wf[b][h] = *(const bf8*)(W + (size_t)(m0 + wm * 32 + b * 16 + i) * 128 + h * 32 + g * 8);
  __syncthreads();
#pragma unroll
  for (int p = 0; p < 8; ++p) {
    us8 v = *(const us8*)(Bp + (size_t)sn * 128 + sk + p * 16);
    const int kb = sk + p * 16;
    float scv[8], shv[8];
    *(float4*)scv = *(const float4*)&scl_s[kb];
    *(float4*)(scv + 4) = *(const float4*)&scl_s[kb + 4];
    *(float4*)shv = *(const float4*)&sht_s[kb];
    *(float4*)(shv + 4) = *(const float4*)&sht_s[kb + 4];
#pragma unroll
    for (int j = 0; j < 8; ++j)
      v[j] = f2bf(fmaxf(fmaf(b2f(v[j]), scv[j], shv[j]), 0.f));
    *(us8*)(&Blds[sn * BS + sk + p * 16]) = v;
  }
  __syncthreads();

  const bool actA = (mt >= 4);
  if (actA) {
#pragma unroll
    for (int h = 0; h < 4; ++h) {
      bf8 af[4];
#pragma unroll
      for (int a = 0; a < 4; ++a)
        af[a] = *(const bf8*)&Blds[(wn * 64 + a * 16 + i) * BS + h * 32 + g * 8];
#pragma unroll
      for (int a = 0; a < 4; ++a)
#pragma unroll
        for (int b = 0; b < 2; ++b)
          acc[a][b] = __builtin_amdgcn_mfma_f32_16x16x32_bf16(af[a], wf[b][h], acc[a][b], 0, 0, 0);
    }
  } else {
#pragma unroll
    for (int h = 0; h < 4; ++h) {
      bf8 af[4];
#pragma unroll
      for (int a = 0; a < 4; ++a)
        af[a] = *(const bf8*)&Blds[(wn * 64 + a * 16 + i) * BS + h * 32 + g * 8];
#pragma unroll
      for (int a = 0; a < 4; ++a)
#pragma unroll
        for (int b = 0; b < 2; ++b)
          acc[a][b] = __builtin_amdgcn_mfma_f32_16x16x32_bf16(wf[b][h], af[a], acc[a][b], 0, 0, 0);
    }
  }

  if (mt < 2) {           // q: [bh][n][32], scaled
#pragma unroll
    for (int a = 0; a < 4; ++a)
#pragma unroll
      for (int b = 0; b < 2; ++b) {
        const int n = n0 + wn * 64 + a * 16 + i;
        const int c = m0 + wm * 32 + b * 16 + 4 * g;
        const int hh = c >> 5, d = c & 31;
        us4 pk = {f2bf(acc[a][b][0] * QSCALE), f2bf(acc[a][b][1] * QSCALE),
                  f2bf(acc[a][b][2] * QSCALE), f2bf(acc[a][b][3] * QSCALE)};
        *(us4*)(out0 + (((size_t)(bb * 4 + hh) << 10) + n) * 32 + d) = pk;
      }
  } else if (mt < 4) {    // k: [bh][n][32], + r bias
#pragma unroll
    for (int a = 0; a < 4; ++a)
#pragma unroll
      for (int b = 0; b < 2; ++b) {
        const int n = n0 + wn * 64 + a * 16 + i;
        const int c = (m0 - 128) + wm * 32 + b * 16 + 4 * g;
        const int hh = c >> 5, d = c & 31;
        const int wcol = n & 31, hrow = n >> 5;
        float vv[4];
#pragma unroll
        for (int r = 0; r < 4; ++r)
          vv[r] = acc[a][b][r] + rw[(c + r) * 32 + wcol] + rh[(c + r) * 32 + hrow];
        us4 pk = {f2bf(vv[0]), f2bf(vv[1]), f2bf(vv[2]), f2bf(vv[3])};
        *(us4*)(out1 + (((size_t)(bb * 4 + hh) << 10) + n) * 32 + d) = pk;
      }
  } else {                // v: [bh][32][1024] (n-run per lane)
#pragma unroll
    for (int a = 0; a < 4; ++a)
#pragma unroll
      for (int b = 0; b < 2; ++b) {
        const int c = (m0 - 256) + wm * 32 + b * 16 + i;
        const int nb = n0 + wn * 64 + a * 16 + 4 * g;
        const int hh = c >> 5, dd = c & 31;
        us4 pk = {f2bf(acc[a][b][0]), f2bf(acc[a][b][1]), f2bf(acc[a][b][2]), f2bf(acc[a][b][3])};
        *(us4*)(out2 + (((size_t)(bb * 4 + hh) * 32 + dd) << 10) + nb) = pk;
      }
  }
}

// ---------------------------------------------------------------------------
// conv2, split-precision, full-M per block + fused bn2 atomic partials.
// Block 64n x 512m (8 m-subtiles of 64), 4 waves (2n x 2m). grid (16,1,16).
// ---------------------------------------------------------------------------
__global__ __launch_bounds__(256) void k_mm2(const unsigned short* __restrict__ W,
                                             const float* __restrict__ Aof,
                                             float* __restrict__ y2,
                                             float* __restrict__ S2,
                                             float* __restrict__ Q2) {
  constexpr int BS = 264;                    // 128 hi | 128 lo | 8 pad
  __shared__ unsigned short Blds[64 * BS];   // 33792 B
  const int bb = blockIdx.z;
  const int n0 = blockIdx.x * 64;
  const int tid = threadIdx.x, lane = tid & 63, wv = tid >> 6;
  const int wn = wv & 1, wm = wv >> 1;
  const int i = lane & 15, g = lane >> 4;

  const int sn = tid >> 2, sk = (tid & 3) * 32;
  const float* src = Aof + (((size_t)(bb << 10)) + n0 + sn) * 128 + sk;
#pragma unroll
  for (int p = 0; p < 4; ++p) {
    float4 f0 = *(const float4*)(src + p * 8);
    float4 f1 = *(const float4*)(src + p * 8 + 4);
    float fv[8] = {f0.x, f0.y, f0.z, f0.w, f1.x, f1.y, f1.z, f1.w};
    us8 hi, lo;
#pragma unroll
    for (int j = 0; j < 8; ++j) {
      unsigned short h16 = f2bf(fv[j]);
      hi[j] = h16;
      lo[j] = f2bf(fv[j] - b2f(h16));
    }
    *(us8*)&Blds[sn * BS + sk + p * 8]       = hi;
    *(us8*)&Blds[sn * BS + 128 + sk + p * 8] = lo;
  }
  __syncthreads();

  auto loadw = [&](bf8 (&wf)[2][4], int mt) {
#pragma unroll
    for (int b = 0; b < 2; ++b)
#pragma unroll
      for (int h = 0; h < 4; ++h)
        wf[b][h] = *(const bf8*)(W + (size_t)(mt * 64 + wm * 32 + b * 16 + i) * 128 + h * 32 + g * 8);
  };

  auto step = [&](bf8 (&wf)[2][4], int mt) {
    f32x4 acc[2][2];
#pragma unroll
    for (int a = 0; a < 2; ++a)
#pragma unroll
      for (int b = 0; b < 2; ++b) acc[a][b] = {0.f, 0.f, 0.f, 0.f};
#pragma unroll
    for (int h = 0; h < 4; ++h) {
      bf8 ah[2], al[2];
#pragma unroll
      for (int a = 0; a < 2; ++a) {
        ah[a] = *(const bf8*)&Blds[(wn * 32 + a * 16 + i) * BS + h * 32 + g * 8];
        al[a] = *(const bf8*)&Blds[(wn * 32 + a * 16 + i) * BS + 128 + h * 32 + g * 8];
      }
#pragma unroll
      for (int a = 0; a < 2; ++a)
#pragma unroll
        for (int b = 0; b < 2; ++b) {
          acc[a][b] = __builtin_amdgcn_mfma_f32_16x16x32_bf16(ah[a], wf[b][h], acc[a][b], 0, 0, 0);
          acc[a][b] = __builtin_amdgcn_mfma_f32_16x16x32_bf16(al[a], wf[b][h], acc[a][b], 0, 0, 0);
        }
    }
    // store y2 fp32 (D: n-run 4g+r, c = lane i)
#pragma unroll
    for (int a = 0; a < 2; ++a)
#pragma unroll
      for (int b = 0; b < 2; ++b) {
        const int c = mt * 64 + wm * 32 + b * 16 + i;
        const int nb = n0 + wn * 32 + a * 16 + 4 * g;
        *(f32x4*)(y2 + (((size_t)(bb * 512 + c)) << 10) + nb) = acc[a][b];
      }
    // bn2 partials: channel is lane-invariant in r -> reduce over g, atomicAdd
#pragma unroll
    for (int b = 0; b < 2; ++b) {
      float s = 0.f, q = 0.f;
#pragma unroll
      for (int a = 0; a < 2; ++a)
#pragma unroll
        for (int r = 0; r < 4; ++r) {
          float v = acc[a][b][r];
          s += v; q += v * v;
        }
      s += __shfl_xor(s, 16); s += __shfl_xor(s, 32);
      q += __shfl_xor(q, 16); q += __shfl_xor(q, 32);
      if (lane < 16) {
        const int c = mt * 64 + wm * 32 + b * 16 + i;
        atomicAdd(&S2[c], s);
        atomicAdd(&Q2[c], q);
      }
    }
  };

  bf8 wfA[2][4], wfB[2][4];
  loadw(wfA, 0);
#pragma unroll
  for (int mp = 0; mp < 4; ++mp) {
    loadw(wfB, 2 * mp + 1);
    step(wfA, 2 * mp);
    if (mp < 3) loadw(wfA, 2 * mp + 2);
    step(wfB, 2 * mp + 1);
  }
}

// ---------------------------------------------------------------------------
// bn1 stats over y1T [16384 rows][128 c] bf16 (unchanged).
// ---------------------------------------------------------------------------
__global__ __launch_bounds__(256) void k_bnstat1a(const unsigned short* __restrict__ y1T,
                                                  float* __restrict__ pS,
                                                  float* __restrict__ pQ) {
  const int blk = blockIdx.x, t = threadIdx.x;
  const int rr = t >> 4, co = t & 15;
  float s[8], q[8];
#pragma unroll
  for (int j = 0; j < 8; ++j) { s[j] = 0.f; q[j] = 0.f; }
  for (int it = 0; it < 16; ++it) {
    const int r = blk * 256 + rr + it * 16;
    us8 v = *(const us8*)(y1T + (size_t)r * 128 + co * 8);
#pragma unroll
    for (int j = 0; j < 8; ++j) { float f = b2f(v[j]); s[j] += f; q[j] += f * f; }
  }
  __shared__ float rs[16][16][8], rq[16][16][8];
#pragma unroll
  for (int j = 0; j < 8; ++j) { rs[rr][co][j] = s[j]; rq[rr][co][j] = q[j]; }
  __syncthreads();
  if (t < 128) {
    const int c = t;
    float S = 0.f, Q = 0.f;
    for (int r2 = 0; r2 < 16; ++r2) { S += rs[r2][c >> 3][c & 7]; Q += rq[r2][c >> 3][c & 7]; }
    pS[c * 64 + blk] = S;
    pQ[c * 64 + blk] = Q;
  }
}

__global__ __launch_bounds__(128) void k_bnfin1(const float* __restrict__ pS,
                                                const float* __restrict__ pQ,
                                                const float* __restrict__ g,
                                                const float* __restrict__ be,
                                                float* __restrict__ scl,
                                                float* __restrict__ sht) {
  const int c = threadIdx.x;
  float S = 0.f, Q = 0.f;
  for (int k = 0; k < 64; ++k) { S += pS[c * 64 + k]; Q += pQ[c * 64 + k]; }
  const float inv_n = 1.f / 16384.f;
  const float mean = S * inv_n, var = Q * inv_n - mean * mean;
  const float sc = rsqrtf(var + 1e-5f) * g[c];
  scl[c] = sc;
  sht[c] = be[c] - mean * sc;
}

__global__ __launch_bounds__(512) void k_bnfin2(const float* __restrict__ S2,
                                                const float* __restrict__ Q2,
                                                const float* __restrict__ g,
                                                const float* __restrict__ be,
                                                float* __restrict__ scl,
                                                float* __restrict__ sht) {
  const int c = threadIdx.x;
  const float inv_n = 1.f / 16384.f;
  const float mean = S2[c] * inv_n, var = Q2[c] * inv_n - mean * mean;
  const float sc = rsqrtf(var + 1e-5f) * g[c];
  scl[c] = sc;
  sht[c] = be[c] - mean * sc;
}

// ---------------------------------------------------------------------------
// MFMA flash attention (r4-proven core); writes fp32 aoT [b][n][128].
// ---------------------------------------------------------------------------
__global__ __launch_bounds__(256) void k_attn_mfma(const unsigned short* __restrict__ qs,
                                                   const unsigned short* __restrict__ kt,
                                                   const unsigned short* __restrict__ vt,
                                                   float* __restrict__ aoT) {
  const int bh   = blockIdx.y;
  const int tid  = threadIdx.x;
  const int lane = tid & 63;
  const int wv   = tid >> 6;
  const int i    = lane & 15;
  const int g    = lane >> 4;
  const int n0w  = blockIdx.x * 64 + wv * 16;

  __shared__ unsigned short Ks[64 * 56];
  __shared__ unsigned short Vt[32 * 72];

  const bf8 qf = *reinterpret_cast<const bf8*>(
      qs + ((size_t)bh * NQ + n0w + i) * 32 + g * 8);

  f32x4 o0 = {0.f, 0.f, 0.f, 0.f}, o1 = {0.f, 0.f, 0.f, 0.f};
  float m = -1e30f, lsum = 0.f;

  const unsigned short* kb = kt + (size_t)bh * NQ * 32;
  const unsigned short* vb = vt + (size_t)bh * 32 * NQ;

  const int skey = tid >> 2, sds = (tid & 3) * 8;
  const int svd  = tid >> 3, svn = (tid & 7) * 8;

  for (int k0 = 0; k0 < NQ; k0 += 64) {
    bf8 kvld = *reinterpret_cast<const bf8*>(kb + (size_t)(k0 + skey) * 32 + sds);
    bf8 vvld = *reinterpret_cast<const bf8*>(vb + (size_t)svd * NQ + k0 + svn);
    __syncthreads();
    *reinterpret_cast<bf8*>(&Ks[skey * 56 + sds]) = kvld;
    *reinterpret_cast<bf8*>(&Vt[svd * 72 + svn])  = vvld;
    __syncthreads();

    f32x4 st[4];
    const f32x4 zero = {0.f, 0.f, 0.f, 0.f};
#pragma unroll
    for (int t = 0; t < 4; ++t) {
      bf8 kf = *reinterpret_cast<const bf8*>(&Ks[(t * 16 + i) * 56 + g * 8]);
      st[t] = __builtin_amdgcn_mfma_f32_16x16x32_bf16(kf, qf, zero, 0, 0, 0);
    }

    float tmax = st[0][0];
#pragma unroll
    for (int t = 0; t < 4; ++t)
#pragma unroll
      for (int r = 0; r < 4; ++r) tmax = fmaxf(tmax, st[t][r]);
    tmax = fmaxf(tmax, __shfl_xor(tmax, 16));
    tmax = fmaxf(tmax, __shfl_xor(tmax, 32));

    const float mn   = fmaxf(m, tmax);
    const float corr = fast_exp2(m - mn);
    m = mn;

    float ps = 0.f;
    unsigned int pk[4][2];
#pragma unroll
    for (int t = 0; t < 4; ++t) {
      float p0 = fast_exp2(st[t][0] - mn);
      float p1 = fast_exp2(st[t][1] - mn);
      float p2 = fast_exp2(st[t][2] - mn);
      float p3 = fast_exp2(st[t][3] - mn);
      ps += (p0 + p1) + (p2 + p3);
      unsigned int pa, pb;
      asm("v_cvt_pk_bf16_f32 %0, %1, %2" : "=v"(pa) : "v"(p0), "v"(p1));
      asm("v_cvt_pk_bf16_f32 %0, %1, %2" : "=v"(pb) : "v"(p2), "v"(p3));
      pk[t][0] = pa; pk[t][1] = pb;
    }
    ps += __shfl_xor(ps, 16);
    ps += __shfl_xor(ps, 32);
    lsum = lsum * corr + ps;
#pragma unroll
    for (int r = 0; r < 4; ++r) { o0[r] *= corr; o1[r] *= corr; }

    const int src0 = ((g & 1) << 5) + i;
    const int src1 = src0 + 16;
    const bool hi = (g >= 2);
#pragma unroll
    for (int s = 0; s < 2; ++s) {
      int a0 = __shfl((int)pk[2 * s][0], src0);
      int a1 = __shfl((int)pk[2 * s][1], src0);
      int a2 = __shfl((int)pk[2 * s][0], src1);
      int a3 = __shfl((int)pk[2 * s][1], src1);
      int b0 = __shfl((int)pk[2 * s + 1][0], src0);
      int b1 = __shfl((int)pk[2 * s + 1][1], src0);
      int b2 = __shfl((int)pk[2 * s + 1][0], src1);
      int b3 = __shfl((int)pk[2 * s + 1][1], src1);
      union { int d[4]; bf8 v; } pf;
      pf.d[0] = hi ? b0 : a0;
      pf.d[1] = hi ? b1 : a1;
      pf.d[2] = hi ? b2 : a2;
      pf.d[3] = hi ? b3 : a3;
      bf8 vf0 = *reinterpret_cast<const bf8*>(&Vt[(i)      * 72 + s * 32 + g * 8]);
      bf8 vf1 = *reinterpret_cast<const bf8*>(&Vt[(16 + i) * 72 + s * 32 + g * 8]);
      o0 = __builtin_amdgcn_mfma_f32_16x16x32_bf16(vf0, pf.v, o0, 0, 0, 0);
      o1 = __builtin_amdgcn_mfma_f32_16x16x32_bf16(vf1, pf.v, o1, 0, 0, 0);
    }
  }

  const float inv = 1.f / lsum;
  float* dst = aoT + (((size_t)(bh >> 2) << 10) + n0w + i) * 128 + (bh & 3) * 32 + 4 * g;
  f32x4 p0 = {o0[0] * inv, o0[1] * inv, o0[2] * inv, o0[3] * inv};
  f32x4 p1 = {o1[0] * inv, o1[1] * inv, o1[2] * inv, o1[3] * inv};
  *(f32x4*)dst        = p0;
  *(f32x4*)(dst + 16) = p1;
}

// ---------------------------------------------------------------------------
// Final: out = relu(bn2(y2) + x), all fp32.  8 elts/thread.
// ---------------------------------------------------------------------------
__global__ __launch_bounds__(256) void k_final(const float* __restrict__ y2,
                                               const float* __restrict__ x,
                                               const float* __restrict__ scl,
                                               const float* __restrict__ sht,
                                               float* __restrict__ out) {
  const size_t idx = ((size_t)blockIdx.x * 256 + threadIdx.x) * 8;
  const int c = (int)((idx >> 10) & 511);
  const float sc = scl[c], sh = sht[c];
  float4 v0 = *(const float4*)(y2 + idx);
  float4 v1 = *(const float4*)(y2 + idx + 4);
  float4 x0 = *(const float4*)(x + idx);
  float4 x1 = *(const float4*)(x + idx + 4);
  float4 o0, o1;
  o0.x = fmaxf(v0.x * sc + sh + x0.x, 0.f);
  o0.y = fmaxf(v0.y * sc + sh + x0.y, 0.f);
  o0.z = fmaxf(v0.z * sc + sh + x0.z, 0.f);
  o0.w = fmaxf(v0.w * sc + sh + x0.w, 0.f);
  o1.x = fmaxf(v1.x * sc + sh + x1.x, 0.f);
  o1.y = fmaxf(v1.y * sc + sh + x1.y, 0.f);
  o1.z = fmaxf(v1.z * sc + sh + x1.z, 0.f);
  o1.w = fmaxf(v1.w * sc + sh + x1.w, 0.f);
  *(float4*)(out + idx)     = o0;
  *(float4*)(out + idx + 4) = o1;
}

// ---------------------------------------------------------------------------
extern "C" void kernel_launch(void* const* d_in, const int* in_sizes, int n_in,
                              void* d_out, int out_size, void* d_ws, size_t ws_size,
                              hipStream_t stream) {
  (void)in_sizes; (void)n_in; (void)out_size; (void)ws_size;
  const float* x    = (const float*)d_in[0];
  const float* w1   = (const float*)d_in[1];
  const float* g1   = (const float*)d_in[2];
  const float* b1   = (const float*)d_in[3];
  const float* wqkv = (const float*)d_in[4];
  const float* rw   = (const float*)d_in[5];
  const float* rh   = (const float*)d_in[6];
  const float* w2   = (const float*)d_in[7];
  const float* g2   = (const float*)d_in[8];
  const float* b2   = (const float*)d_in[9];
  float* out = (float*)d_out;
  char* base = (char*)d_ws;

  // Workspace (bytes):
  // y2 fp32 [0,32M) | y1T [16? no:] -- layout:
  //   y2 [0,32M) | y1T [32,36) | qs [36,40) | kt [40,44) | vt [44,48)
  //   aoT fp32 [48,56) | weights bf16 [56M,+352K) | partials/scalars [57M..)
  float*          y2  = (float*)(base);
  unsigned short* y1T = (unsigned short*)(base + (32u << 20));
  unsigned short* qs  = (unsigned short*)(base + (36u << 20));
  unsigned short* kt  = (unsigned short*)(base + (40u << 20));
  unsigned short* vt  = (unsigned short*)(base + (44u << 20));
  float*          aoT = (float*)(base + (48u << 20));
  unsigned short* wb1 = (unsigned short*)(base + (56u << 20));
  unsigned short* wbq = wb1 + 65536;
  unsigned short* wb2 = wbq + 49152;
  float* pS   = (float*)(base + (57u << 20));
  float* pQ   = pS + 8192;
  float* S2   = pQ + 8192;
  float* Q2   = S2 + 512;
  float* scl1 = Q2 + 512;
  float* sht1 = scl1 + 128;
  float* scl2 = sht1 + 128;
  float* sht2 = scl2 + 512;

  // 1) weights -> bf16; zero bn2 atomic partials
  k_wcvt<<<89, 256, 0, stream>>>(w1, wqkv, w2, wb1, wbq, wb2, S2, Q2);
  // 2) conv1 (fused transpose, MFMA) -> y1T [b][n][128] bf16
  k_conv1<<<dim3(16, 1, BATCH), 256, 0, stream>>>(x, wb1, y1T);
  // 3) bn1 stats
  k_bnstat1a<<<64, 256, 0, stream>>>(y1T, pS, pQ);
  k_bnfin1<<<1, 128, 0, stream>>>(pS, pQ, g1, b1, scl1, sht1);
  // 4) qkv (MFMA, bn1+relu fused) -> q,k'(+r),v bf16
  k_mm<128, 1><<<dim3(8, 6, BATCH), 256, 0, stream>>>(wbq, y1T, scl1, sht1,
                                                      rw, rh, qs, kt, vt);
  // 5) flash attention -> aoT fp32 [b][n][128]
  k_attn_mfma<<<dim3(NQ / 64, BATCH * 4), 256, 0, stream>>>(qs, kt, vt, aoT);
  // 6) conv2 split-precision MFMA + fused bn2 partials -> y2 fp32
  k_mm2<<<dim3(16, 1, BATCH), 256, 0, stream>>>(wb2, aoT, y2, S2, Q2);
  // 7) bn2 finalize
  k_bnfin2<<<1, 512, 0, stream>>>(S2, Q2, g2, b2, scl2, sht2);
  // 8) out = relu(bn2(y2) + x)
  k_final<<<4096, 256, 0, stream>>>(y2, x, scl2, sht2, out);
}

// Round 8
// 111.547 us; speedup vs baseline: 4.3284x; 1.1202x over previous
//
#include <hip/hip_runtime.h>
#include <cstddef>
#include <cstdint>

constexpr int BATCH = 16;
constexpr int NQ    = 1024;
constexpr float QSCALE = 0.17677669529663687f * 1.4426950408889634f; // 32^-0.5 * log2e

typedef __attribute__((ext_vector_type(8))) short bf8;            // MFMA operand (8 bf16)
typedef __attribute__((ext_vector_type(4))) float f32x4;
typedef __attribute__((ext_vector_type(4))) unsigned short us4;
typedef __attribute__((ext_vector_type(8))) unsigned short us8;

__device__ inline unsigned short f2bf(float x) {
  union { float f; uint32_t u; } c{x};
  uint32_t r = c.u + 0x7fffu + ((c.u >> 16) & 1u);   // RNE
  return (unsigned short)(r >> 16);
}
__device__ inline float b2f(unsigned short v) {
  union { uint32_t u; float f; } c{(uint32_t)v << 16};
  return c.f;
}
__device__ inline float fast_exp2(float x) {
#if __has_builtin(__builtin_amdgcn_exp2f)
  return __builtin_amdgcn_exp2f(x);
#else
  return exp2f(x);
#endif
}

// ---------------------------------------------------------------------------
// Weights -> bf16.
// ---------------------------------------------------------------------------
__global__ __launch_bounds__(256) void k_wcvt(const float* __restrict__ w1,
                                              const float* __restrict__ wq,
                                              const float* __restrict__ w2,
                                              unsigned short* __restrict__ o1,
                                              unsigned short* __restrict__ oq,
                                              unsigned short* __restrict__ o2) {
  int idx = (blockIdx.x * 256 + threadIdx.x) * 8;
  const float* s; unsigned short* d; int off;
  if (idx < 65536)        { s = w1; d = o1; off = idx; }
  else if (idx < 114688)  { s = wq; d = oq; off = idx - 65536; }
  else                    { s = w2; d = o2; off = idx - 114688; }
  float4 a = *(const float4*)(s + off);
  float4 b = *(const float4*)(s + off + 4);
  us8 o = {f2bf(a.x), f2bf(a.y), f2bf(a.z), f2bf(a.w),
           f2bf(b.x), f2bf(b.y), f2bf(b.z), f2bf(b.w)};
  *(us8*)(d + off) = o;
}

// ---------------------------------------------------------------------------
// conv1 with fused transpose: y1T[b][n][128] bf16 = w1 @ x, x read directly.
// Block: 64n x 128m, K=512 in 8 steps of 64. grid (16, 1, 16).
// ---------------------------------------------------------------------------
__global__ __launch_bounds__(256) void k_conv1(const float* __restrict__ x,
                                               const unsigned short* __restrict__ W,
                                               unsigned short* __restrict__ y1T) {
  constexpr int BS = 68;
  __shared__ unsigned short Bl[64 * BS];

  const int bb = blockIdx.z;
  const int n0 = blockIdx.x * 64;
  const int tid = threadIdx.x, lane = tid & 63, wv = tid >> 6;
  const int wn = wv & 1, wm = wv >> 1;
  const int i = lane & 15, g = lane >> 4;

  const int kb = tid >> 4, nb = tid & 15;

  f32x4 acc[2][4];
#pragma unroll
  for (int a = 0; a < 2; ++a)
#pragma unroll
    for (int b = 0; b < 4; ++b) acc[a][b] = {0.f, 0.f, 0.f, 0.f};

  float4 rv[4];
#pragma unroll
  for (int r = 0; r < 4; ++r)
    rv[r] = *(const float4*)(x + (((size_t)(bb * 512 + kb * 4 + r)) << 10) + n0 + nb * 4);

  for (int s = 0; s < 8; ++s) {
    bf8 wf[4][2];
#pragma unroll
    for (int b = 0; b < 4; ++b)
#pragma unroll
      for (int h = 0; h < 2; ++h)
        wf[b][h] = *(const bf8*)(W + (size_t)(wm * 64 + b * 16 + i) * 512 + s * 64 + h * 32 + g * 8);

    __syncthreads();
#pragma unroll
    for (int j = 0; j < 4; ++j) {
      us4 pk = {f2bf((&rv[0].x)[j]), f2bf((&rv[1].x)[j]),
                f2bf((&rv[2].x)[j]), f2bf((&rv[3].x)[j])};
      *(us4*)&Bl[(nb * 4 + j) * BS + kb * 4] = pk;
    }
    __syncthreads();

    if (s < 7) {
#pragma unroll
      for (int r = 0; r < 4; ++r)
        rv[r] = *(const float4*)(x + (((size_t)(bb * 512 + (s + 1) * 64 + kb * 4 + r)) << 10) + n0 + nb * 4);
    }

#pragma unroll
    for (int h = 0; h < 2; ++h) {
      bf8 af[2];
#pragma unroll
      for (int a = 0; a < 2; ++a)
        af[a] = *(const bf8*)&Bl[(wn * 32 + a * 16 + i) * BS + h * 32 + g * 8];
#pragma unroll
      for (int a = 0; a < 2; ++a)
#pragma unroll
        for (int b = 0; b < 4; ++b)
          acc[a][b] = __builtin_amdgcn_mfma_f32_16x16x32_bf16(wf[b][h], af[a], acc[a][b], 0, 0, 0);
    }
  }

#pragma unroll
  for (int a = 0; a < 2; ++a)
#pragma unroll
    for (int b = 0; b < 4; ++b) {
      const int n = n0 + wn * 32 + a * 16 + i;
      const int c = wm * 64 + b * 16 + 4 * g;
      us4 pk = {f2bf(acc[a][b][0]), f2bf(acc[a][b][1]), f2bf(acc[a][b][2]), f2bf(acc[a][b][3])};
      *(us4*)(y1T + ((size_t)(bb << 10) + n) * 128 + c) = pk;
    }
}

// ---------------------------------------------------------------------------
// qkv GEMM: reads y1T with fused bn1+relu. grid: (8, 6, 16); mt 0,1=q 2,3=k 4,5=v
// ---------------------------------------------------------------------------
template<int KTOT, int MODE>
__global__ __launch_bounds__(256) void k_mm(const unsigned short* __restrict__ W,
                                            const unsigned short* __restrict__ Bact,
                                            const float* __restrict__ scl,
                                            const float* __restrict__ sht,
                                            const float* __restrict__ rw,
                                            const float* __restrict__ rh,
                                            unsigned short* __restrict__ out0,
                                            unsigned short* __restrict__ out1,
                                            unsigned short* __restrict__ out2) {
  constexpr int BS = 136;
  __shared__ unsigned short Blds[128 * BS];
  __shared__ float scl_s[128], sht_s[128];

  const int bb = blockIdx.z, mt = blockIdx.y;
  const int n0 = blockIdx.x * 128, m0 = mt * 64;
  const int tid = threadIdx.x, lane = tid & 63, wv = tid >> 6;
  const int wn = wv & 1, wm = wv >> 1;
  const int i = lane & 15, g = lane >> 4;

  const unsigned short* Bp = Bact + ((size_t)bb * NQ + n0) * KTOT;

  f32x4 acc[4][2];
#pragma unroll
  for (int a = 0; a < 4; ++a)
#pragma unroll
    for (int b = 0; b < 2; ++b) acc[a][b] = {0.f, 0.f, 0.f, 0.f};

  const int sn = tid >> 1;
  const int sk = (tid & 1) * 8;

  if (tid < 128) { scl_s[tid] = scl[tid]; sht_s[tid] = sht[tid]; }
  bf8 wf[2][4];
#pragma unroll
  for (int b = 0; b < 2; ++b)
#pragma unroll
    for (int h = 0; h < 4; ++h)
      wf[b][h] = *(const bf8*)(W + (size_t)(m0 + wm * 32 + b * 16 + i) * 128 + h * 32 + g * 8);
  __syncthreads();
#pragma unroll
  for (int p = 0; p < 8; ++p) {
    us8 v = *(const us8*)(Bp + (size_t)sn * 128 + sk + p * 16);
    const int kb = sk + p * 16;
    float scv[8], shv[8];
    *(float4*)scv = *(const float4*)&scl_s[kb];
    *(float4*)(scv + 4) = *(const float4*)&scl_s[kb + 4];
    *(float4*)shv = *(const float4*)&sht_s[kb];
    *(float4*)(shv + 4) = *(const float4*)&sht_s[kb + 4];
#pragma unroll
    for (int j = 0; j < 8; ++j)
      v[j] = f2bf(fmaxf(fmaf(b2f(v[j]), scv[j], shv[j]), 0.f));
    *(us8*)(&Blds[sn * BS + sk + p * 16]) = v;
  }
  __syncthreads();

  const bool actA = (mt >= 4);
  if (actA) {
#pragma unroll
    for (int h = 0; h < 4; ++h) {
      bf8 af[4];
#pragma unroll
      for (int a = 0; a < 4; ++a)
        af[a] = *(const bf8*)&Blds[(wn * 64 + a * 16 + i) * BS + h * 32 + g * 8];
#pragma unroll
      for (int a = 0; a < 4; ++a)
#pragma unroll
        for (int b = 0; b < 2; ++b)
          acc[a][b] = __builtin_amdgcn_mfma_f32_16x16x32_bf16(af[a], wf[b][h], acc[a][b], 0, 0, 0);
    }
  } else {
#pragma unroll
    for (int h = 0; h < 4; ++h) {
      bf8 af[4];
#pragma unroll
      for (int a = 0; a < 4; ++a)
        af[a] = *(const bf8*)&Blds[(wn * 64 + a * 16 + i) * BS + h * 32 + g * 8];
#pragma unroll
      for (int a = 0; a < 4; ++a)
#pragma unroll
        for (int b = 0; b < 2; ++b)
          acc[a][b] = __builtin_amdgcn_mfma_f32_16x16x32_bf16(wf[b][h], af[a], acc[a][b], 0, 0, 0);
    }
  }

  if (mt < 2) {           // q: [bh][n][32], scaled
#pragma unroll
    for (int a = 0; a < 4; ++a)
#pragma unroll
      for (int b = 0; b < 2; ++b) {
        const int n = n0 + wn * 64 + a * 16 + i;
        const int c = m0 + wm * 32 + b * 16 + 4 * g;
        const int hh = c >> 5, d = c & 31;
        us4 pk = {f2bf(acc[a][b][0] * QSCALE), f2bf(acc[a][b][1] * QSCALE),
                  f2bf(acc[a][b][2] * QSCALE), f2bf(acc[a][b][3] * QSCALE)};
        *(us4*)(out0 + (((size_t)(bb * 4 + hh) << 10) + n) * 32 + d) = pk;
      }
  } else if (mt < 4) {    // k: [bh][n][32], + r bias
#pragma unroll
    for (int a = 0; a < 4; ++a)
#pragma unroll
      for (int b = 0; b < 2; ++b) {
        const int n = n0 + wn * 64 + a * 16 + i;
        const int c = (m0 - 128) + wm * 32 + b * 16 + 4 * g;
        const int hh = c >> 5, d = c & 31;
        const int wcol = n & 31, hrow = n >> 5;
        float vv[4];
#pragma unroll
        for (int r = 0; r < 4; ++r)
          vv[r] = acc[a][b][r] + rw[(c + r) * 32 + wcol] + rh[(c + r) * 32 + hrow];
        us4 pk = {f2bf(vv[0]), f2bf(vv[1]), f2bf(vv[2]), f2bf(vv[3])};
        *(us4*)(out1 + (((size_t)(bb * 4 + hh) << 10) + n) * 32 + d) = pk;
      }
  } else {                // v: [bh][32][1024] (n-run per lane)
#pragma unroll
    for (int a = 0; a < 4; ++a)
#pragma unroll
      for (int b = 0; b < 2; ++b) {
        const int c = (m0 - 256) + wm * 32 + b * 16 + i;
        const int nb = n0 + wn * 64 + a * 16 + 4 * g;
        const int hh = c >> 5, dd = c & 31;
        us4 pk = {f2bf(acc[a][b][0]), f2bf(acc[a][b][1]), f2bf(acc[a][b][2]), f2bf(acc[a][b][3])};
        *(us4*)(out2 + (((size_t)(bb * 4 + hh) * 32 + dd) << 10) + nb) = pk;
      }
  }
}

// ---------------------------------------------------------------------------
// conv2, split-precision + fused bn2 partials (LDS-reduced, NO global atomics).
// Block 64n x 256m (4 m-subtiles), 4 waves. grid (16, 2, 16).
// Per-block partials -> pBS/pBQ[c][256], reduced by k_bnfin2.
// ---------------------------------------------------------------------------
__global__ __launch_bounds__(256) void k_mm2(const unsigned short* __restrict__ W,
                                             const float* __restrict__ Aof,
                                             float* __restrict__ y2,
                                             float* __restrict__ pBS,
                                             float* __restrict__ pBQ) {
  constexpr int BS = 264;                    // 128 hi | 128 lo | 8 pad
  __shared__ unsigned short Blds[64 * BS];   // 33792 B
  __shared__ float Sl[256], Ql[256];         // per-block bn2 partials (256 ch)
  const int bb = blockIdx.z;
  const int mh = blockIdx.y;                 // m half: channels [mh*256, mh*256+256)
  const int n0 = blockIdx.x * 64;
  const int tid = threadIdx.x, lane = tid & 63, wv = tid >> 6;
  const int wn = wv & 1, wm = wv >> 1;
  const int i = lane & 15, g = lane >> 4;

  Sl[tid] = 0.f; Ql[tid] = 0.f;

  const int sn = tid >> 2, sk = (tid & 3) * 32;
  const float* src = Aof + (((size_t)(bb << 10)) + n0 + sn) * 128 + sk;
#pragma unroll
  for (int p = 0; p < 4; ++p) {
    float4 f0 = *(const float4*)(src + p * 8);
    float4 f1 = *(const float4*)(src + p * 8 + 4);
    float fv[8] = {f0.x, f0.y, f0.z, f0.w, f1.x, f1.y, f1.z, f1.w};
    us8 hi, lo;
#pragma unroll
    for (int j = 0; j < 8; ++j) {
      unsigned short h16 = f2bf(fv[j]);
      hi[j] = h16;
      lo[j] = f2bf(fv[j] - b2f(h16));
    }
    *(us8*)&Blds[sn * BS + sk + p * 8]       = hi;
    *(us8*)&Blds[sn * BS + 128 + sk + p * 8] = lo;
  }
  __syncthreads();

  auto loadw = [&](bf8 (&wf)[2][4], int lp) {
    const int mt = mh * 4 + lp;
#pragma unroll
    for (int b = 0; b < 2; ++b)
#pragma unroll
      for (int h = 0; h < 4; ++h)
        wf[b][h] = *(const bf8*)(W + (size_t)(mt * 64 + wm * 32 + b * 16 + i) * 128 + h * 32 + g * 8);
  };

  auto step = [&](bf8 (&wf)[2][4], int lp) {
    const int mt = mh * 4 + lp;
    f32x4 acc[2][2];
#pragma unroll
    for (int a = 0; a < 2; ++a)
#pragma unroll
      for (int b = 0; b < 2; ++b) acc[a][b] = {0.f, 0.f, 0.f, 0.f};
#pragma unroll
    for (int h = 0; h < 4; ++h) {
      bf8 ah[2], al[2];
#pragma unroll
      for (int a = 0; a < 2; ++a) {
        ah[a] = *(const bf8*)&Blds[(wn * 32 + a * 16 + i) * BS + h * 32 + g * 8];
        al[a] = *(const bf8*)&Blds[(wn * 32 + a * 16 + i) * BS + 128 + h * 32 + g * 8];
      }
#pragma unroll
      for (int a = 0; a < 2; ++a)
#pragma unroll
        for (int b = 0; b < 2; ++b) {
          acc[a][b] = __builtin_amdgcn_mfma_f32_16x16x32_bf16(ah[a], wf[b][h], acc[a][b], 0, 0, 0);
          acc[a][b] = __builtin_amdgcn_mfma_f32_16x16x32_bf16(al[a], wf[b][h], acc[a][b], 0, 0, 0);
        }
    }
#pragma unroll
    for (int a = 0; a < 2; ++a)
#pragma unroll
      for (int b = 0; b < 2; ++b) {
        const int c = mt * 64 + wm * 32 + b * 16 + i;
        const int nb = n0 + wn * 32 + a * 16 + 4 * g;
        *(f32x4*)(y2 + (((size_t)(bb * 512 + c)) << 10) + nb) = acc[a][b];
      }
    // bn2 partials: reduce over g-groups, then LDS atomic (2-way wn contention)
#pragma unroll
    for (int b = 0; b < 2; ++b) {
      float s = 0.f, q = 0.f;
#pragma unroll
      for (int a = 0; a < 2; ++a)
#pragma unroll
        for (int r = 0; r < 4; ++r) {
          float v = acc[a][b][r];
          s += v; q += v * v;
        }
      s += __shfl_xor(s, 16); s += __shfl_xor(s, 32);
      q += __shfl_xor(q, 16); q += __shfl_xor(q, 32);
      if ((lane & 48) == 0) {   // one lane per channel per wave
        const int cl = lp * 64 + wm * 32 + b * 16 + i;
        atomicAdd(&Sl[cl], s);
        atomicAdd(&Ql[cl], q);
      }
    }
  };

  bf8 wfA[2][4], wfB[2][4];
  loadw(wfA, 0);
#pragma unroll
  for (int mp = 0; mp < 2; ++mp) {
    loadw(wfB, 2 * mp + 1);
    step(wfA, 2 * mp);
    if (mp < 1) loadw(wfA, 2 * mp + 2);
    step(wfB, 2 * mp + 1);
  }

  __syncthreads();
  const int pidx = bb * 16 + blockIdx.x;     // 256 partials per channel
  pBS[(size_t)(mh * 256 + tid) * 256 + pidx] = Sl[tid];
  pBQ[(size_t)(mh * 256 + tid) * 256 + pidx] = Ql[tid];
}

// ---------------------------------------------------------------------------
// bn1 stats over y1T (unchanged).
// ---------------------------------------------------------------------------
__global__ __launch_bounds__(256) void k_bnstat1a(const unsigned short* __restrict__ y1T,
                                                  float* __restrict__ pS,
                                                  float* __restrict__ pQ) {
  const int blk = blockIdx.x, t = threadIdx.x;
  const int rr = t >> 4, co = t & 15;
  float s[8], q[8];
#pragma unroll
  for (int j = 0; j < 8; ++j) { s[j] = 0.f; q[j] = 0.f; }
  for (int it = 0; it < 16; ++it) {
    const int r = blk * 256 + rr + it * 16;
    us8 v = *(const us8*)(y1T + (size_t)r * 128 + co * 8);
#pragma unroll
    for (int j = 0; j < 8; ++j) { float f = b2f(v[j]); s[j] += f; q[j] += f * f; }
  }
  __shared__ float rs[16][16][8], rq[16][16][8];
#pragma unroll
  for (int j = 0; j < 8; ++j) { rs[rr][co][j] = s[j]; rq[rr][co][j] = q[j]; }
  __syncthreads();
  if (t < 128) {
    const int c = t;
    float S = 0.f, Q = 0.f;
    for (int r2 = 0; r2 < 16; ++r2) { S += rs[r2][c >> 3][c & 7]; Q += rq[r2][c >> 3][c & 7]; }
    pS[c * 64 + blk] = S;
    pQ[c * 64 + blk] = Q;
  }
}

__global__ __launch_bounds__(128) void k_bnfin1(const float* __restrict__ pS,
                                                const float* __restrict__ pQ,
                                                const float* __restrict__ g,
                                                const float* __restrict__ be,
                                                float* __restrict__ scl,
                                                float* __restrict__ sht) {
  const int c = threadIdx.x;
  float S = 0.f, Q = 0.f;
  for (int k = 0; k < 64; ++k) { S += pS[c * 64 + k]; Q += pQ[c * 64 + k]; }
  const float inv_n = 1.f / 16384.f;
  const float mean = S * inv_n, var = Q * inv_n - mean * mean;
  const float sc = rsqrtf(var + 1e-5f) * g[c];
  scl[c] = sc;
  sht[c] = be[c] - mean * sc;
}

// 512 blocks x 64 threads: reduce 256 partials per channel.
__global__ __launch_bounds__(64) void k_bnfin2(const float* __restrict__ pBS,
                                               const float* __restrict__ pBQ,
                                               const float* __restrict__ g,
                                               const float* __restrict__ be,
                                               float* __restrict__ scl,
                                               float* __restrict__ sht) {
  const int c = blockIdx.x, t = threadIdx.x;
  float S = 0.f, Q = 0.f;
#pragma unroll
  for (int k = 0; k < 4; ++k) {
    S += pBS[(size_t)c * 256 + t + k * 64];
    Q += pBQ[(size_t)c * 256 + t + k * 64];
  }
#pragma unroll
  for (int o = 32; o > 0; o >>= 1) {
    S += __shfl_down(S, o);
    Q += __shfl_down(Q, o);
  }
  if (t == 0) {
    const float inv_n = 1.f / 16384.f;
    const float mean = S * inv_n, var = Q * inv_n - mean * mean;
    const float sc = rsqrtf(var + 1e-5f) * g[c];
    scl[c] = sc;
    sht[c] = be[c] - mean * sc;
  }
}

// ---------------------------------------------------------------------------
// MFMA flash attention (r4-proven core); writes fp32 aoT [b][n][128].
// ---------------------------------------------------------------------------
__global__ __launch_bounds__(256) void k_attn_mfma(const unsigned short* __restrict__ qs,
                                                   const unsigned short* __restrict__ kt,
                                                   const unsigned short* __restrict__ vt,
                                                   float* __restrict__ aoT) {
  const int bh   = blockIdx.y;
  const int tid  = threadIdx.x;
  const int lane = tid & 63;
  const int wv   = tid >> 6;
  const int i    = lane & 15;
  const int g    = lane >> 4;
  const int n0w  = blockIdx.x * 64 + wv * 16;

  __shared__ unsigned short Ks[64 * 56];
  __shared__ unsigned short Vt[32 * 72];

  const bf8 qf = *reinterpret_cast<const bf8*>(
      qs + ((size_t)bh * NQ + n0w + i) * 32 + g * 8);

  f32x4 o0 = {0.f, 0.f, 0.f, 0.f}, o1 = {0.f, 0.f, 0.f, 0.f};
  float m = -1e30f, lsum = 0.f;

  const unsigned short* kb = kt + (size_t)bh * NQ * 32;
  const unsigned short* vb = vt + (size_t)bh * 32 * NQ;

  const int skey = tid >> 2, sds = (tid & 3) * 8;
  const int svd  = tid >> 3, svn = (tid & 7) * 8;

  for (int k0 = 0; k0 < NQ; k0 += 64) {
    bf8 kvld = *reinterpret_cast<const bf8*>(kb + (size_t)(k0 + skey) * 32 + sds);
    bf8 vvld = *reinterpret_cast<const bf8*>(vb + (size_t)svd * NQ + k0 + svn);
    __syncthreads();
    *reinterpret_cast<bf8*>(&Ks[skey * 56 + sds]) = kvld;
    *reinterpret_cast<bf8*>(&Vt[svd * 72 + svn])  = vvld;
    __syncthreads();

    f32x4 st[4];
    const f32x4 zero = {0.f, 0.f, 0.f, 0.f};
#pragma unroll
    for (int t = 0; t < 4; ++t) {
      bf8 kf = *reinterpret_cast<const bf8*>(&Ks[(t * 16 + i) * 56 + g * 8]);
      st[t] = __builtin_amdgcn_mfma_f32_16x16x32_bf16(kf, qf, zero, 0, 0, 0);
    }

    float tmax = st[0][0];
#pragma unroll
    for (int t = 0; t < 4; ++t)
#pragma unroll
      for (int r = 0; r < 4; ++r) tmax = fmaxf(tmax, st[t][r]);
    tmax = fmaxf(tmax, __shfl_xor(tmax, 16));
    tmax = fmaxf(tmax, __shfl_xor(tmax, 32));

    const float mn   = fmaxf(m, tmax);
    const float corr = fast_exp2(m - mn);
    m = mn;

    float ps = 0.f;
    unsigned int pk[4][2];
#pragma unroll
    for (int t = 0; t < 4; ++t) {
      float p0 = fast_exp2(st[t][0] - mn);
      float p1 = fast_exp2(st[t][1] - mn);
      float p2 = fast_exp2(st[t][2] - mn);
      float p3 = fast_exp2(st[t][3] - mn);
      ps += (p0 + p1) + (p2 + p3);
      unsigned int pa, pb;
      asm("v_cvt_pk_bf16_f32 %0, %1, %2" : "=v"(pa) : "v"(p0), "v"(p1));
      asm("v_cvt_pk_bf16_f32 %0, %1, %2" : "=v"(pb) : "v"(p2), "v"(p3));
      pk[t][0] = pa; pk[t][1] = pb;
    }
    ps += __shfl_xor(ps, 16);
    ps += __shfl_xor(ps, 32);
    lsum = lsum * corr + ps;
#pragma unroll
    for (int r = 0; r < 4; ++r) { o0[r] *= corr; o1[r] *= corr; }

    const int src0 = ((g & 1) << 5) + i;
    const int src1 = src0 + 16;
    const bool hi = (g >= 2);
#pragma unroll
    for (int s = 0; s < 2; ++s) {
      int a0 = __shfl((int)pk[2 * s][0], src0);
      int a1 = __shfl((int)pk[2 * s][1], src0);
      int a2 = __shfl((int)pk[2 * s][0], src1);
      int a3 = __shfl((int)pk[2 * s][1], src1);
      int b0 = __shfl((int)pk[2 * s + 1][0], src0);
      int b1 = __shfl((int)pk[2 * s + 1][1], src0);
      int b2 = __shfl((int)pk[2 * s + 1][0], src1);
      int b3 = __shfl((int)pk[2 * s + 1][1], src1);
      union { int d[4]; bf8 v; } pf;
      pf.d[0] = hi ? b0 : a0;
      pf.d[1] = hi ? b1 : a1;
      pf.d[2] = hi ? b2 : a2;
      pf.d[3] = hi ? b3 : a3;
      bf8 vf0 = *reinterpret_cast<const bf8*>(&Vt[(i)      * 72 + s * 32 + g * 8]);
      bf8 vf1 = *reinterpret_cast<const bf8*>(&Vt[(16 + i) * 72 + s * 32 + g * 8]);
      o0 = __builtin_amdgcn_mfma_f32_16x16x32_bf16(vf0, pf.v, o0, 0, 0, 0);
      o1 = __builtin_amdgcn_mfma_f32_16x16x32_bf16(vf1, pf.v, o1, 0, 0, 0);
    }
  }

  const float inv = 1.f / lsum;
  float* dst = aoT + (((size_t)(bh >> 2) << 10) + n0w + i) * 128 + (bh & 3) * 32 + 4 * g;
  f32x4 p0 = {o0[0] * inv, o0[1] * inv, o0[2] * inv, o0[3] * inv};
  f32x4 p1 = {o1[0] * inv, o1[1] * inv, o1[2] * inv, o1[3] * inv};
  *(f32x4*)dst        = p0;
  *(f32x4*)(dst + 16) = p1;
}

// ---------------------------------------------------------------------------
// Final: out = relu(bn2(y2) + x), all fp32.  8 elts/thread.
// ---------------------------------------------------------------------------
__global__ __launch_bounds__(256) void k_final(const float* __restrict__ y2,
                                               const float* __restrict__ x,
                                               const float* __restrict__ scl,
                                               const float* __restrict__ sht,
                                               float* __restrict__ out) {
  const size_t idx = ((size_t)blockIdx.x * 256 + threadIdx.x) * 8;
  const int c = (int)((idx >> 10) & 511);
  const float sc = scl[c], sh = sht[c];
  float4 v0 = *(const float4*)(y2 + idx);
  float4 v1 = *(const float4*)(y2 + idx + 4);
  float4 x0 = *(const float4*)(x + idx);
  float4 x1 = *(const float4*)(x + idx + 4);
  float4 o0, o1;
  o0.x = fmaxf(v0.x * sc + sh + x0.x, 0.f);
  o0.y = fmaxf(v0.y * sc + sh + x0.y, 0.f);
  o0.z = fmaxf(v0.z * sc + sh + x0.z, 0.f);
  o0.w = fmaxf(v0.w * sc + sh + x0.w, 0.f);
  o1.x = fmaxf(v1.x * sc + sh + x1.x, 0.f);
  o1.y = fmaxf(v1.y * sc + sh + x1.y, 0.f);
  o1.z = fmaxf(v1.z * sc + sh + x1.z, 0.f);
  o1.w = fmaxf(v1.w * sc + sh + x1.w, 0.f);
  *(float4*)(out + idx)     = o0;
  *(float4*)(out + idx + 4) = o1;
}

// ---------------------------------------------------------------------------
extern "C" void kernel_launch(void* const* d_in, const int* in_sizes, int n_in,
                              void* d_out, int out_size, void* d_ws, size_t ws_size,
                              hipStream_t stream) {
  (void)in_sizes; (void)n_in; (void)out_size; (void)ws_size;
  const float* x    = (const float*)d_in[0];
  const float* w1   = (const float*)d_in[1];
  const float* g1   = (const float*)d_in[2];
  const float* b1   = (const float*)d_in[3];
  const float* wqkv = (const float*)d_in[4];
  const float* rw   = (const float*)d_in[5];
  const float* rh   = (const float*)d_in[6];
  const float* w2   = (const float*)d_in[7];
  const float* g2   = (const float*)d_in[8];
  const float* b2   = (const float*)d_in[9];
  float* out = (float*)d_out;
  char* base = (char*)d_ws;

  // Workspace (bytes):
  //   y2 [0,32M) | y1T [32,36) | qs [36,40) | kt [40,44) | vt [44,48)
  //   aoT fp32 [48,56) | weights bf16 [56M,+352K) | partials/scalars [57M..58.2M)
  float*          y2  = (float*)(base);
  unsigned short* y1T = (unsigned short*)(base + (32u << 20));
  unsigned short* qs  = (unsigned short*)(base + (36u << 20));
  unsigned short* kt  = (unsigned short*)(base + (40u << 20));
  unsigned short* vt  = (unsigned short*)(base + (44u << 20));
  float*          aoT = (float*)(base + (48u << 20));
  unsigned short* wb1 = (unsigned short*)(base + (56u << 20));
  unsigned short* wbq = wb1 + 65536;
  unsigned short* wb2 = wbq + 49152;
  float* pS   = (float*)(base + (57u << 20));  // 128*64
  float* pQ   = pS + 8192;
  float* pBS  = pQ + 8192;                     // 512*256
  float* pBQ  = pBS + 131072;
  float* scl1 = pBQ + 131072;
  float* sht1 = scl1 + 128;
  float* scl2 = sht1 + 128;
  float* sht2 = scl2 + 512;

  // 1) weights -> bf16
  k_wcvt<<<88, 256, 0, stream>>>(w1, wqkv, w2, wb1, wbq, wb2);
  // 2) conv1 (fused transpose, MFMA) -> y1T [b][n][128] bf16
  k_conv1<<<dim3(16, 1, BATCH), 256, 0, stream>>>(x, wb1, y1T);
  // 3) bn1 stats
  k_bnstat1a<<<64, 256, 0, stream>>>(y1T, pS, pQ);
  k_bnfin1<<<1, 128, 0, stream>>>(pS, pQ, g1, b1, scl1, sht1);
  // 4) qkv (MFMA, bn1+relu fused) -> q,k'(+r),v bf16
  k_mm<128, 1><<<dim3(8, 6, BATCH), 256, 0, stream>>>(wbq, y1T, scl1, sht1,
                                                      rw, rh, qs, kt, vt);
  // 5) flash attention -> aoT fp32 [b][n][128]
  k_attn_mfma<<<dim3(NQ / 64, BATCH * 4), 256, 0, stream>>>(qs, kt, vt, aoT);
  // 6) conv2 split-precision MFMA + per-block bn2 partials -> y2 fp32
  k_mm2<<<dim3(16, 2, BATCH), 256, 0, stream>>>(wb2, aoT, y2, pBS, pBQ);
  // 7) bn2 finalize (reduce 256 partials/channel)
  k_bnfin2<<<512, 64, 0, stream>>>(pBS, pBQ, g2, b2, scl2, sht2);
  // 8) out = relu(bn2(y2) + x)
  k_final<<<4096, 256, 0, stream>>>(y2, x, scl2, sht2, out);
}

// Round 9
// 107.729 us; speedup vs baseline: 4.4818x; 1.0354x over previous
//
#include <hip/hip_runtime.h>
#include <cstddef>
#include <cstdint>

constexpr int BATCH = 16;
constexpr int NQ    = 1024;
constexpr float QSCALE = 0.17677669529663687f * 1.4426950408889634f; // 32^-0.5 * log2e

typedef __attribute__((ext_vector_type(8))) short bf8;            // MFMA operand (8 bf16)
typedef __attribute__((ext_vector_type(4))) float f32x4;
typedef __attribute__((ext_vector_type(4))) unsigned short us4;
typedef __attribute__((ext_vector_type(8))) unsigned short us8;

__device__ inline unsigned short f2bf(float x) {
  union { float f; uint32_t u; } c{x};
  uint32_t r = c.u + 0x7fffu + ((c.u >> 16) & 1u);   // RNE
  return (unsigned short)(r >> 16);
}
__device__ inline float b2f(unsigned short v) {
  union { uint32_t u; float f; } c{(uint32_t)v << 16};
  return c.f;
}
__device__ inline float fast_exp2(float x) {
#if __has_builtin(__builtin_amdgcn_exp2f)
  return __builtin_amdgcn_exp2f(x);
#else
  return exp2f(x);
#endif
}

// ---------------------------------------------------------------------------
// Weights -> bf16.
// ---------------------------------------------------------------------------
__global__ __launch_bounds__(256) void k_wcvt(const float* __restrict__ w1,
                                              const float* __restrict__ wq,
                                              const float* __restrict__ w2,
                                              unsigned short* __restrict__ o1,
                                              unsigned short* __restrict__ oq,
                                              unsigned short* __restrict__ o2) {
  int idx = (blockIdx.x * 256 + threadIdx.x) * 8;
  const float* s; unsigned short* d; int off;
  if (idx < 65536)        { s = w1; d = o1; off = idx; }
  else if (idx < 114688)  { s = wq; d = oq; off = idx - 65536; }
  else                    { s = w2; d = o2; off = idx - 114688; }
  float4 a = *(const float4*)(s + off);
  float4 b = *(const float4*)(s + off + 4);
  us8 o = {f2bf(a.x), f2bf(a.y), f2bf(a.z), f2bf(a.w),
           f2bf(b.x), f2bf(b.y), f2bf(b.z), f2bf(b.w)};
  *(us8*)(d + off) = o;
}

// ---------------------------------------------------------------------------
// conv1 (fused transpose + fused bn1 partial stats).
// y1T[b][n][128] bf16 = w1 @ x. Block 64n x 128m, K=512 in 8 steps.
// Per-block channel partials (over bf16-rounded values) -> pS1/pQ1[c][256].
// grid (16, 1, 16).
// ---------------------------------------------------------------------------
__global__ __launch_bounds__(256) void k_conv1(const float* __restrict__ x,
                                               const unsigned short* __restrict__ W,
                                               unsigned short* __restrict__ y1T,
                                               float* __restrict__ pS1,
                                               float* __restrict__ pQ1) {
  constexpr int BS = 68;
  __shared__ unsigned short Bl[64 * BS];
  __shared__ float Sl[128], Ql[128];

  const int bb = blockIdx.z;
  const int n0 = blockIdx.x * 64;
  const int tid = threadIdx.x, lane = tid & 63, wv = tid >> 6;
  const int wn = wv & 1, wm = wv >> 1;
  const int i = lane & 15, g = lane >> 4;

  if (tid < 128) { Sl[tid] = 0.f; Ql[tid] = 0.f; }

  const int kb = tid >> 4, nb = tid & 15;

  f32x4 acc[2][4];
#pragma unroll
  for (int a = 0; a < 2; ++a)
#pragma unroll
    for (int b = 0; b < 4; ++b) acc[a][b] = {0.f, 0.f, 0.f, 0.f};

  float4 rv[4];
#pragma unroll
  for (int r = 0; r < 4; ++r)
    rv[r] = *(const float4*)(x + (((size_t)(bb * 512 + kb * 4 + r)) << 10) + n0 + nb * 4);

  for (int s = 0; s < 8; ++s) {
    bf8 wf[4][2];
#pragma unroll
    for (int b = 0; b < 4; ++b)
#pragma unroll
      for (int h = 0; h < 2; ++h)
        wf[b][h] = *(const bf8*)(W + (size_t)(wm * 64 + b * 16 + i) * 512 + s * 64 + h * 32 + g * 8);

    __syncthreads();
#pragma unroll
    for (int j = 0; j < 4; ++j) {
      us4 pk = {f2bf((&rv[0].x)[j]), f2bf((&rv[1].x)[j]),
                f2bf((&rv[2].x)[j]), f2bf((&rv[3].x)[j])};
      *(us4*)&Bl[(nb * 4 + j) * BS + kb * 4] = pk;
    }
    __syncthreads();

    if (s < 7) {
#pragma unroll
      for (int r = 0; r < 4; ++r)
        rv[r] = *(const float4*)(x + (((size_t)(bb * 512 + (s + 1) * 64 + kb * 4 + r)) << 10) + n0 + nb * 4);
    }

#pragma unroll
    for (int h = 0; h < 2; ++h) {
      bf8 af[2];
#pragma unroll
      for (int a = 0; a < 2; ++a)
        af[a] = *(const bf8*)&Bl[(wn * 32 + a * 16 + i) * BS + h * 32 + g * 8];
#pragma unroll
      for (int a = 0; a < 2; ++a)
#pragma unroll
        for (int b = 0; b < 4; ++b)
          acc[a][b] = __builtin_amdgcn_mfma_f32_16x16x32_bf16(wf[b][h], af[a], acc[a][b], 0, 0, 0);
    }
  }

  // epilogue: store y1T + accumulate bn1 partials on the ROUNDED values
#pragma unroll
  for (int a = 0; a < 2; ++a)
#pragma unroll
    for (int b = 0; b < 4; ++b) {
      const int n = n0 + wn * 32 + a * 16 + i;
      const int c = wm * 64 + b * 16 + 4 * g;
      us4 pk = {f2bf(acc[a][b][0]), f2bf(acc[a][b][1]), f2bf(acc[a][b][2]), f2bf(acc[a][b][3])};
      *(us4*)(y1T + ((size_t)(bb << 10) + n) * 128 + c) = pk;
    }

#pragma unroll
  for (int b = 0; b < 4; ++b) {
    float sb[4], qb[4];
#pragma unroll
    for (int r = 0; r < 4; ++r) {
      float v0 = b2f(f2bf(acc[0][b][r]));
      float v1 = b2f(f2bf(acc[1][b][r]));
      sb[r] = v0 + v1;
      qb[r] = v0 * v0 + v1 * v1;
    }
#pragma unroll
    for (int o = 1; o < 16; o <<= 1) {
#pragma unroll
      for (int r = 0; r < 4; ++r) {
        sb[r] += __shfl_xor(sb[r], o);
        qb[r] += __shfl_xor(qb[r], o);
      }
    }
    if (i == 0) {
#pragma unroll
      for (int r = 0; r < 4; ++r) {
        const int c = wm * 64 + b * 16 + 4 * g + r;
        atomicAdd(&Sl[c], sb[r]);
        atomicAdd(&Ql[c], qb[r]);
      }
    }
  }

  __syncthreads();
  const int blk = bb * 16 + blockIdx.x;   // 0..255
  if (tid < 128) {
    pS1[(size_t)tid * 256 + blk] = Sl[tid];
    pQ1[(size_t)tid * 256 + blk] = Ql[tid];
  }
}

// 128 blocks x 64 threads: reduce 256 partials per channel -> scl1/sht1.
__global__ __launch_bounds__(64) void k_bnfin1(const float* __restrict__ pS1,
                                               const float* __restrict__ pQ1,
                                               const float* __restrict__ g,
                                               const float* __restrict__ be,
                                               float* __restrict__ scl,
                                               float* __restrict__ sht) {
  const int c = blockIdx.x, t = threadIdx.x;
  float S = 0.f, Q = 0.f;
#pragma unroll
  for (int k = 0; k < 4; ++k) {
    S += pS1[(size_t)c * 256 + t + k * 64];
    Q += pQ1[(size_t)c * 256 + t + k * 64];
  }
#pragma unroll
  for (int o = 32; o > 0; o >>= 1) {
    S += __shfl_down(S, o);
    Q += __shfl_down(Q, o);
  }
  if (t == 0) {
    const float inv_n = 1.f / 16384.f;
    const float mean = S * inv_n, var = Q * inv_n - mean * mean;
    const float sc = rsqrtf(var + 1e-5f) * g[c];
    scl[c] = sc;
    sht[c] = be[c] - mean * sc;
  }
}

// ---------------------------------------------------------------------------
// qkv GEMM: reads y1T with fused bn1+relu. grid: (8, 6, 16); mt 0,1=q 2,3=k 4,5=v
// ---------------------------------------------------------------------------
__global__ __launch_bounds__(256) void k_qkv(const unsigned short* __restrict__ W,
                                             const unsigned short* __restrict__ Bact,
                                             const float* __restrict__ scl,
                                             const float* __restrict__ sht,
                                             const float* __restrict__ rw,
                                             const float* __restrict__ rh,
                                             unsigned short* __restrict__ out0,
                                             unsigned short* __restrict__ out1,
                                             unsigned short* __restrict__ out2) {
  constexpr int BS = 136;
  __shared__ unsigned short Blds[128 * BS];
  __shared__ float scl_s[128], sht_s[128];

  const int bb = blockIdx.z, mt = blockIdx.y;
  const int n0 = blockIdx.x * 128, m0 = mt * 64;
  const int tid = threadIdx.x, lane = tid & 63, wv = tid >> 6;
  const int wn = wv & 1, wm = wv >> 1;
  const int i = lane & 15, g = lane >> 4;

  const unsigned short* Bp = Bact + ((size_t)bb * NQ + n0) * 128;

  f32x4 acc[4][2];
#pragma unroll
  for (int a = 0; a < 4; ++a)
#pragma unroll
    for (int b = 0; b < 2; ++b) acc[a][b] = {0.f, 0.f, 0.f, 0.f};

  const int sn = tid >> 1;
  const int sk = (tid & 1) * 8;

  if (tid < 128) { scl_s[tid] = scl[tid]; sht_s[tid] = sht[tid]; }
  bf8 wf[2][4];
#pragma unroll
  for (int b = 0; b < 2; ++b)
#pragma unroll
    for (int h = 0; h < 4; ++h)
      wf[b][h] = *(const bf8*)(W + (size_t)(m0 + wm * 32 + b * 16 + i) * 128 + h * 32 + g * 8);
  __syncthreads();
#pragma unroll
  for (int p = 0; p < 8; ++p) {
    us8 v = *(const us8*)(Bp + (size_t)sn * 128 + sk + p * 16);
    const int kb = sk + p * 16;
    float scv[8], shv[8];
    *(float4*)scv = *(const float4*)&scl_s[kb];
    *(float4*)(scv + 4) = *(const float4*)&scl_s[kb + 4];
    *(float4*)shv = *(const float4*)&sht_s[kb];
    *(float4*)(shv + 4) = *(const float4*)&sht_s[kb + 4];
#pragma unroll
    for (int j = 0; j < 8; ++j)
      v[j] = f2bf(fmaxf(fmaf(b2f(v[j]), scv[j], shv[j]), 0.f));
    *(us8*)(&Blds[sn * BS + sk + p * 16]) = v;
  }
  __syncthreads();

  const bool actA = (mt >= 4);
  if (actA) {
#pragma unroll
    for (int h = 0; h < 4; ++h) {
      bf8 af[4];
#pragma unroll
      for (int a = 0; a < 4; ++a)
        af[a] = *(const bf8*)&Blds[(wn * 64 + a * 16 + i) * BS + h * 32 + g * 8];
#pragma unroll
      for (int a = 0; a < 4; ++a)
#pragma unroll
        for (int b = 0; b < 2; ++b)
          acc[a][b] = __builtin_amdgcn_mfma_f32_16x16x32_bf16(af[a], wf[b][h], acc[a][b], 0, 0, 0);
    }
  } else {
#pragma unroll
    for (int h = 0; h < 4; ++h) {
      bf8 af[4];
#pragma unroll
      for (int a = 0; a < 4; ++a)
        af[a] = *(const bf8*)&Blds[(wn * 64 + a * 16 + i) * BS + h * 32 + g * 8];
#pragma unroll
      for (int a = 0; a < 4; ++a)
#pragma unroll
        for (int b = 0; b < 2; ++b)
          acc[a][b] = __builtin_amdgcn_mfma_f32_16x16x32_bf16(wf[b][h], af[a], acc[a][b], 0, 0, 0);
    }
  }

  if (mt < 2) {           // q: [bh][n][32], scaled
#pragma unroll
    for (int a = 0; a < 4; ++a)
#pragma unroll
      for (int b = 0; b < 2; ++b) {
        const int n = n0 + wn * 64 + a * 16 + i;
        const int c = m0 + wm * 32 + b * 16 + 4 * g;
        const int hh = c >> 5, d = c & 31;
        us4 pk = {f2bf(acc[a][b][0] * QSCALE), f2bf(acc[a][b][1] * QSCALE),
                  f2bf(acc[a][b][2] * QSCALE), f2bf(acc[a][b][3] * QSCALE)};
        *(us4*)(out0 + (((size_t)(bb * 4 + hh) << 10) + n) * 32 + d) = pk;
      }
  } else if (mt < 4) {    // k: [bh][n][32], + r bias
#pragma unroll
    for (int a = 0; a < 4; ++a)
#pragma unroll
      for (int b = 0; b < 2; ++b) {
        const int n = n0 + wn * 64 + a * 16 + i;
        const int c = (m0 - 128) + wm * 32 + b * 16 + 4 * g;
        const int hh = c >> 5, d = c & 31;
        const int wcol = n & 31, hrow = n >> 5;
        float vv[4];
#pragma unroll
        for (int r = 0; r < 4; ++r)
          vv[r] = acc[a][b][r] + rw[(c + r) * 32 + wcol] + rh[(c + r) * 32 + hrow];
        us4 pk = {f2bf(vv[0]), f2bf(vv[1]), f2bf(vv[2]), f2bf(vv[3])};
        *(us4*)(out1 + (((size_t)(bb * 4 + hh) << 10) + n) * 32 + d) = pk;
      }
  } else {                // v: [bh][32][1024] (n-run per lane)
#pragma unroll
    for (int a = 0; a < 4; ++a)
#pragma unroll
      for (int b = 0; b < 2; ++b) {
        const int c = (m0 - 256) + wm * 32 + b * 16 + i;
        const int nb = n0 + wn * 64 + a * 16 + 4 * g;
        const int hh = c >> 5, dd = c & 31;
        us4 pk = {f2bf(acc[a][b][0]), f2bf(acc[a][b][1]), f2bf(acc[a][b][2]), f2bf(acc[a][b][3])};
        *(us4*)(out2 + (((size_t)(bb * 4 + hh) * 32 + dd) << 10) + nb) = pk;
      }
  }
}

// ---------------------------------------------------------------------------
// MFMA flash attention (r4-proven core); writes fp32 aoT [b][n][128].
// ---------------------------------------------------------------------------
__global__ __launch_bounds__(256) void k_attn_mfma(const unsigned short* __restrict__ qs,
                                                   const unsigned short* __restrict__ kt,
                                                   const unsigned short* __restrict__ vt,
                                                   float* __restrict__ aoT) {
  const int bh   = blockIdx.y;
  const int tid  = threadIdx.x;
  const int lane = tid & 63;
  const int wv   = tid >> 6;
  const int i    = lane & 15;
  const int g    = lane >> 4;
  const int n0w  = blockIdx.x * 64 + wv * 16;

  __shared__ unsigned short Ks[64 * 56];
  __shared__ unsigned short Vt[32 * 72];

  const bf8 qf = *reinterpret_cast<const bf8*>(
      qs + ((size_t)bh * NQ + n0w + i) * 32 + g * 8);

  f32x4 o0 = {0.f, 0.f, 0.f, 0.f}, o1 = {0.f, 0.f, 0.f, 0.f};
  float m = -1e30f, lsum = 0.f;

  const unsigned short* kb = kt + (size_t)bh * NQ * 32;
  const unsigned short* vb = vt + (size_t)bh * 32 * NQ;

  const int skey = tid >> 2, sds = (tid & 3) * 8;
  const int svd  = tid >> 3, svn = (tid & 7) * 8;

  for (int k0 = 0; k0 < NQ; k0 += 64) {
    bf8 kvld = *reinterpret_cast<const bf8*>(kb + (size_t)(k0 + skey) * 32 + sds);
    bf8 vvld = *reinterpret_cast<const bf8*>(vb + (size_t)svd * NQ + k0 + svn);
    __syncthreads();
    *reinterpret_cast<bf8*>(&Ks[skey * 56 + sds]) = kvld;
    *reinterpret_cast<bf8*>(&Vt[svd * 72 + svn])  = vvld;
    __syncthreads();

    f32x4 st[4];
    const f32x4 zero = {0.f, 0.f, 0.f, 0.f};
#pragma unroll
    for (int t = 0; t < 4; ++t) {
      bf8 kf = *reinterpret_cast<const bf8*>(&Ks[(t * 16 + i) * 56 + g * 8]);
      st[t] = __builtin_amdgcn_mfma_f32_16x16x32_bf16(kf, qf, zero, 0, 0, 0);
    }

    float tmax = st[0][0];
#pragma unroll
    for (int t = 0; t < 4; ++t)
#pragma unroll
      for (int r = 0; r < 4; ++r) tmax = fmaxf(tmax, st[t][r]);
    tmax = fmaxf(tmax, __shfl_xor(tmax, 16));
    tmax = fmaxf(tmax, __shfl_xor(tmax, 32));

    const float mn   = fmaxf(m, tmax);
    const float corr = fast_exp2(m - mn);
    m = mn;

    float ps = 0.f;
    unsigned int pk[4][2];
#pragma unroll
    for (int t = 0; t < 4; ++t) {
      float p0 = fast_exp2(st[t][0] - mn);
      float p1 = fast_exp2(st[t][1] - mn);
      float p2 = fast_exp2(st[t][2] - mn);
      float p3 = fast_exp2(st[t][3] - mn);
      ps += (p0 + p1) + (p2 + p3);
      unsigned int pa, pb;
      asm("v_cvt_pk_bf16_f32 %0, %1, %2" : "=v"(pa) : "v"(p0), "v"(p1));
      asm("v_cvt_pk_bf16_f32 %0, %1, %2" : "=v"(pb) : "v"(p2), "v"(p3));
      pk[t][0] = pa; pk[t][1] = pb;
    }
    ps += __shfl_xor(ps, 16);
    ps += __shfl_xor(ps, 32);
    lsum = lsum * corr + ps;
#pragma unroll
    for (int r = 0; r < 4; ++r) { o0[r] *= corr; o1[r] *= corr; }

    const int src0 = ((g & 1) << 5) + i;
    const int src1 = src0 + 16;
    const bool hi = (g >= 2);
#pragma unroll
    for (int s = 0; s < 2; ++s) {
      int a0 = __shfl((int)pk[2 * s][0], src0);
      int a1 = __shfl((int)pk[2 * s][1], src0);
      int a2 = __shfl((int)pk[2 * s][0], src1);
      int a3 = __shfl((int)pk[2 * s][1], src1);
      int b0 = __shfl((int)pk[2 * s + 1][0], src0);
      int b1 = __shfl((int)pk[2 * s + 1][1], src0);
      int b2 = __shfl((int)pk[2 * s + 1][0], src1);
      int b3 = __shfl((int)pk[2 * s + 1][1], src1);
      union { int d[4]; bf8 v; } pf;
      pf.d[0] = hi ? b0 : a0;
      pf.d[1] = hi ? b1 : a1;
      pf.d[2] = hi ? b2 : a2;
      pf.d[3] = hi ? b3 : a3;
      bf8 vf0 = *reinterpret_cast<const bf8*>(&Vt[(i)      * 72 + s * 32 + g * 8]);
      bf8 vf1 = *reinterpret_cast<const bf8*>(&Vt[(16 + i) * 72 + s * 32 + g * 8]);
      o0 = __builtin_amdgcn_mfma_f32_16x16x32_bf16(vf0, pf.v, o0, 0, 0, 0);
      o1 = __builtin_amdgcn_mfma_f32_16x16x32_bf16(vf1, pf.v, o1, 0, 0, 0);
    }
  }

  const float inv = 1.f / lsum;
  float* dst = aoT + (((size_t)(bh >> 2) << 10) + n0w + i) * 128 + (bh & 3) * 32 + 4 * g;
  f32x4 p0 = {o0[0] * inv, o0[1] * inv, o0[2] * inv, o0[3] * inv};
  f32x4 p1 = {o1[0] * inv, o1[1] * inv, o1[2] * inv, o1[3] * inv};
  *(f32x4*)dst        = p0;
  *(f32x4*)(dst + 16) = p1;
}

// ---------------------------------------------------------------------------
// conv2 stats pass: split-precision MFMA, NO y2 store; bn2 per-block partials.
// Block 64n x 256m (4 m-subtiles), 4 waves. grid (16, 2, 16).
// ---------------------------------------------------------------------------
__global__ __launch_bounds__(256) void k_stat2(const unsigned short* __restrict__ W,
                                               const float* __restrict__ Aof,
                                               float* __restrict__ pBS,
                                               float* __restrict__ pBQ) {
  constexpr int BS = 264;
  __shared__ unsigned short Blds[64 * BS];
  __shared__ float Sl[256], Ql[256];
  const int bb = blockIdx.z;
  const int mh = blockIdx.y;
  const int n0 = blockIdx.x * 64;
  const int tid = threadIdx.x, lane = tid & 63, wv = tid >> 6;
  const int wn = wv & 1, wm = wv >> 1;
  const int i = lane & 15, g = lane >> 4;

  Sl[tid] = 0.f; Ql[tid] = 0.f;

  const int sn = tid >> 2, sk = (tid & 3) * 32;
  const float* src = Aof + (((size_t)(bb << 10)) + n0 + sn) * 128 + sk;
#pragma unroll
  for (int p = 0; p < 4; ++p) {
    float4 f0 = *(const float4*)(src + p * 8);
    float4 f1 = *(const float4*)(src + p * 8 + 4);
    float fv[8] = {f0.x, f0.y, f0.z, f0.w, f1.x, f1.y, f1.z, f1.w};
    us8 hi, lo;
#pragma unroll
    for (int j = 0; j < 8; ++j) {
      unsigned short h16 = f2bf(fv[j]);
      hi[j] = h16;
      lo[j] = f2bf(fv[j] - b2f(h16));
    }
    *(us8*)&Blds[sn * BS + sk + p * 8]       = hi;
    *(us8*)&Blds[sn * BS + 128 + sk + p * 8] = lo;
  }
  __syncthreads();

  auto loadw = [&](bf8 (&wf)[2][4], int lp) {
    const int mt = mh * 4 + lp;
#pragma unroll
    for (int b = 0; b < 2; ++b)
#pragma unroll
      for (int h = 0; h < 4; ++h)
        wf[b][h] = *(const bf8*)(W + (size_t)(mt * 64 + wm * 32 + b * 16 + i) * 128 + h * 32 + g * 8);
  };

  auto step = [&](bf8 (&wf)[2][4], int lp) {
    f32x4 acc[2][2];
#pragma unroll
    for (int a = 0; a < 2; ++a)
#pragma unroll
      for (int b = 0; b < 2; ++b) acc[a][b] = {0.f, 0.f, 0.f, 0.f};
#pragma unroll
    for (int h = 0; h < 4; ++h) {
      bf8 ah[2], al[2];
#pragma unroll
      for (int a = 0; a < 2; ++a) {
        ah[a] = *(const bf8*)&Blds[(wn * 32 + a * 16 + i) * BS + h * 32 + g * 8];
        al[a] = *(const bf8*)&Blds[(wn * 32 + a * 16 + i) * BS + 128 + h * 32 + g * 8];
      }
#pragma unroll
      for (int a = 0; a < 2; ++a)
#pragma unroll
        for (int b = 0; b < 2; ++b) {
          acc[a][b] = __builtin_amdgcn_mfma_f32_16x16x32_bf16(ah[a], wf[b][h], acc[a][b], 0, 0, 0);
          acc[a][b] = __builtin_amdgcn_mfma_f32_16x16x32_bf16(al[a], wf[b][h], acc[a][b], 0, 0, 0);
        }
    }
#pragma unroll
    for (int b = 0; b < 2; ++b) {
      float s = 0.f, q = 0.f;
#pragma unroll
      for (int a = 0; a < 2; ++a)
#pragma unroll
        for (int r = 0; r < 4; ++r) {
          float v = acc[a][b][r];
          s += v; q += v * v;
        }
      s += __shfl_xor(s, 16); s += __shfl_xor(s, 32);
      q += __shfl_xor(q, 16); q += __shfl_xor(q, 32);
      if ((lane & 48) == 0) {
        const int cl = lp * 64 + wm * 32 + b * 16 + i;
        atomicAdd(&Sl[cl], s);
        atomicAdd(&Ql[cl], q);
      }
    }
  };

  bf8 wfA[2][4], wfB[2][4];
  loadw(wfA, 0);
  loadw(wfB, 1);
  step(wfA, 0);
  loadw(wfA, 2);
  step(wfB, 1);
  loadw(wfB, 3);
  step(wfA, 2);
  step(wfB, 3);

  __syncthreads();
  const int pidx = bb * 16 + blockIdx.x;
  pBS[(size_t)(mh * 256 + tid) * 256 + pidx] = Sl[tid];
  pBQ[(size_t)(mh * 256 + tid) * 256 + pidx] = Ql[tid];
}

// 512 blocks x 64 threads: reduce 256 partials per channel.
__global__ __launch_bounds__(64) void k_bnfin2(const float* __restrict__ pBS,
                                               const float* __restrict__ pBQ,
                                               const float* __restrict__ g,
                                               const float* __restrict__ be,
                                               float* __restrict__ scl,
                                               float* __restrict__ sht) {
  const int c = blockIdx.x, t = threadIdx.x;
  float S = 0.f, Q = 0.f;
#pragma unroll
  for (int k = 0; k < 4; ++k) {
    S += pBS[(size_t)c * 256 + t + k * 64];
    Q += pBQ[(size_t)c * 256 + t + k * 64];
  }
#pragma unroll
  for (int o = 32; o > 0; o >>= 1) {
    S += __shfl_down(S, o);
    Q += __shfl_down(Q, o);
  }
  if (t == 0) {
    const float inv_n = 1.f / 16384.f;
    const float mean = S * inv_n, var = Q * inv_n - mean * mean;
    const float sc = rsqrtf(var + 1e-5f) * g[c];
    scl[c] = sc;
    sht[c] = be[c] - mean * sc;
  }
}

// ---------------------------------------------------------------------------
// final pass: recompute conv2 (identical staging/MFMA order as k_stat2),
// apply bn2 + residual + relu, write out. grid (16, 2, 16).
// ---------------------------------------------------------------------------
__global__ __launch_bounds__(256) void k_final2(const unsigned short* __restrict__ W,
                                                const float* __restrict__ Aof,
                                                const float* __restrict__ x,
                                                const float* __restrict__ scl2,
                                                const float* __restrict__ sht2,
                                                float* __restrict__ out) {
  constexpr int BS = 264;
  __shared__ unsigned short Blds[64 * BS];
  __shared__ float scl_s[256], sht_s[256];
  const int bb = blockIdx.z;
  const int mh = blockIdx.y;
  const int n0 = blockIdx.x * 64;
  const int tid = threadIdx.x, lane = tid & 63, wv = tid >> 6;
  const int wn = wv & 1, wm = wv >> 1;
  const int i = lane & 15, g = lane >> 4;

  scl_s[tid] = scl2[mh * 256 + tid];
  sht_s[tid] = sht2[mh * 256 + tid];

  const int sn = tid >> 2, sk = (tid & 3) * 32;
  const float* src = Aof + (((size_t)(bb << 10)) + n0 + sn) * 128 + sk;
#pragma unroll
  for (int p = 0; p < 4; ++p) {
    float4 f0 = *(const float4*)(src + p * 8);
    float4 f1 = *(const float4*)(src + p * 8 + 4);
    float fv[8] = {f0.x, f0.y, f0.z, f0.w, f1.x, f1.y, f1.z, f1.w};
    us8 hi, lo;
#pragma unroll
    for (int j = 0; j < 8; ++j) {
      unsigned short h16 = f2bf(fv[j]);
      hi[j] = h16;
      lo[j] = f2bf(fv[j] - b2f(h16));
    }
    *(us8*)&Blds[sn * BS + sk + p * 8]       = hi;
    *(us8*)&Blds[sn * BS + 128 + sk + p * 8] = lo;
  }
  __syncthreads();

  auto loadw = [&](bf8 (&wf)[2][4], int lp) {
    const int mt = mh * 4 + lp;
#pragma unroll
    for (int b = 0; b < 2; ++b)
#pragma unroll
      for (int h = 0; h < 4; ++h)
        wf[b][h] = *(const bf8*)(W + (size_t)(mt * 64 + wm * 32 + b * 16 + i) * 128 + h * 32 + g * 8);
  };

  auto step = [&](bf8 (&wf)[2][4], int lp) {
    const int mt = mh * 4 + lp;
    f32x4 acc[2][2];
#pragma unroll
    for (int a = 0; a < 2; ++a)
#pragma unroll
      for (int b = 0; b < 2; ++b) acc[a][b] = {0.f, 0.f, 0.f, 0.f};
#pragma unroll
    for (int h = 0; h < 4; ++h) {
      bf8 ah[2], al[2];
#pragma unroll
      for (int a = 0; a < 2; ++a) {
        ah[a] = *(const bf8*)&Blds[(wn * 32 + a * 16 + i) * BS + h * 32 + g * 8];
        al[a] = *(const bf8*)&Blds[(wn * 32 + a * 16 + i) * BS + 128 + h * 32 + g * 8];
      }
#pragma unroll
      for (int a = 0; a < 2; ++a)
#pragma unroll
        for (int b = 0; b < 2; ++b) {
          acc[a][b] = __builtin_amdgcn_mfma_f32_16x16x32_bf16(ah[a], wf[b][h], acc[a][b], 0, 0, 0);
          acc[a][b] = __builtin_amdgcn_mfma_f32_16x16x32_bf16(al[a], wf[b][h], acc[a][b], 0, 0, 0);
        }
    }
#pragma unroll
    for (int a = 0; a < 2; ++a)
#pragma unroll
      for (int b = 0; b < 2; ++b) {
        const int c = mt * 64 + wm * 32 + b * 16 + i;
        const int cl = lp * 64 + wm * 32 + b * 16 + i;
        const int nb = n0 + wn * 32 + a * 16 + 4 * g;
        const float sc = scl_s[cl], sh = sht_s[cl];
        const size_t off = (((size_t)(bb * 512 + c)) << 10) + nb;
        float4 xv = *(const float4*)(x + off);
        f32x4 o;
        o[0] = fmaxf(acc[a][b][0] * sc + sh + xv.x, 0.f);
        o[1] = fmaxf(acc[a][b][1] * sc + sh + xv.y, 0.f);
        o[2] = fmaxf(acc[a][b][2] * sc + sh + xv.z, 0.f);
        o[3] = fmaxf(acc[a][b][3] * sc + sh + xv.w, 0.f);
        *(f32x4*)(out + off) = o;
      }
  };

  bf8 wfA[2][4], wfB[2][4];
  loadw(wfA, 0);
  loadw(wfB, 1);
  step(wfA, 0);
  loadw(wfA, 2);
  step(wfB, 1);
  loadw(wfB, 3);
  step(wfA, 2);
  step(wfB, 3);
}

// ---------------------------------------------------------------------------
extern "C" void kernel_launch(void* const* d_in, const int* in_sizes, int n_in,
                              void* d_out, int out_size, void* d_ws, size_t ws_size,
                              hipStream_t stream) {
  (void)in_sizes; (void)n_in; (void)out_size; (void)ws_size;
  const float* x    = (const float*)d_in[0];
  const float* w1   = (const float*)d_in[1];
  const float* g1   = (const float*)d_in[2];
  const float* b1   = (const float*)d_in[3];
  const float* wqkv = (const float*)d_in[4];
  const float* rw   = (const float*)d_in[5];
  const float* rh   = (const float*)d_in[6];
  const float* w2   = (const float*)d_in[7];
  const float* g2   = (const float*)d_in[8];
  const float* b2   = (const float*)d_in[9];
  float* out = (float*)d_out;
  char* base = (char*)d_ws;

  // Workspace (bytes): aoT fp32 [0,8M) | y1T [8,12) | qs [12,16) | kt [16,20)
  // | vt [20,24) | weights bf16 [24M,+352K) | partials/scalars [25M..26.3M)
  float*          aoT = (float*)(base);
  unsigned short* y1T = (unsigned short*)(base + (8u  << 20));
  unsigned short* qs  = (unsigned short*)(base + (12u << 20));
  unsigned short* kt  = (unsigned short*)(base + (16u << 20));
  unsigned short* vt  = (unsigned short*)(base + (20u << 20));
  unsigned short* wb1 = (unsigned short*)(base + (24u << 20));
  unsigned short* wbq = wb1 + 65536;
  unsigned short* wb2 = wbq + 49152;
  float* pS1  = (float*)(base + (25u << 20));  // 128*256
  float* pQ1  = pS1 + 32768;
  float* pBS  = pQ1 + 32768;                   // 512*256
  float* pBQ  = pBS + 131072;
  float* scl1 = pBQ + 131072;
  float* sht1 = scl1 + 128;
  float* scl2 = sht1 + 128;
  float* sht2 = scl2 + 512;

  // 1) weights -> bf16
  k_wcvt<<<88, 256, 0, stream>>>(w1, wqkv, w2, wb1, wbq, wb2);
  // 2) conv1 (fused transpose + bn1 partials) -> y1T, pS1/pQ1
  k_conv1<<<dim3(16, 1, BATCH), 256, 0, stream>>>(x, wb1, y1T, pS1, pQ1);
  // 3) bn1 finalize
  k_bnfin1<<<128, 64, 0, stream>>>(pS1, pQ1, g1, b1, scl1, sht1);
  // 4) qkv (MFMA, bn1+relu fused) -> q,k'(+r),v bf16
  k_qkv<<<dim3(8, 6, BATCH), 256, 0, stream>>>(wbq, y1T, scl1, sht1,
                                               rw, rh, qs, kt, vt);
  // 5) flash attention -> aoT fp32 [b][n][128]
  k_attn_mfma<<<dim3(NQ / 64, BATCH * 4), 256, 0, stream>>>(qs, kt, vt, aoT);
  // 6) conv2 stats pass (no y2) -> pBS/pBQ
  k_stat2<<<dim3(16, 2, BATCH), 256, 0, stream>>>(wb2, aoT, pBS, pBQ);
  // 7) bn2 finalize
  k_bnfin2<<<512, 64, 0, stream>>>(pBS, pBQ, g2, b2, scl2, sht2);
  // 8) final: recompute conv2 + bn2 + residual + relu -> out
  k_final2<<<dim3(16, 2, BATCH), 256, 0, stream>>>(wb2, aoT, x, scl2, sht2, out);
}

// Round 10
// 104.676 us; speedup vs baseline: 4.6126x; 1.0292x over previous
//
#include <hip/hip_runtime.h>
#include <cstddef>
#include <cstdint>

constexpr int BATCH = 16;
constexpr int NQ    = 1024;
constexpr float QSCALE = 0.17677669529663687f * 1.4426950408889634f; // 32^-0.5 * log2e

typedef __attribute__((ext_vector_type(8))) short bf8;            // MFMA operand (8 bf16)
typedef __attribute__((ext_vector_type(4))) float f32x4;
typedef __attribute__((ext_vector_type(4))) unsigned short us4;
typedef __attribute__((ext_vector_type(8))) unsigned short us8;

__device__ inline unsigned short f2bf(float x) {
  union { float f; uint32_t u; } c{x};
  uint32_t r = c.u + 0x7fffu + ((c.u >> 16) & 1u);   // RNE
  return (unsigned short)(r >> 16);
}
__device__ inline float b2f(unsigned short v) {
  union { uint32_t u; float f; } c{(uint32_t)v << 16};
  return c.f;
}
__device__ inline float fast_exp2(float x) {
#if __has_builtin(__builtin_amdgcn_exp2f)
  return __builtin_amdgcn_exp2f(x);
#else
  return exp2f(x);
#endif
}

// ---------------------------------------------------------------------------
// Weights -> bf16.
// ---------------------------------------------------------------------------
__global__ __launch_bounds__(256) void k_wcvt(const float* __restrict__ w1,
                                              const float* __restrict__ wq,
                                              const float* __restrict__ w2,
                                              unsigned short* __restrict__ o1,
                                              unsigned short* __restrict__ oq,
                                              unsigned short* __restrict__ o2) {
  int idx = (blockIdx.x * 256 + threadIdx.x) * 8;
  const float* s; unsigned short* d; int off;
  if (idx < 65536)        { s = w1; d = o1; off = idx; }
  else if (idx < 114688)  { s = wq; d = oq; off = idx - 65536; }
  else                    { s = w2; d = o2; off = idx - 114688; }
  float4 a = *(const float4*)(s + off);
  float4 b = *(const float4*)(s + off + 4);
  us8 o = {f2bf(a.x), f2bf(a.y), f2bf(a.z), f2bf(a.w),
           f2bf(b.x), f2bf(b.y), f2bf(b.z), f2bf(b.w)};
  *(us8*)(d + off) = o;
}

// ---------------------------------------------------------------------------
// conv1 (fused transpose + fused bn1 partial stats).  grid (16, 1, 16).
// ---------------------------------------------------------------------------
__global__ __launch_bounds__(256) void k_conv1(const float* __restrict__ x,
                                               const unsigned short* __restrict__ W,
                                               unsigned short* __restrict__ y1T,
                                               float* __restrict__ pS1,
                                               float* __restrict__ pQ1) {
  constexpr int BS = 68;
  __shared__ unsigned short Bl[64 * BS];
  __shared__ float Sl[128], Ql[128];

  const int bb = blockIdx.z;
  const int n0 = blockIdx.x * 64;
  const int tid = threadIdx.x, lane = tid & 63, wv = tid >> 6;
  const int wn = wv & 1, wm = wv >> 1;
  const int i = lane & 15, g = lane >> 4;

  if (tid < 128) { Sl[tid] = 0.f; Ql[tid] = 0.f; }

  const int kb = tid >> 4, nb = tid & 15;

  f32x4 acc[2][4];
#pragma unroll
  for (int a = 0; a < 2; ++a)
#pragma unroll
    for (int b = 0; b < 4; ++b) acc[a][b] = {0.f, 0.f, 0.f, 0.f};

  float4 rv[4];
#pragma unroll
  for (int r = 0; r < 4; ++r)
    rv[r] = *(const float4*)(x + (((size_t)(bb * 512 + kb * 4 + r)) << 10) + n0 + nb * 4);

  for (int s = 0; s < 8; ++s) {
    bf8 wf[4][2];
#pragma unroll
    for (int b = 0; b < 4; ++b)
#pragma unroll
      for (int h = 0; h < 2; ++h)
        wf[b][h] = *(const bf8*)(W + (size_t)(wm * 64 + b * 16 + i) * 512 + s * 64 + h * 32 + g * 8);

    __syncthreads();
#pragma unroll
    for (int j = 0; j < 4; ++j) {
      us4 pk = {f2bf((&rv[0].x)[j]), f2bf((&rv[1].x)[j]),
                f2bf((&rv[2].x)[j]), f2bf((&rv[3].x)[j])};
      *(us4*)&Bl[(nb * 4 + j) * BS + kb * 4] = pk;
    }
    __syncthreads();

    if (s < 7) {
#pragma unroll
      for (int r = 0; r < 4; ++r)
        rv[r] = *(const float4*)(x + (((size_t)(bb * 512 + (s + 1) * 64 + kb * 4 + r)) << 10) + n0 + nb * 4);
    }

#pragma unroll
    for (int h = 0; h < 2; ++h) {
      bf8 af[2];
#pragma unroll
      for (int a = 0; a < 2; ++a)
        af[a] = *(const bf8*)&Bl[(wn * 32 + a * 16 + i) * BS + h * 32 + g * 8];
#pragma unroll
      for (int a = 0; a < 2; ++a)
#pragma unroll
        for (int b = 0; b < 4; ++b)
          acc[a][b] = __builtin_amdgcn_mfma_f32_16x16x32_bf16(wf[b][h], af[a], acc[a][b], 0, 0, 0);
    }
  }

#pragma unroll
  for (int a = 0; a < 2; ++a)
#pragma unroll
    for (int b = 0; b < 4; ++b) {
      const int n = n0 + wn * 32 + a * 16 + i;
      const int c = wm * 64 + b * 16 + 4 * g;
      us4 pk = {f2bf(acc[a][b][0]), f2bf(acc[a][b][1]), f2bf(acc[a][b][2]), f2bf(acc[a][b][3])};
      *(us4*)(y1T + ((size_t)(bb << 10) + n) * 128 + c) = pk;
    }

#pragma unroll
  for (int b = 0; b < 4; ++b) {
    float sb[4], qb[4];
#pragma unroll
    for (int r = 0; r < 4; ++r) {
      float v0 = b2f(f2bf(acc[0][b][r]));
      float v1 = b2f(f2bf(acc[1][b][r]));
      sb[r] = v0 + v1;
      qb[r] = v0 * v0 + v1 * v1;
    }
#pragma unroll
    for (int o = 1; o < 16; o <<= 1) {
#pragma unroll
      for (int r = 0; r < 4; ++r) {
        sb[r] += __shfl_xor(sb[r], o);
        qb[r] += __shfl_xor(qb[r], o);
      }
    }
    if (i == 0) {
#pragma unroll
      for (int r = 0; r < 4; ++r) {
        const int c = wm * 64 + b * 16 + 4 * g + r;
        atomicAdd(&Sl[c], sb[r]);
        atomicAdd(&Ql[c], qb[r]);
      }
    }
  }

  __syncthreads();
  const int blk = bb * 16 + blockIdx.x;
  if (tid < 128) {
    pS1[(size_t)tid * 256 + blk] = Sl[tid];
    pQ1[(size_t)tid * 256 + blk] = Ql[tid];
  }
}

// 128 blocks x 64 threads: reduce 256 partials per channel -> scl1/sht1.
__global__ __launch_bounds__(64) void k_bnfin1(const float* __restrict__ pS1,
                                               const float* __restrict__ pQ1,
                                               const float* __restrict__ g,
                                               const float* __restrict__ be,
                                               float* __restrict__ scl,
                                               float* __restrict__ sht) {
  const int c = blockIdx.x, t = threadIdx.x;
  float S = 0.f, Q = 0.f;
#pragma unroll
  for (int k = 0; k < 4; ++k) {
    S += pS1[(size_t)c * 256 + t + k * 64];
    Q += pQ1[(size_t)c * 256 + t + k * 64];
  }
#pragma unroll
  for (int o = 32; o > 0; o >>= 1) {
    S += __shfl_down(S, o);
    Q += __shfl_down(Q, o);
  }
  if (t == 0) {
    const float inv_n = 1.f / 16384.f;
    const float mean = S * inv_n, var = Q * inv_n - mean * mean;
    const float sc = rsqrtf(var + 1e-5f) * g[c];
    scl[c] = sc;
    sht[c] = be[c] - mean * sc;
  }
}

// ---------------------------------------------------------------------------
// qkv GEMM: stage y1T tile ONCE (bn1+relu fused), compute q,k,v against it.
// grid (8, 2, 16); blockIdx.y = half (64-channel half of each of q/k/v).
// ---------------------------------------------------------------------------
__global__ __launch_bounds__(256) void k_qkv(const unsigned short* __restrict__ W,
                                             const unsigned short* __restrict__ Bact,
                                             const float* __restrict__ scl,
                                             const float* __restrict__ sht,
                                             const float* __restrict__ rw,
                                             const float* __restrict__ rh,
                                             unsigned short* __restrict__ out0,
                                             unsigned short* __restrict__ out1,
                                             unsigned short* __restrict__ out2) {
  constexpr int BS = 136;
  __shared__ unsigned short Blds[128 * BS];
  __shared__ float scl_s[128], sht_s[128];

  const int bb = blockIdx.z, half = blockIdx.y;
  const int n0 = blockIdx.x * 128;
  const int tid = threadIdx.x, lane = tid & 63, wv = tid >> 6;
  const int wn = wv & 1, wm = wv >> 1;
  const int i = lane & 15, g = lane >> 4;

  const unsigned short* Bp = Bact + ((size_t)bb * NQ + n0) * 128;

  const int sn = tid >> 1;
  const int sk = (tid & 1) * 8;

  if (tid < 128) { scl_s[tid] = scl[tid]; sht_s[tid] = sht[tid]; }

  auto loadw = [&](bf8 (&wf)[2][4], int typ) {
    const int m0 = typ * 128 + half * 64;
#pragma unroll
    for (int b = 0; b < 2; ++b)
#pragma unroll
      for (int h = 0; h < 4; ++h)
        wf[b][h] = *(const bf8*)(W + (size_t)(m0 + wm * 32 + b * 16 + i) * 128 + h * 32 + g * 8);
  };

  bf8 wf0[2][4], wf1[2][4];
  loadw(wf0, 0);
  __syncthreads();                        // scl_s ready

#pragma unroll
  for (int p = 0; p < 8; ++p) {
    us8 v = *(const us8*)(Bp + (size_t)sn * 128 + sk + p * 16);
    const int kb = sk + p * 16;
    float scv[8], shv[8];
    *(float4*)scv = *(const float4*)&scl_s[kb];
    *(float4*)(scv + 4) = *(const float4*)&scl_s[kb + 4];
    *(float4*)shv = *(const float4*)&sht_s[kb];
    *(float4*)(shv + 4) = *(const float4*)&sht_s[kb + 4];
#pragma unroll
    for (int j = 0; j < 8; ++j)
      v[j] = f2bf(fmaxf(fmaf(b2f(v[j]), scv[j], shv[j]), 0.f));
    *(us8*)(&Blds[sn * BS + sk + p * 16]) = v;
  }
  __syncthreads();

  f32x4 acc[4][2];

  auto gemmWA = [&](bf8 (&wf)[2][4]) {    // D = W * act  (c-run, n-lane)
#pragma unroll
    for (int a = 0; a < 4; ++a)
#pragma unroll
      for (int b = 0; b < 2; ++b) acc[a][b] = {0.f, 0.f, 0.f, 0.f};
#pragma unroll
    for (int h = 0; h < 4; ++h) {
      bf8 af[4];
#pragma unroll
      for (int a = 0; a < 4; ++a)
        af[a] = *(const bf8*)&Blds[(wn * 64 + a * 16 + i) * BS + h * 32 + g * 8];
#pragma unroll
      for (int a = 0; a < 4; ++a)
#pragma unroll
        for (int b = 0; b < 2; ++b)
          acc[a][b] = __builtin_amdgcn_mfma_f32_16x16x32_bf16(wf[b][h], af[a], acc[a][b], 0, 0, 0);
    }
  };
  auto gemmAW = [&](bf8 (&wf)[2][4]) {    // D = act * W  (n-run, c-lane)
#pragma unroll
    for (int a = 0; a < 4; ++a)
#pragma unroll
      for (int b = 0; b < 2; ++b) acc[a][b] = {0.f, 0.f, 0.f, 0.f};
#pragma unroll
    for (int h = 0; h < 4; ++h) {
      bf8 af[4];
#pragma unroll
      for (int a = 0; a < 4; ++a)
        af[a] = *(const bf8*)&Blds[(wn * 64 + a * 16 + i) * BS + h * 32 + g * 8];
#pragma unroll
      for (int a = 0; a < 4; ++a)
#pragma unroll
        for (int b = 0; b < 2; ++b)
          acc[a][b] = __builtin_amdgcn_mfma_f32_16x16x32_bf16(af[a], wf[b][h], acc[a][b], 0, 0, 0);
    }
  };

  // ---- q (typ 0) ----
  loadw(wf1, 1);
  gemmWA(wf0);
#pragma unroll
  for (int a = 0; a < 4; ++a)
#pragma unroll
    for (int b = 0; b < 2; ++b) {
      const int n = n0 + wn * 64 + a * 16 + i;
      const int c = half * 64 + wm * 32 + b * 16 + 4 * g;
      const int hh = c >> 5, d = c & 31;
      us4 pk = {f2bf(acc[a][b][0] * QSCALE), f2bf(acc[a][b][1] * QSCALE),
                f2bf(acc[a][b][2] * QSCALE), f2bf(acc[a][b][3] * QSCALE)};
      *(us4*)(out0 + (((size_t)(bb * 4 + hh) << 10) + n) * 32 + d) = pk;
    }

  // ---- k (typ 1) ----
  loadw(wf0, 2);
  gemmWA(wf1);
#pragma unroll
  for (int a = 0; a < 4; ++a)
#pragma unroll
    for (int b = 0; b < 2; ++b) {
      const int n = n0 + wn * 64 + a * 16 + i;
      const int c = half * 64 + wm * 32 + b * 16 + 4 * g;
      const int hh = c >> 5, d = c & 31;
      const int wcol = n & 31, hrow = n >> 5;
      float vv[4];
#pragma unroll
      for (int r = 0; r < 4; ++r)
        vv[r] = acc[a][b][r] + rw[(c + r) * 32 + wcol] + rh[(c + r) * 32 + hrow];
      us4 pk = {f2bf(vv[0]), f2bf(vv[1]), f2bf(vv[2]), f2bf(vv[3])};
      *(us4*)(out1 + (((size_t)(bb * 4 + hh) << 10) + n) * 32 + d) = pk;
    }

  // ---- v (typ 2) ----
  gemmAW(wf0);
#pragma unroll
  for (int a = 0; a < 4; ++a)
#pragma unroll
    for (int b = 0; b < 2; ++b) {
      const int c = half * 64 + wm * 32 + b * 16 + i;
      const int nb = n0 + wn * 64 + a * 16 + 4 * g;
      const int hh = c >> 5, dd = c & 31;
      us4 pk = {f2bf(acc[a][b][0]), f2bf(acc[a][b][1]), f2bf(acc[a][b][2]), f2bf(acc[a][b][3])};
      *(us4*)(out2 + (((size_t)(bb * 4 + hh) * 32 + dd) << 10) + nb) = pk;
    }
}

// ---------------------------------------------------------------------------
// MFMA flash attention: 32 queries/wave (2 Q-frags), pipelined K/V staging.
// grid (NQ/128, BATCH*HEADS), 256 threads. Writes fp32 aoT [b][n][128].
// ---------------------------------------------------------------------------
__global__ __launch_bounds__(256) void k_attn_mfma(const unsigned short* __restrict__ qs,
                                                   const unsigned short* __restrict__ kt,
                                                   const unsigned short* __restrict__ vt,
                                                   float* __restrict__ aoT) {
  const int bh   = blockIdx.y;
  const int tid  = threadIdx.x;
  const int lane = tid & 63;
  const int wv   = tid >> 6;
  const int i    = lane & 15;
  const int g    = lane >> 4;
  const int n0w  = blockIdx.x * 128 + wv * 32;

  __shared__ unsigned short Ks[64 * 56];
  __shared__ unsigned short Vt[32 * 72];

  const bf8 qfA = *(const bf8*)(qs + ((size_t)bh * NQ + n0w + i) * 32 + g * 8);
  const bf8 qfB = *(const bf8*)(qs + ((size_t)bh * NQ + n0w + 16 + i) * 32 + g * 8);

  f32x4 o0A = {0.f,0.f,0.f,0.f}, o1A = {0.f,0.f,0.f,0.f};
  f32x4 o0B = {0.f,0.f,0.f,0.f}, o1B = {0.f,0.f,0.f,0.f};
  float mA = -1e30f, lA = 0.f, mB = -1e30f, lB = 0.f;

  const unsigned short* kb = kt + (size_t)bh * NQ * 32;
  const unsigned short* vb = vt + (size_t)bh * 32 * NQ;

  const int skey = tid >> 2, sds = (tid & 3) * 8;
  const int svd  = tid >> 3, svn = (tid & 7) * 8;

  // prologue loads for tile 0
  bf8 kvld = *(const bf8*)(kb + (size_t)skey * 32 + sds);
  bf8 vvld = *(const bf8*)(vb + (size_t)svd * NQ + svn);

  for (int k0 = 0; k0 < NQ; k0 += 64) {
    __syncthreads();
    *(bf8*)&Ks[skey * 56 + sds] = kvld;
    *(bf8*)&Vt[svd * 72 + svn]  = vvld;
    __syncthreads();
    if (k0 + 64 < NQ) {   // issue next-tile loads; latency hides under compute
      kvld = *(const bf8*)(kb + (size_t)(k0 + 64 + skey) * 32 + sds);
      vvld = *(const bf8*)(vb + (size_t)svd * NQ + (k0 + 64) + svn);
    }

    const f32x4 zero = {0.f,0.f,0.f,0.f};
    f32x4 stA[4], stB[4];
#pragma unroll
    for (int t = 0; t < 4; ++t) {
      bf8 kf = *(const bf8*)&Ks[(t * 16 + i) * 56 + g * 8];
      stA[t] = __builtin_amdgcn_mfma_f32_16x16x32_bf16(kf, qfA, zero, 0, 0, 0);
      stB[t] = __builtin_amdgcn_mfma_f32_16x16x32_bf16(kf, qfB, zero, 0, 0, 0);
    }

    // ---- softmax A ----
    unsigned int pkA[4][2], pkB[4][2];
    {
      float tmax = stA[0][0];
#pragma unroll
      for (int t = 0; t < 4; ++t)
#pragma unroll
        for (int r = 0; r < 4; ++r) tmax = fmaxf(tmax, stA[t][r]);
      tmax = fmaxf(tmax, __shfl_xor(tmax, 16));
      tmax = fmaxf(tmax, __shfl_xor(tmax, 32));
      const float mn = fmaxf(mA, tmax);
      const float corr = fast_exp2(mA - mn);
      mA = mn;
      float ps = 0.f;
#pragma unroll
      for (int t = 0; t < 4; ++t) {
        float p0 = fast_exp2(stA[t][0] - mn);
        float p1 = fast_exp2(stA[t][1] - mn);
        float p2 = fast_exp2(stA[t][2] - mn);
        float p3 = fast_exp2(stA[t][3] - mn);
        ps += (p0 + p1) + (p2 + p3);
        unsigned int pa, pb;
        asm("v_cvt_pk_bf16_f32 %0, %1, %2" : "=v"(pa) : "v"(p0), "v"(p1));
        asm("v_cvt_pk_bf16_f32 %0, %1, %2" : "=v"(pb) : "v"(p2), "v"(p3));
        pkA[t][0] = pa; pkA[t][1] = pb;
      }
      ps += __shfl_xor(ps, 16);
      ps += __shfl_xor(ps, 32);
      lA = lA * corr + ps;
#pragma unroll
      for (int r = 0; r < 4; ++r) { o0A[r] *= corr; o1A[r] *= corr; }
    }
    // ---- softmax B ----
    {
      float tmax = stB[0][0];
#pragma unroll
      for (int t = 0; t < 4; ++t)
#pragma unroll
        for (int r = 0; r < 4; ++r) tmax = fmaxf(tmax, stB[t][r]);
      tmax = fmaxf(tmax, __shfl_xor(tmax, 16));
      tmax = fmaxf(tmax, __shfl_xor(tmax, 32));
      const float mn = fmaxf(mB, tmax);
      const float corr = fast_exp2(mB - mn);
      mB = mn;
      float ps = 0.f;
#pragma unroll
      for (int t = 0; t < 4; ++t) {
        float p0 = fast_exp2(stB[t][0] - mn);
        float p1 = fast_exp2(stB[t][1] - mn);
        float p2 = fast_exp2(stB[t][2] - mn);
        float p3 = fast_exp2(stB[t][3] - mn);
        ps += (p0 + p1) + (p2 + p3);
        unsigned int pa, pb;
        asm("v_cvt_pk_bf16_f32 %0, %1, %2" : "=v"(pa) : "v"(p0), "v"(p1));
        asm("v_cvt_pk_bf16_f32 %0, %1, %2" : "=v"(pb) : "v"(p2), "v"(p3));
        pkB[t][0] = pa; pkB[t][1] = pb;
      }
      ps += __shfl_xor(ps, 16);
      ps += __shfl_xor(ps, 32);
      lB = lB * corr + ps;
#pragma unroll
      for (int r = 0; r < 4; ++r) { o0B[r] *= corr; o1B[r] *= corr; }
    }

    // ---- PV (shared vf loads for both halves) ----
    const int src0 = ((g & 1) << 5) + i;
    const int src1 = src0 + 16;
    const bool hi = (g >= 2);
#pragma unroll
    for (int s = 0; s < 2; ++s) {
      int a0 = __shfl((int)pkA[2 * s][0], src0);
      int a1 = __shfl((int)pkA[2 * s][1], src0);
      int a2 = __shfl((int)pkA[2 * s][0], src1);
      int a3 = __shfl((int)pkA[2 * s][1], src1);
      int b0 = __shfl((int)pkA[2 * s + 1][0], src0);
      int b1 = __shfl((int)pkA[2 * s + 1][1], src0);
      int b2 = __shfl((int)pkA[2 * s + 1][0], src1);
      int b3 = __shfl((int)pkA[2 * s + 1][1], src1);
      union { int d[4]; bf8 v; } pfA;
      pfA.d[0] = hi ? b0 : a0;
      pfA.d[1] = hi ? b1 : a1;
      pfA.d[2] = hi ? b2 : a2;
      pfA.d[3] = hi ? b3 : a3;
      int c0 = __shfl((int)pkB[2 * s][0], src0);
      int c1 = __shfl((int)pkB[2 * s][1], src0);
      int c2 = __shfl((int)pkB[2 * s][0], src1);
      int c3 = __shfl((int)pkB[2 * s][1], src1);
      int d0 = __shfl((int)pkB[2 * s + 1][0], src0);
      int d1 = __shfl((int)pkB[2 * s + 1][1], src0);
      int d2 = __shfl((int)pkB[2 * s + 1][0], src1);
      int d3 = __shfl((int)pkB[2 * s + 1][1], src1);
      union { int d[4]; bf8 v; } pfB;
      pfB.d[0] = hi ? d0 : c0;
      pfB.d[1] = hi ? d1 : c1;
      pfB.d[2] = hi ? d2 : c2;
      pfB.d[3] = hi ? d3 : c3;
      bf8 vf0 = *(const bf8*)&Vt[(i)      * 72 + s * 32 + g * 8];
      bf8 vf1 = *(const bf8*)&Vt[(16 + i) * 72 + s * 32 + g * 8];
      o0A = __builtin_amdgcn_mfma_f32_16x16x32_bf16(vf0, pfA.v, o0A, 0, 0, 0);
      o1A = __builtin_amdgcn_mfma_f32_16x16x32_bf16(vf1, pfA.v, o1A, 0, 0, 0);
      o0B = __builtin_amdgcn_mfma_f32_16x16x32_bf16(vf0, pfB.v, o0B, 0, 0, 0);
      o1B = __builtin_amdgcn_mfma_f32_16x16x32_bf16(vf1, pfB.v, o1B, 0, 0, 0);
    }
  }

  const float invA = 1.f / lA;
  const float invB = 1.f / lB;
  float* dstA = aoT + (((size_t)(bh >> 2) << 10) + n0w + i) * 128 + (bh & 3) * 32 + 4 * g;
  float* dstB = aoT + (((size_t)(bh >> 2) << 10) + n0w + 16 + i) * 128 + (bh & 3) * 32 + 4 * g;
  f32x4 pA0 = {o0A[0] * invA, o0A[1] * invA, o0A[2] * invA, o0A[3] * invA};
  f32x4 pA1 = {o1A[0] * invA, o1A[1] * invA, o1A[2] * invA, o1A[3] * invA};
  f32x4 pB0 = {o0B[0] * invB, o0B[1] * invB, o0B[2] * invB, o0B[3] * invB};
  f32x4 pB1 = {o1B[0] * invB, o1B[1] * invB, o1B[2] * invB, o1B[3] * invB};
  *(f32x4*)dstA        = pA0;
  *(f32x4*)(dstA + 16) = pA1;
  *(f32x4*)dstB        = pB0;
  *(f32x4*)(dstB + 16) = pB1;
}

// ---------------------------------------------------------------------------
// conv2 stats pass: split-precision MFMA, NO y2 store; bn2 per-block partials.
// Block 64n x 256m (4 m-subtiles), 4 waves. grid (16, 2, 16).
// ---------------------------------------------------------------------------
__global__ __launch_bounds__(256) void k_stat2(const unsigned short* __restrict__ W,
                                               const float* __restrict__ Aof,
                                               float* __restrict__ pBS,
                                               float* __restrict__ pBQ) {
  constexpr int BS = 264;
  __shared__ unsigned short Blds[64 * BS];
  __shared__ float Sl[256], Ql[256];
  const int bb = blockIdx.z;
  const int mh = blockIdx.y;
  const int n0 = blockIdx.x * 64;
  const int tid = threadIdx.x, lane = tid & 63, wv = tid >> 6;
  const int wn = wv & 1, wm = wv >> 1;
  const int i = lane & 15, g = lane >> 4;

  Sl[tid] = 0.f; Ql[tid] = 0.f;

  const int sn = tid >> 2, sk = (tid & 3) * 32;
  const float* src = Aof + (((size_t)(bb << 10)) + n0 + sn) * 128 + sk;
#pragma unroll
  for (int p = 0; p < 4; ++p) {
    float4 f0 = *(const float4*)(src + p * 8);
    float4 f1 = *(const float4*)(src + p * 8 + 4);
    float fv[8] = {f0.x, f0.y, f0.z, f0.w, f1.x, f1.y, f1.z, f1.w};
    us8 hi, lo;
#pragma unroll
    for (int j = 0; j < 8; ++j) {
      unsigned short h16 = f2bf(fv[j]);
      hi[j] = h16;
      lo[j] = f2bf(fv[j] - b2f(h16));
    }
    *(us8*)&Blds[sn * BS + sk + p * 8]       = hi;
    *(us8*)&Blds[sn * BS + 128 + sk + p * 8] = lo;
  }
  __syncthreads();

  auto loadw = [&](bf8 (&wf)[2][4], int lp) {
    const int mt = mh * 4 + lp;
#pragma unroll
    for (int b = 0; b < 2; ++b)
#pragma unroll
      for (int h = 0; h < 4; ++h)
        wf[b][h] = *(const bf8*)(W + (size_t)(mt * 64 + wm * 32 + b * 16 + i) * 128 + h * 32 + g * 8);
  };

  auto step = [&](bf8 (&wf)[2][4], int lp) {
    f32x4 acc[2][2];
#pragma unroll
    for (int a = 0; a < 2; ++a)
#pragma unroll
      for (int b = 0; b < 2; ++b) acc[a][b] = {0.f, 0.f, 0.f, 0.f};
#pragma unroll
    for (int h = 0; h < 4; ++h) {
      bf8 ah[2], al[2];
#pragma unroll
      for (int a = 0; a < 2; ++a) {
        ah[a] = *(const bf8*)&Blds[(wn * 32 + a * 16 + i) * BS + h * 32 + g * 8];
        al[a] = *(const bf8*)&Blds[(wn * 32 + a * 16 + i) * BS + 128 + h * 32 + g * 8];
      }
#pragma unroll
      for (int a = 0; a < 2; ++a)
#pragma unroll
        for (int b = 0; b < 2; ++b) {
          acc[a][b] = __builtin_amdgcn_mfma_f32_16x16x32_bf16(ah[a], wf[b][h], acc[a][b], 0, 0, 0);
          acc[a][b] = __builtin_amdgcn_mfma_f32_16x16x32_bf16(al[a], wf[b][h], acc[a][b], 0, 0, 0);
        }
    }
#pragma unroll
    for (int b = 0; b < 2; ++b) {
      float s = 0.f, q = 0.f;
#pragma unroll
      for (int a = 0; a < 2; ++a)
#pragma unroll
        for (int r = 0; r < 4; ++r) {
          float v = acc[a][b][r];
          s += v; q += v * v;
        }
      s += __shfl_xor(s, 16); s += __shfl_xor(s, 32);
      q += __shfl_xor(q, 16); q += __shfl_xor(q, 32);
      if ((lane & 48) == 0) {
        const int cl = lp * 64 + wm * 32 + b * 16 + i;
        atomicAdd(&Sl[cl], s);
        atomicAdd(&Ql[cl], q);
      }
    }
  };

  bf8 wfA[2][4], wfB[2][4];
  loadw(wfA, 0);
  loadw(wfB, 1);
  step(wfA, 0);
  loadw(wfA, 2);
  step(wfB, 1);
  loadw(wfB, 3);
  step(wfA, 2);
  step(wfB, 3);

  __syncthreads();
  const int pidx = bb * 16 + blockIdx.x;
  pBS[(size_t)(mh * 256 + tid) * 256 + pidx] = Sl[tid];
  pBQ[(size_t)(mh * 256 + tid) * 256 + pidx] = Ql[tid];
}

// 512 blocks x 64 threads: reduce 256 partials per channel.
__global__ __launch_bounds__(64) void k_bnfin2(const float* __restrict__ pBS,
                                               const float* __restrict__ pBQ,
                                               const float* __restrict__ g,
                                               const float* __restrict__ be,
                                               float* __restrict__ scl,
                                               float* __restrict__ sht) {
  const int c = blockIdx.x, t = threadIdx.x;
  float S = 0.f, Q = 0.f;
#pragma unroll
  for (int k = 0; k < 4; ++k) {
    S += pBS[(size_t)c * 256 + t + k * 64];
    Q += pBQ[(size_t)c * 256 + t + k * 64];
  }
#pragma unroll
  for (int o = 32; o > 0; o >>= 1) {
    S += __shfl_down(S, o);
    Q += __shfl_down(Q, o);
  }
  if (t == 0) {
    const float inv_n = 1.f / 16384.f;
    const float mean = S * inv_n, var = Q * inv_n - mean * mean;
    const float sc = rsqrtf(var + 1e-5f) * g[c];
    scl[c] = sc;
    sht[c] = be[c] - mean * sc;
  }
}

// ---------------------------------------------------------------------------
// final pass: recompute conv2 (identical staging/MFMA order as k_stat2),
// apply bn2 + residual + relu, write out. grid (16, 2, 16).
// ---------------------------------------------------------------------------
__global__ __launch_bounds__(256) void k_final2(const unsigned short* __restrict__ W,
                                                const float* __restrict__ Aof,
                                                const float* __restrict__ x,
                                                const float* __restrict__ scl2,
                                                const float* __restrict__ sht2,
                                                float* __restrict__ out) {
  constexpr int BS = 264;
  __shared__ unsigned short Blds[64 * BS];
  __shared__ float scl_s[256], sht_s[256];
  const int bb = blockIdx.z;
  const int mh = blockIdx.y;
  const int n0 = blockIdx.x * 64;
  const int tid = threadIdx.x, lane = tid & 63, wv = tid >> 6;
  const int wn = wv & 1, wm = wv >> 1;
  const int i = lane & 15, g = lane >> 4;

  scl_s[tid] = scl2[mh * 256 + tid];
  sht_s[tid] = sht2[mh * 256 + tid];

  const int sn = tid >> 2, sk = (tid & 3) * 32;
  const float* src = Aof + (((size_t)(bb << 10)) + n0 + sn) * 128 + sk;
#pragma unroll
  for (int p = 0; p < 4; ++p) {
    float4 f0 = *(const float4*)(src + p * 8);
    float4 f1 = *(const float4*)(src + p * 8 + 4);
    float fv[8] = {f0.x, f0.y, f0.z, f0.w, f1.x, f1.y, f1.z, f1.w};
    us8 hi, lo;
#pragma unroll
    for (int j = 0; j < 8; ++j) {
      unsigned short h16 = f2bf(fv[j]);
      hi[j] = h16;
      lo[j] = f2bf(fv[j] - b2f(h16));
    }
    *(us8*)&Blds[sn * BS + sk + p * 8]       = hi;
    *(us8*)&Blds[sn * BS + 128 + sk + p * 8] = lo;
  }
  __syncthreads();

  auto loadw = [&](bf8 (&wf)[2][4], int lp) {
    const int mt = mh * 4 + lp;
#pragma unroll
    for (int b = 0; b < 2; ++b)
#pragma unroll
      for (int h = 0; h < 4; ++h)
        wf[b][h] = *(const bf8*)(W + (size_t)(mt * 64 + wm * 32 + b * 16 + i) * 128 + h * 32 + g * 8);
  };

  auto step = [&](bf8 (&wf)[2][4], int lp) {
    const int mt = mh * 4 + lp;
    f32x4 acc[2][2];
#pragma unroll
    for (int a = 0; a < 2; ++a)
#pragma unroll
      for (int b = 0; b < 2; ++b) acc[a][b] = {0.f, 0.f, 0.f, 0.f};
#pragma unroll
    for (int h = 0; h < 4; ++h) {
      bf8 ah[2], al[2];
#pragma unroll
      for (int a = 0; a < 2; ++a) {
        ah[a] = *(const bf8*)&Blds[(wn * 32 + a * 16 + i) * BS + h * 32 + g * 8];
        al[a] = *(const bf8*)&Blds[(wn * 32 + a * 16 + i) * BS + 128 + h * 32 + g * 8];
      }
#pragma unroll
      for (int a = 0; a < 2; ++a)
#pragma unroll
        for (int b = 0; b < 2; ++b) {
          acc[a][b] = __builtin_amdgcn_mfma_f32_16x16x32_bf16(ah[a], wf[b][h], acc[a][b], 0, 0, 0);
          acc[a][b] = __builtin_amdgcn_mfma_f32_16x16x32_bf16(al[a], wf[b][h], acc[a][b], 0, 0, 0);
        }
    }
#pragma unroll
    for (int a = 0; a < 2; ++a)
#pragma unroll
      for (int b = 0; b < 2; ++b) {
        const int c = mt * 64 + wm * 32 + b * 16 + i;
        const int cl = lp * 64 + wm * 32 + b * 16 + i;
        const int nb = n0 + wn * 32 + a * 16 + 4 * g;
        const float sc = scl_s[cl], sh = sht_s[cl];
        const size_t off = (((size_t)(bb * 512 + c)) << 10) + nb;
        float4 xv = *(const float4*)(x + off);
        f32x4 o;
        o[0] = fmaxf(acc[a][b][0] * sc + sh + xv.x, 0.f);
        o[1] = fmaxf(acc[a][b][1] * sc + sh + xv.y, 0.f);
        o[2] = fmaxf(acc[a][b][2] * sc + sh + xv.z, 0.f);
        o[3] = fmaxf(acc[a][b][3] * sc + sh + xv.w, 0.f);
        *(f32x4*)(out + off) = o;
      }
  };

  bf8 wfA[2][4], wfB[2][4];
  loadw(wfA, 0);
  loadw(wfB, 1);
  step(wfA, 0);
  loadw(wfA, 2);
  step(wfB, 1);
  loadw(wfB, 3);
  step(wfA, 2);
  step(wfB, 3);
}

// ---------------------------------------------------------------------------
extern "C" void kernel_launch(void* const* d_in, const int* in_sizes, int n_in,
                              void* d_out, int out_size, void* d_ws, size_t ws_size,
                              hipStream_t stream) {
  (void)in_sizes; (void)n_in; (void)out_size; (void)ws_size;
  const float* x    = (const float*)d_in[0];
  const float* w1   = (const float*)d_in[1];
  const float* g1   = (const float*)d_in[2];
  const float* b1   = (const float*)d_in[3];
  const float* wqkv = (const float*)d_in[4];
  const float* rw   = (const float*)d_in[5];
  const float* rh   = (const float*)d_in[6];
  const float* w2   = (const float*)d_in[7];
  const float* g2   = (const float*)d_in[8];
  const float* b2   = (const float*)d_in[9];
  float* out = (float*)d_out;
  char* base = (char*)d_ws;

  // Workspace (bytes): aoT fp32 [0,8M) | y1T [8,12) | qs [12,16) | kt [16,20)
  // | vt [20,24) | weights bf16 [24M,+352K) | partials/scalars [25M..26.3M)
  float*          aoT = (float*)(base);
  unsigned short* y1T = (unsigned short*)(base + (8u  << 20));
  unsigned short* qs  = (unsigned short*)(base + (12u << 20));
  unsigned short* kt  = (unsigned short*)(base + (16u << 20));
  unsigned short* vt  = (unsigned short*)(base + (20u << 20));
  unsigned short* wb1 = (unsigned short*)(base + (24u << 20));
  unsigned short* wbq = wb1 + 65536;
  unsigned short* wb2 = wbq + 49152;
  float* pS1  = (float*)(base + (25u << 20));  // 128*256
  float* pQ1  = pS1 + 32768;
  float* pBS  = pQ1 + 32768;                   // 512*256
  float* pBQ  = pBS + 131072;
  float* scl1 = pBQ + 131072;
  float* sht1 = scl1 + 128;
  float* scl2 = sht1 + 128;
  float* sht2 = scl2 + 512;

  // 1) weights -> bf16
  k_wcvt<<<88, 256, 0, stream>>>(w1, wqkv, w2, wb1, wbq, wb2);
  // 2) conv1 (fused transpose + bn1 partials) -> y1T, pS1/pQ1
  k_conv1<<<dim3(16, 1, BATCH), 256, 0, stream>>>(x, wb1, y1T, pS1, pQ1);
  // 3) bn1 finalize
  k_bnfin1<<<128, 64, 0, stream>>>(pS1, pQ1, g1, b1, scl1, sht1);
  // 4) qkv (MFMA, bn1+relu fused, single-staged) -> q,k'(+r),v bf16
  k_qkv<<<dim3(8, 2, BATCH), 256, 0, stream>>>(wbq, y1T, scl1, sht1,
                                               rw, rh, qs, kt, vt);
  // 5) flash attention (32 q/wave, pipelined) -> aoT fp32 [b][n][128]
  k_attn_mfma<<<dim3(NQ / 128, BATCH * 4), 256, 0, stream>>>(qs, kt, vt, aoT);
  // 6) conv2 stats pass (no y2) -> pBS/pBQ
  k_stat2<<<dim3(16, 2, BATCH), 256, 0, stream>>>(wb2, aoT, pBS, pBQ);
  // 7) bn2 finalize
  k_bnfin2<<<512, 64, 0, stream>>>(pBS, pBQ, g2, b2, scl2, sht2);
  // 8) final: recompute conv2 + bn2 + residual + relu -> out
  k_final2<<<dim3(16, 2, BATCH), 256, 0, stream>>>(wb2, aoT, x, scl2, sht2, out);
}